// Round 1
// baseline (34736.166 us; speedup 1.0000x reference)
//
#include <hip/hip_runtime.h>
#include <cstdint>
#include <cstddef>

// ---------------------------------------------------------------------------
// ParityGameGATNetwork: 3x GATConv -> JK bidirectional LSTM -> node/edge MLPs
// Round 1: correctness-first f32 pipeline with on-device dtype sniffing
// (inputs may be f32 or bf16; edge_index may be int32 or int64 — detected).
// ---------------------------------------------------------------------------

#define NIN 28

struct InPtrs { const void* p[NIN]; int n[NIN]; };

__device__ __forceinline__ float bf2f(unsigned short v) {
    unsigned int u = ((unsigned int)v) << 16;
    return __uint_as_float(u);
}

// ---------------- dtype sniffing -------------------------------------------
// flags[i] for float arrays: 1 => underlying f32, 0 => underlying bf16
// flags[1] for edge_index:   1 => int64, 0 => int32
__global__ void k_sniff(InPtrs in, int* flags) {
    int ai = blockIdx.x;
    if (ai >= NIN) return;
    __shared__ int cnt;
    if (threadIdx.x == 0) cnt = 0;
    __syncthreads();
    if (ai == 1) {
        const int* w = (const int*)in.p[1];
        int nw = in.n[1] < 512 ? in.n[1] : 512;   // safe: nw*4 <= bytes either way
        int local = 0;
        for (int i = threadIdx.x; i < nw; i += blockDim.x)
            if ((i & 1) && w[i] != 0) local++;
        atomicAdd(&cnt, local);
        __syncthreads();
        if (threadIdx.x == 0) flags[1] = (cnt < 4) ? 1 : 0;  // odd words all zero => int64
        return;
    }
    const unsigned short* u = (const unsigned short*)in.p[ai];
    int ns = in.n[ai] < 256 ? in.n[ai] : 256;     // safe: ns*2 <= bytes either way
    int local = 0;
    for (int i = threadIdx.x; i < ns; i += blockDim.x) {
        if (i & 1) continue;  // even bf16 slots = low halves of f32 words if f32
        unsigned short v = u[i];
        int e = (v >> 7) & 0xff;
        if ((v & 0x7fff) != 0 && (e < 100 || e > 154)) local++;
    }
    atomicAdd(&cnt, local);
    __syncthreads();
    if (threadIdx.x == 0) flags[ai] = (cnt * 4 >= ns) ? 1 : 0;  // many wild exponents => f32
}

__global__ void k_convf(const void* src, float* dst, int n, const int* flags, int ai) {
    int i = blockIdx.x * blockDim.x + threadIdx.x;
    if (i >= n) return;
    if (flags[ai]) dst[i] = ((const float*)src)[i];
    else           dst[i] = bf2f(((const unsigned short*)src)[i]);
}

__global__ void k_conve(const void* src, int* row, int* col, int E, const int* flags) {
    int i = blockIdx.x * blockDim.x + threadIdx.x;
    if (i >= E) return;
    if (flags[1]) {
        const long long* s = (const long long*)src;
        row[i] = (int)s[i];
        col[i] = (int)s[(size_t)E + i];
    } else {
        const int* s = (const int*)src;
        row[i] = s[i];
        col[i] = s[(size_t)E + i];
    }
}

// ---------------- CSR build ------------------------------------------------
__global__ void k_zeroi(int* p, int n) {
    int i = blockIdx.x * blockDim.x + threadIdx.x;
    if (i < n) p[i] = 0;
}

__global__ void k_hist(const int* __restrict__ row, int* __restrict__ cnt, int E) {
    int i = blockIdx.x * blockDim.x + threadIdx.x;
    if (i < E) atomicAdd(&cnt[row[i]], 1);
}

__global__ void k_scan(const int* __restrict__ deg, int* __restrict__ indptr, int N) {
    __shared__ int buf[1024];
    __shared__ int carryS;
    const int t = threadIdx.x;
    if (t == 0) carryS = 0;
    __syncthreads();
    for (int base = 0; base < N; base += 1024) {
        int v = (base + t < N) ? deg[base + t] : 0;
        buf[t] = v;
        __syncthreads();
        for (int ofs = 1; ofs < 1024; ofs <<= 1) {
            int add = (t >= ofs) ? buf[t - ofs] : 0;
            __syncthreads();
            buf[t] += add;
            __syncthreads();
        }
        int carry = carryS;
        if (base + t < N) indptr[base + t] = carry + buf[t] - v;  // exclusive
        __syncthreads();
        if (t == 1023) carryS = carry + buf[1023];
        __syncthreads();
    }
    if (t == 0) indptr[N] = carryS;
}

__global__ void k_fill(const int* __restrict__ row, const int* __restrict__ col,
                       const int* __restrict__ indptr, int* __restrict__ cur,
                       int* __restrict__ colS, int E) {
    int i = blockIdx.x * blockDim.x + threadIdx.x;
    if (i >= E) return;
    int r = row[i];
    int p = indptr[r] + atomicAdd(&cur[r], 1);
    colS[p] = col[i];
}

// ---------------- GAT linear (h = x @ W) + a_src/a_dst epilogue ------------
__global__ __launch_bounds__(256) void k_lin0(
    const float* __restrict__ x, const float* __restrict__ W0,
    const float* __restrict__ asrc, const float* __restrict__ adst,
    float* __restrict__ hlin, float* __restrict__ hs, float* __restrict__ hd, int N) {
    const int wid = threadIdx.x >> 6, lane = threadIdx.x & 63;
    const int n = blockIdx.x * 4 + wid;
    if (n >= N) return;
    float x0 = x[(size_t)n * 3], x1 = x[(size_t)n * 3 + 1], x2 = x[(size_t)n * 3 + 2];
    const int c0 = lane, c1 = lane + 64;
    float h0 = x0 * W0[c0] + x1 * W0[128 + c0] + x2 * W0[256 + c0];
    float h1 = x0 * W0[c1] + x1 * W0[128 + c1] + x2 * W0[256 + c1];
    hlin[(size_t)n * 128 + c0] = h0;
    hlin[(size_t)n * 128 + c1] = h1;
    float sp = h0 * asrc[c0] + h1 * asrc[c1];
    float dp = h0 * adst[c0] + h1 * adst[c1];
    for (int o = 32; o; o >>= 1) { sp += __shfl_down(sp, o); dp += __shfl_down(dp, o); }
    if (lane == 0) { hs[n] = sp; hd[n] = dp; }
}

__global__ __launch_bounds__(256) void k_lin(
    const float* __restrict__ xin, const float* __restrict__ W,
    const float* __restrict__ asrc, const float* __restrict__ adst,
    float* __restrict__ hlin, float* __restrict__ hs, float* __restrict__ hd, int N) {
    __shared__ float xl[4][128];
    const int wid = threadIdx.x >> 6, lane = threadIdx.x & 63;
    const int n = blockIdx.x * 4 + wid;
    if (n < N) {
        xl[wid][lane]      = xin[(size_t)n * 128 + lane];
        xl[wid][lane + 64] = xin[(size_t)n * 128 + lane + 64];
    }
    __syncthreads();
    if (n >= N) return;
    const int c0 = lane, c1 = lane + 64;
    float h0 = 0.f, h1 = 0.f;
    #pragma unroll 4
    for (int k = 0; k < 128; ++k) {
        float xv = xl[wid][k];
        h0 += xv * W[k * 128 + c0];
        h1 += xv * W[k * 128 + c1];
    }
    hlin[(size_t)n * 128 + c0] = h0;
    hlin[(size_t)n * 128 + c1] = h1;
    float sp = h0 * asrc[c0] + h1 * asrc[c1];
    float dp = h0 * adst[c0] + h1 * adst[c1];
    for (int o = 32; o; o >>= 1) { sp += __shfl_down(sp, o); dp += __shfl_down(dp, o); }
    if (lane == 0) { hs[n] = sp; hd[n] = dp; }
}

// ---------------- GAT aggregation: online segment softmax + weighted sum ---
__global__ __launch_bounds__(256) void k_aggr(
    const float* __restrict__ hlin, const float* __restrict__ hs, const float* __restrict__ hd,
    const int* __restrict__ indptr, const int* __restrict__ colS,
    const float* __restrict__ b, float* __restrict__ xout, int N) {
    const int wid = threadIdx.x >> 6, lane = threadIdx.x & 63;
    const int n = blockIdx.x * 4 + wid;
    if (n >= N) return;
    const int s = indptr[n], epos = indptr[n + 1];
    const float hdv = hd[n];
    const int c0 = lane, c1 = lane + 64;
    float m = -1e30f, d = 0.f, a0 = 0.f, a1 = 0.f;
    for (int idx = s; idx < epos; ++idx) {
        int col = colS[idx];
        float e = hs[col] + hdv;
        e = (e > 0.f) ? e : 0.2f * e;          // leaky_relu 0.2
        const float* hr = hlin + (size_t)col * 128;
        float v0 = hr[c0], v1 = hr[c1];
        if (e > m) {                            // wave-uniform branch
            float sc = __expf(m - e);
            a0 = a0 * sc + v0;
            a1 = a1 * sc + v1;
            d  = d * sc + 1.f;
            m  = e;
        } else {
            float w = __expf(e - m);
            a0 += w * v0;
            a1 += w * v1;
            d  += w;
        }
    }
    float inv = 1.f / (d + 1e-16f);
    float r0 = a0 * inv + b[c0];
    float r1 = a1 * inv + b[c1];
    xout[(size_t)n * 128 + c0] = fmaxf(r0, 0.f);  // relu
    xout[(size_t)n * 128 + c1] = fmaxf(r1, 0.f);
}

// ---------------- JK bidirectional LSTM + attention + weighted sum ---------
// 16 nodes per 256-thread block; thread (nl,q) owns hidden slots [q*12, q*12+12)
__global__ __launch_bounds__(256) void k_lstmjk(
    const float* __restrict__ xs,    // [3][N][128]
    const float* __restrict__ Wih_f, const float* __restrict__ Whh_f,
    const float* __restrict__ bih_f, const float* __restrict__ bhh_f,
    const float* __restrict__ Wih_b, const float* __restrict__ Whh_b,
    const float* __restrict__ bih_b, const float* __restrict__ bhh_b,
    const float* __restrict__ attW,  // [384]
    float* __restrict__ hJK, int N) {
    __shared__ float xtL[16 * 128];
    __shared__ float hA[16 * 192];
    __shared__ float hB[16 * 192];
    __shared__ float cL[16 * 192];
    __shared__ float partS[256];
    __shared__ float scoreS[48];
    const int t = threadIdx.x;
    const int nl = t >> 4;
    const int q = t & 15;
    const int node0 = blockIdx.x * 16;
    const int node = node0 + nl;
    if (t < 48) scoreS[t] = 0.f;

    for (int dir = 0; dir < 2; ++dir) {
        const float* Wih = dir ? Wih_b : Wih_f;
        const float* Whh = dir ? Whh_b : Whh_f;
        const float* bi  = dir ? bih_b : bih_f;
        const float* bh  = dir ? bhh_b : bhh_f;
        for (int i = t; i < 16 * 192; i += 256) { hA[i] = 0.f; cL[i] = 0.f; }
        float* hcur = hA;
        float* hnxt = hB;
        __syncthreads();
        for (int s = 0; s < 3; ++s) {
            const int l = dir ? (2 - s) : s;
            {
                const float* src = xs + ((size_t)l * N + node0) * 128;
                int lim = (N - node0) * 128;
                if (lim > 16 * 128) lim = 16 * 128;
                for (int i = t; i < 16 * 128; i += 256) xtL[i] = (i < lim) ? src[i] : 0.f;
            }
            __syncthreads();
            const float4* xv4 = (const float4*)(xtL + nl * 128);
            const float4* hv4 = (const float4*)(hcur + nl * 192);
            float sp = 0.f;
            #pragma unroll 1
            for (int r = 0; r < 12; ++r) {
                const int hidx = q * 12 + r;
                float a0 = bi[hidx]       + bh[hidx];
                float a1 = bi[192 + hidx] + bh[192 + hidx];
                float a2 = bi[384 + hidx] + bh[384 + hidx];
                float a3 = bi[576 + hidx] + bh[576 + hidx];
                {
                    const float4* w0 = (const float4*)Wih + (size_t)hidx * 32;
                    const float4* w1 = (const float4*)Wih + (size_t)(192 + hidx) * 32;
                    const float4* w2 = (const float4*)Wih + (size_t)(384 + hidx) * 32;
                    const float4* w3 = (const float4*)Wih + (size_t)(576 + hidx) * 32;
                    #pragma unroll 8
                    for (int k = 0; k < 32; ++k) {
                        float4 xx = xv4[k];
                        float4 u0 = w0[k], u1 = w1[k], u2 = w2[k], u3 = w3[k];
                        a0 += u0.x * xx.x + u0.y * xx.y + u0.z * xx.z + u0.w * xx.w;
                        a1 += u1.x * xx.x + u1.y * xx.y + u1.z * xx.z + u1.w * xx.w;
                        a2 += u2.x * xx.x + u2.y * xx.y + u2.z * xx.z + u2.w * xx.w;
                        a3 += u3.x * xx.x + u3.y * xx.y + u3.z * xx.z + u3.w * xx.w;
                    }
                }
                {
                    const float4* v0 = (const float4*)Whh + (size_t)hidx * 48;
                    const float4* v1 = (const float4*)Whh + (size_t)(192 + hidx) * 48;
                    const float4* v2 = (const float4*)Whh + (size_t)(384 + hidx) * 48;
                    const float4* v3 = (const float4*)Whh + (size_t)(576 + hidx) * 48;
                    #pragma unroll 8
                    for (int k = 0; k < 48; ++k) {
                        float4 hh = hv4[k];
                        float4 u0 = v0[k], u1 = v1[k], u2 = v2[k], u3 = v3[k];
                        a0 += u0.x * hh.x + u0.y * hh.y + u0.z * hh.z + u0.w * hh.w;
                        a1 += u1.x * hh.x + u1.y * hh.y + u1.z * hh.z + u1.w * hh.w;
                        a2 += u2.x * hh.x + u2.y * hh.y + u2.z * hh.z + u2.w * hh.w;
                        a3 += u3.x * hh.x + u3.y * hh.y + u3.z * hh.z + u3.w * hh.w;
                    }
                }
                float ig = 1.f / (1.f + __expf(-a0));
                float fg = 1.f / (1.f + __expf(-a1));
                float gg = tanhf(a2);
                float og = 1.f / (1.f + __expf(-a3));
                float cn = fg * cL[nl * 192 + hidx] + ig * gg;
                cL[nl * 192 + hidx] = cn;
                float hh = og * tanhf(cn);
                hnxt[nl * 192 + hidx] = hh;
                sp += hh * attW[dir * 192 + hidx];
            }
            partS[t] = sp;
            __syncthreads();
            if (q == 0) {
                float ss = 0.f;
                #pragma unroll
                for (int j = 0; j < 16; ++j) ss += partS[nl * 16 + j];
                scoreS[nl * 3 + l] += ss;
            }
            float* tmp = hcur; hcur = hnxt; hnxt = tmp;
        }
        __syncthreads();
    }
    if (node < N) {
        float s0 = scoreS[nl * 3 + 0], s1 = scoreS[nl * 3 + 1], s2 = scoreS[nl * 3 + 2];
        // att_b is a uniform shift -> softmax-invariant; skipped.
        float m = fmaxf(s0, fmaxf(s1, s2));
        float e0 = __expf(s0 - m), e1 = __expf(s1 - m), e2 = __expf(s2 - m);
        float inv = 1.f / (e0 + e1 + e2);
        e0 *= inv; e1 *= inv; e2 *= inv;
        const size_t nb = (size_t)node * 128;
        const size_t L1o = (size_t)N * 128, L2o = 2 * (size_t)N * 128;
        #pragma unroll
        for (int j = 0; j < 8; ++j) {
            int ch = q + 16 * j;
            float v = e0 * xs[nb + ch] + e1 * xs[L1o + nb + ch] + e2 * xs[L2o + nb + ch];
            hJK[nb + ch] = v;
        }
    }
}

// ---------------- node classifier ------------------------------------------
__global__ __launch_bounds__(256) void k_nodemlp(
    const float* __restrict__ hJK, const float* __restrict__ W1, const float* __restrict__ b1,
    const float* __restrict__ W2, const float* __restrict__ b2,
    float* __restrict__ out, int N) {
    __shared__ float xl[4][128];
    const int wid = threadIdx.x >> 6, lane = threadIdx.x & 63;
    const int n = blockIdx.x * 4 + wid;
    if (n < N) {
        xl[wid][lane]      = hJK[(size_t)n * 128 + lane];
        xl[wid][lane + 64] = hJK[(size_t)n * 128 + lane + 64];
    }
    __syncthreads();
    if (n >= N) return;
    const int c0 = lane, c1 = lane + 64;
    float h0 = 0.f, h1 = 0.f;
    #pragma unroll 4
    for (int k = 0; k < 128; ++k) {
        float xv = xl[wid][k];
        h0 += xv * W1[k * 128 + c0];
        h1 += xv * W1[k * 128 + c1];
    }
    h0 = fmaxf(h0 + b1[c0], 0.f);
    h1 = fmaxf(h1 + b1[c1], 0.f);
    float p0 = h0 * W2[c0 * 2 + 0] + h1 * W2[c1 * 2 + 0];
    float p1 = h0 * W2[c0 * 2 + 1] + h1 * W2[c1 * 2 + 1];
    for (int o = 32; o; o >>= 1) { p0 += __shfl_down(p0, o); p1 += __shfl_down(p1, o); }
    if (lane == 0) {
        float l0 = p0 + b2[0], l1 = p1 + b2[1];
        float mm = fmaxf(l0, l1);
        float e0 = __expf(l0 - mm), e1 = __expf(l1 - mm);
        float inv = 1.f / (e0 + e1);
        out[2 * (size_t)n]     = e0 * inv;
        out[2 * (size_t)n + 1] = e1 * inv;
    }
}

// ---------------- edge classifier: 8 edges per wave ------------------------
__global__ __launch_bounds__(256) void k_edgemlp(
    const float* __restrict__ hJK, const int* __restrict__ row, const int* __restrict__ col,
    const float* __restrict__ W1, const float* __restrict__ b1,
    const float* __restrict__ W2, const float* __restrict__ b2,
    float* __restrict__ out, int E, int N) {
    __shared__ float rep[4][8][256];
    const int wid = threadIdx.x >> 6, lane = threadIdx.x & 63;
    const long long base = ((long long)blockIdx.x * 4 + wid) * 8;
    for (int e = 0; e < 8; ++e) {
        long long ei = base + e;
        int r = 0, cc = 0;
        if (ei < E) { r = row[ei]; cc = col[ei]; }
        const float* pr = hJK + (size_t)r * 128;
        const float* pc = hJK + (size_t)cc * 128;
        #pragma unroll
        for (int j = 0; j < 4; ++j) {
            int idx = lane + 64 * j;
            rep[wid][e][idx] = (idx < 128) ? pr[idx] : pc[idx - 128];
        }
    }
    __syncthreads();
    const int c0 = lane, c1 = lane + 64;
    float acc0[8], acc1[8];
    #pragma unroll
    for (int e = 0; e < 8; ++e) { acc0[e] = 0.f; acc1[e] = 0.f; }
    #pragma unroll 2
    for (int k = 0; k < 256; k += 4) {
        float w00 = W1[(k + 0) * 128 + c0], w01 = W1[(k + 0) * 128 + c1];
        float w10 = W1[(k + 1) * 128 + c0], w11 = W1[(k + 1) * 128 + c1];
        float w20 = W1[(k + 2) * 128 + c0], w21 = W1[(k + 2) * 128 + c1];
        float w30 = W1[(k + 3) * 128 + c0], w31 = W1[(k + 3) * 128 + c1];
        #pragma unroll
        for (int e = 0; e < 8; ++e) {
            float4 v = *(const float4*)&rep[wid][e][k];
            acc0[e] += v.x * w00 + v.y * w10 + v.z * w20 + v.w * w30;
            acc1[e] += v.x * w01 + v.y * w11 + v.z * w21 + v.w * w31;
        }
    }
    float p0[8], p1[8];
    #pragma unroll
    for (int e = 0; e < 8; ++e) {
        float h0 = fmaxf(acc0[e] + b1[c0], 0.f);
        float h1 = fmaxf(acc1[e] + b1[c1], 0.f);
        p0[e] = h0 * W2[c0 * 2 + 0] + h1 * W2[c1 * 2 + 0];
        p1[e] = h0 * W2[c0 * 2 + 1] + h1 * W2[c1 * 2 + 1];
    }
    #pragma unroll
    for (int st = 0; st < 6; ++st) {
        int o = 32 >> st;
        #pragma unroll
        for (int e = 0; e < 8; ++e) {
            p0[e] += __shfl_xor(p0[e], o);
            p1[e] += __shfl_xor(p1[e], o);
        }
    }
    float l0 = 0.f, l1 = 0.f;
    #pragma unroll
    for (int e = 0; e < 8; ++e)
        if (lane == e) { l0 = p0[e]; l1 = p1[e]; }
    if (lane < 8) {
        long long ei = base + lane;
        if (ei < E) {
            l0 += b2[0]; l1 += b2[1];
            float mm = fmaxf(l0, l1);
            float e0 = __expf(l0 - mm), e1 = __expf(l1 - mm);
            float inv = 1.f / (e0 + e1);
            out[2 * (long long)N + 2 * ei]     = e0 * inv;
            out[2 * (long long)N + 2 * ei + 1] = e1 * inv;
        }
    }
}

// ---------------------------------------------------------------------------
extern "C" void kernel_launch(void* const* d_in, const int* in_sizes, int n_in,
                              void* d_out, int out_size, void* d_ws, size_t ws_size,
                              hipStream_t stream) {
    if (n_in < NIN) return;
    const int N = in_sizes[0] / 3;
    const int E = in_sizes[1] / 2;

    char* ws = (char*)d_ws;
    size_t off = 0;
    auto alloc = [&](size_t bytes) -> char* {
        char* p = ws + off;
        off = (off + bytes + 255) & ~(size_t)255;
        return p;
    };
    int* flags = (int*)alloc(32 * sizeof(int));
    float* canon[NIN];
    for (int i = 0; i < NIN; ++i) canon[i] = nullptr;
    for (int i = 0; i < NIN; ++i) {
        if (i == 1) continue;
        canon[i] = (float*)alloc((size_t)in_sizes[i] * 4);
    }
    int* row32  = (int*)alloc((size_t)E * 4);
    int* col32  = (int*)alloc((size_t)E * 4);
    int* indptr = (int*)alloc((size_t)(N + 1) * 4);
    int* cnt    = (int*)alloc((size_t)N * 4);
    int* colS   = (int*)alloc((size_t)E * 4);
    float* hs   = (float*)alloc((size_t)N * 4);
    float* hd   = (float*)alloc((size_t)N * 4);
    float* hlin = (float*)alloc((size_t)N * 128 * 4);   // reused as hJK later
    float* xs   = (float*)alloc((size_t)3 * N * 128 * 4);
    if (off > ws_size) return;  // insufficient workspace: bail cleanly

    InPtrs ip;
    for (int i = 0; i < NIN; ++i) { ip.p[i] = d_in[i]; ip.n[i] = in_sizes[i]; }

    k_sniff<<<NIN, 256, 0, stream>>>(ip, flags);
    for (int i = 0; i < NIN; ++i) {
        if (i == 1) continue;
        int n = in_sizes[i];
        k_convf<<<(n + 255) / 256, 256, 0, stream>>>(d_in[i], canon[i], n, flags, i);
    }
    k_conve<<<(E + 255) / 256, 256, 0, stream>>>(d_in[1], row32, col32, E, flags);

    // CSR by row (shared across all 3 GAT layers)
    k_zeroi<<<(N + 255) / 256, 256, 0, stream>>>(cnt, N);
    k_hist<<<(E + 255) / 256, 256, 0, stream>>>(row32, cnt, E);
    k_scan<<<1, 1024, 0, stream>>>(cnt, indptr, N);
    k_zeroi<<<(N + 255) / 256, 256, 0, stream>>>(cnt, N);
    k_fill<<<(E + 255) / 256, 256, 0, stream>>>(row32, col32, indptr, cnt, colS, E);

    // GAT layer 0 (in=3)
    k_lin0<<<(N + 3) / 4, 256, 0, stream>>>(canon[0], canon[2], canon[4], canon[5],
                                            hlin, hs, hd, N);
    k_aggr<<<(N + 3) / 4, 256, 0, stream>>>(hlin, hs, hd, indptr, colS, canon[3], xs, N);
    // GAT layers 1..2 (in=128)
    for (int l = 1; l < 3; ++l) {
        const float* W  = canon[6] + (size_t)(l - 1) * 128 * 128;
        const float* bb = canon[7] + (size_t)(l - 1) * 128;
        const float* as = canon[8] + (size_t)(l - 1) * 128;
        const float* ad = canon[9] + (size_t)(l - 1) * 128;
        k_lin<<<(N + 3) / 4, 256, 0, stream>>>(xs + (size_t)(l - 1) * N * 128, W, as, ad,
                                               hlin, hs, hd, N);
        k_aggr<<<(N + 3) / 4, 256, 0, stream>>>(hlin, hs, hd, indptr, colS, bb,
                                                xs + (size_t)l * N * 128, N);
    }

    // JK bidirectional LSTM + attention -> hJK (reuses hlin buffer)
    k_lstmjk<<<(N + 15) / 16, 256, 0, stream>>>(xs,
        canon[10], canon[11], canon[12], canon[13],
        canon[14], canon[15], canon[16], canon[17],
        canon[18], hlin, N);

    float* out = (float*)d_out;
    k_nodemlp<<<(N + 3) / 4, 256, 0, stream>>>(hlin, canon[20], canon[21], canon[22],
                                               canon[23], out, N);
    k_edgemlp<<<(E + 31) / 32, 256, 0, stream>>>(hlin, row32, col32, canon[24], canon[25],
                                                 canon[26], canon[27], out, E, N);
}

// Round 3
// 4637.300 us; speedup vs baseline: 7.4906x; 7.4906x over previous
//
#include <hip/hip_runtime.h>
#include <cstdint>
#include <cstddef>

// ---------------------------------------------------------------------------
// ParityGameGATNetwork: 3x GATConv -> JK bidirectional LSTM -> node/edge MLPs
// Round 3: LSTM fully fused into one kernel (3 steps on-chip, h/c in LDS/regs,
// K-major weights, coalesced B, broadcast A). Workspace kept at the round-1
// footprint (no hstate/cstate; scoreP aliases dead colS; LSTM weights read
// raw by k_wtrans2 instead of being canonicalized).
// ---------------------------------------------------------------------------

#define NIN 28

struct InPtrs { const void* p[NIN]; int n[NIN]; };

__device__ __forceinline__ float bf2f(unsigned short v) {
    unsigned int u = ((unsigned int)v) << 16;
    return __uint_as_float(u);
}

__device__ __forceinline__ float rdx(const void* p, size_t i, int isf32) {
    return isf32 ? ((const float*)p)[i] : bf2f(((const unsigned short*)p)[i]);
}

// ---------------- dtype sniffing -------------------------------------------
__global__ void k_sniff(InPtrs in, int* flags) {
    int ai = blockIdx.x;
    if (ai >= NIN) return;
    __shared__ int cnt;
    if (threadIdx.x == 0) cnt = 0;
    __syncthreads();
    if (ai == 1) {
        const int* w = (const int*)in.p[1];
        int nw = in.n[1] < 512 ? in.n[1] : 512;
        int local = 0;
        for (int i = threadIdx.x; i < nw; i += blockDim.x)
            if ((i & 1) && w[i] != 0) local++;
        atomicAdd(&cnt, local);
        __syncthreads();
        if (threadIdx.x == 0) flags[1] = (cnt < 4) ? 1 : 0;
        return;
    }
    const unsigned short* u = (const unsigned short*)in.p[ai];
    int ns = in.n[ai] < 256 ? in.n[ai] : 256;
    int local = 0;
    for (int i = threadIdx.x; i < ns; i += blockDim.x) {
        if (i & 1) continue;
        unsigned short v = u[i];
        int e = (v >> 7) & 0xff;
        if ((v & 0x7fff) != 0 && (e < 100 || e > 154)) local++;
    }
    atomicAdd(&cnt, local);
    __syncthreads();
    if (threadIdx.x == 0) flags[ai] = (cnt * 4 >= ns) ? 1 : 0;
}

__global__ void k_convf(const void* src, float* dst, int n, const int* flags, int ai) {
    int i = blockIdx.x * blockDim.x + threadIdx.x;
    if (i >= n) return;
    if (flags[ai]) dst[i] = ((const float*)src)[i];
    else           dst[i] = bf2f(((const unsigned short*)src)[i]);
}

__global__ void k_conve(const void* src, int* row, int* col, int E, const int* flags) {
    int i = blockIdx.x * blockDim.x + threadIdx.x;
    if (i >= E) return;
    if (flags[1]) {
        const long long* s = (const long long*)src;
        row[i] = (int)s[i];
        col[i] = (int)s[(size_t)E + i];
    } else {
        const int* s = (const int*)src;
        row[i] = s[i];
        col[i] = s[(size_t)E + i];
    }
}

// ---------------- CSR build ------------------------------------------------
__global__ void k_zeroi(int* p, int n) {
    int i = blockIdx.x * blockDim.x + threadIdx.x;
    if (i < n) p[i] = 0;
}

__global__ void k_hist(const int* __restrict__ row, int* __restrict__ cnt, int E) {
    int i = blockIdx.x * blockDim.x + threadIdx.x;
    if (i < E) atomicAdd(&cnt[row[i]], 1);
}

__global__ void k_scan(const int* __restrict__ deg, int* __restrict__ indptr, int N) {
    __shared__ int buf[1024];
    __shared__ int carryS;
    const int t = threadIdx.x;
    if (t == 0) carryS = 0;
    __syncthreads();
    for (int base = 0; base < N; base += 1024) {
        int v = (base + t < N) ? deg[base + t] : 0;
        buf[t] = v;
        __syncthreads();
        for (int ofs = 1; ofs < 1024; ofs <<= 1) {
            int add = (t >= ofs) ? buf[t - ofs] : 0;
            __syncthreads();
            buf[t] += add;
            __syncthreads();
        }
        int carry = carryS;
        if (base + t < N) indptr[base + t] = carry + buf[t] - v;
        __syncthreads();
        if (t == 1023) carryS = carry + buf[1023];
        __syncthreads();
    }
    if (t == 0) indptr[N] = carryS;
}

__global__ void k_fill(const int* __restrict__ row, const int* __restrict__ col,
                       const int* __restrict__ indptr, int* __restrict__ cur,
                       int* __restrict__ colS, int E) {
    int i = blockIdx.x * blockDim.x + threadIdx.x;
    if (i >= E) return;
    int r = row[i];
    int p = indptr[r] + atomicAdd(&cur[r], 1);
    colS[p] = col[i];
}

// ---------------- GAT linear (h = x @ W) + a_src/a_dst epilogue ------------
__global__ __launch_bounds__(256) void k_lin0(
    const float* __restrict__ x, const float* __restrict__ W0,
    const float* __restrict__ asrc, const float* __restrict__ adst,
    float* __restrict__ hlin, float* __restrict__ hs, float* __restrict__ hd, int N) {
    const int wid = threadIdx.x >> 6, lane = threadIdx.x & 63;
    const int n = blockIdx.x * 4 + wid;
    if (n >= N) return;
    float x0 = x[(size_t)n * 3], x1 = x[(size_t)n * 3 + 1], x2 = x[(size_t)n * 3 + 2];
    const int c0 = lane, c1 = lane + 64;
    float h0 = x0 * W0[c0] + x1 * W0[128 + c0] + x2 * W0[256 + c0];
    float h1 = x0 * W0[c1] + x1 * W0[128 + c1] + x2 * W0[256 + c1];
    hlin[(size_t)n * 128 + c0] = h0;
    hlin[(size_t)n * 128 + c1] = h1;
    float sp = h0 * asrc[c0] + h1 * asrc[c1];
    float dp = h0 * adst[c0] + h1 * adst[c1];
    for (int o = 32; o; o >>= 1) { sp += __shfl_down(sp, o); dp += __shfl_down(dp, o); }
    if (lane == 0) { hs[n] = sp; hd[n] = dp; }
}

__global__ __launch_bounds__(256) void k_lin(
    const float* __restrict__ xin, const float* __restrict__ W,
    const float* __restrict__ asrc, const float* __restrict__ adst,
    float* __restrict__ hlin, float* __restrict__ hs, float* __restrict__ hd, int N) {
    __shared__ float xl[4][128];
    const int wid = threadIdx.x >> 6, lane = threadIdx.x & 63;
    const int n = blockIdx.x * 4 + wid;
    if (n < N) {
        xl[wid][lane]      = xin[(size_t)n * 128 + lane];
        xl[wid][lane + 64] = xin[(size_t)n * 128 + lane + 64];
    }
    __syncthreads();
    if (n >= N) return;
    const int c0 = lane, c1 = lane + 64;
    float h0 = 0.f, h1 = 0.f;
    #pragma unroll 4
    for (int k = 0; k < 128; ++k) {
        float xv = xl[wid][k];
        h0 += xv * W[k * 128 + c0];
        h1 += xv * W[k * 128 + c1];
    }
    hlin[(size_t)n * 128 + c0] = h0;
    hlin[(size_t)n * 128 + c1] = h1;
    float sp = h0 * asrc[c0] + h1 * asrc[c1];
    float dp = h0 * adst[c0] + h1 * adst[c1];
    for (int o = 32; o; o >>= 1) { sp += __shfl_down(sp, o); dp += __shfl_down(dp, o); }
    if (lane == 0) { hs[n] = sp; hd[n] = dp; }
}

// ---------------- GAT aggregation: online segment softmax + weighted sum ---
__global__ __launch_bounds__(256) void k_aggr(
    const float* __restrict__ hlin, const float* __restrict__ hs, const float* __restrict__ hd,
    const int* __restrict__ indptr, const int* __restrict__ colS,
    const float* __restrict__ b, float* __restrict__ xout, int N) {
    const int wid = threadIdx.x >> 6, lane = threadIdx.x & 63;
    const int n = blockIdx.x * 4 + wid;
    if (n >= N) return;
    const int s = indptr[n], epos = indptr[n + 1];
    const float hdv = hd[n];
    const int c0 = lane, c1 = lane + 64;
    float m = -1e30f, d = 0.f, a0 = 0.f, a1 = 0.f;
    for (int idx = s; idx < epos; ++idx) {
        int col = colS[idx];
        float e = hs[col] + hdv;
        e = (e > 0.f) ? e : 0.2f * e;
        const float* hr = hlin + (size_t)col * 128;
        float v0 = hr[c0], v1 = hr[c1];
        if (e > m) {
            float sc = __expf(m - e);
            a0 = a0 * sc + v0;
            a1 = a1 * sc + v1;
            d  = d * sc + 1.f;
            m  = e;
        } else {
            float w = __expf(e - m);
            a0 += w * v0;
            a1 += w * v1;
            d  += w;
        }
    }
    float inv = 1.f / (d + 1e-16f);
    float r0 = a0 * inv + b[c0];
    float r1 = a1 * inv + b[c1];
    xout[(size_t)n * 128 + c0] = fmaxf(r0, 0.f);
    xout[(size_t)n * 128 + c1] = fmaxf(r1, 0.f);
}

// ---------------- LSTM weight transform (reads RAW inputs via flags) -------
// Wt[d][k][j]: k<128 -> Wih_d[j][k]; else Whh_d[j][k-128].  bsum[d][j]=bih+bhh.
__global__ void k_wtrans2(const void* Wihf, const void* Whhf,
                          const void* Wihb, const void* Whhb,
                          const void* bihf, const void* bhhf,
                          const void* bihb, const void* bhhb,
                          const int* __restrict__ flags,
                          float* __restrict__ Wt, float* __restrict__ bsum) {
    int idx = blockIdx.x * blockDim.x + threadIdx.x;
    const int tot = 2 * 320 * 768;
    if (idx < tot) {
        int d = idx / (320 * 768);
        int r = idx % (320 * 768);
        int k = r / 768, j = r % 768;
        float v;
        if (k < 128)
            v = d ? rdx(Wihb, (size_t)j * 128 + k, flags[14])
                  : rdx(Wihf, (size_t)j * 128 + k, flags[10]);
        else
            v = d ? rdx(Whhb, (size_t)j * 192 + (k - 128), flags[15])
                  : rdx(Whhf, (size_t)j * 192 + (k - 128), flags[11]);
        Wt[idx] = v;
    }
    if (idx < 2 * 768) {
        int d = idx / 768, j = idx % 768;
        bsum[idx] = d ? rdx(bihb, j, flags[16]) + rdx(bhhb, j, flags[17])
                      : rdx(bihf, j, flags[12]) + rdx(bhhf, j, flags[13]);
    }
}

// ---------------- fused bidirectional LSTM (all 3 steps on-chip) -----------
// Grid (ceil(N/16), 2); block = 192 threads. Thread m owns hidden unit m for
// all 16 rows and all 4 gates (64 f32 acc, c[16] in regs across steps).
// A-tile [16][320] in LDS: x staged per step, h written back in epilogue.
__global__ __launch_bounds__(192) void k_lstm_fused(
    const float* __restrict__ xs,      // [3][N][128]
    const float* __restrict__ Wt,      // [2][320][768] K-major
    const float* __restrict__ bsum,    // [2][768]
    const float* __restrict__ attW,    // [384]
    float* __restrict__ scoreP,        // [2][3][N]
    int N) {
    __shared__ __align__(16) float AS[16][320];
    __shared__ float scW[3][16];
    const int t = threadIdx.x;
    const int m = t;                    // hidden unit
    const int w = t >> 6, lane = t & 63;
    const int dir = blockIdx.y;
    const int n0 = blockIdx.x * 16;
    const float* Wd = Wt + (size_t)dir * 320 * 768;
    const float aw = attW[dir * 192 + m];
    const float bI = bsum[dir * 768 + m];
    const float bF = bsum[dir * 768 + 192 + m];
    const float bG = bsum[dir * 768 + 384 + m];
    const float bO = bsum[dir * 768 + 576 + m];
    float c[16];
    #pragma unroll
    for (int r = 0; r < 16; ++r) c[r] = 0.f;

    for (int s = 0; s < 3; ++s) {
        const int l = dir ? (2 - s) : s;
        const int Keff = s ? 320 : 128;
        // stage x_l tile (h region AS[.][128..319] holds prev h when s>0)
        {
            const float* xsrc = xs + ((size_t)l * N + n0) * 128;
            int lim = (N - n0) * 128;
            if (lim > 2048) lim = 2048;
            for (int i = t; i < 2048; i += 192)
                AS[i >> 7][i & 127] = (i < lim) ? xsrc[i] : 0.f;
        }
        __syncthreads();

        float gI[16], gF[16], gG[16], gO[16];
        #pragma unroll
        for (int r = 0; r < 16; ++r) { gI[r] = bI; gF[r] = bF; gG[r] = bG; gO[r] = bO; }
        for (int k = 0; k < Keff; k += 4) {
            const float* wp = Wd + (size_t)k * 768 + m;
            float wi0 = wp[0],        wi1 = wp[768],        wi2 = wp[1536],        wi3 = wp[2304];
            float wf0 = wp[192],      wf1 = wp[960],        wf2 = wp[1728],        wf3 = wp[2496];
            float wg0 = wp[384],      wg1 = wp[1152],       wg2 = wp[1920],        wg3 = wp[2688];
            float wo0 = wp[576],      wo1 = wp[1344],       wo2 = wp[2112],        wo3 = wp[2880];
            #pragma unroll
            for (int r = 0; r < 16; ++r) {
                float4 a = *(const float4*)&AS[r][k];
                gI[r] += a.x * wi0 + a.y * wi1 + a.z * wi2 + a.w * wi3;
                gF[r] += a.x * wf0 + a.y * wf1 + a.z * wf2 + a.w * wf3;
                gG[r] += a.x * wg0 + a.y * wg1 + a.z * wg2 + a.w * wg3;
                gO[r] += a.x * wo0 + a.y * wo1 + a.z * wo2 + a.w * wo3;
            }
        }
        __syncthreads();   // all A reads done; safe to write h into AS
        #pragma unroll
        for (int r = 0; r < 16; ++r) {
            float ig = 1.f / (1.f + __expf(-gI[r]));
            float fg = 1.f / (1.f + __expf(-gF[r]));
            float gt = tanhf(gG[r]);
            float og = 1.f / (1.f + __expf(-gO[r]));
            float cn = fg * c[r] + ig * gt;
            c[r] = cn;
            float hh = og * tanhf(cn);
            AS[r][128 + m] = hh;
            float v = hh * aw;
            #pragma unroll
            for (int o = 32; o; o >>= 1) v += __shfl_xor(v, o);
            if (lane == 0) scW[w][r] = v;
        }
        __syncthreads();
        if (t < 16 && n0 + t < N)
            scoreP[((size_t)dir * 3 + l) * N + n0 + t] = scW[0][t] + scW[1][t] + scW[2][t];
        __syncthreads();   // scW reads done before next step overwrites
    }
}

// ---------------- JK finish: layer softmax + weighted sum ------------------
__global__ __launch_bounds__(256) void k_jkfin(
    const float* __restrict__ xs, const float* __restrict__ scoreP,
    float* __restrict__ hJK, int N) {
    const int nl = threadIdx.x >> 7;           // 2 nodes per block
    const int ch = threadIdx.x & 127;
    const int n = blockIdx.x * 2 + nl;
    if (n >= N) return;
    float s0 = scoreP[n]                  + scoreP[(size_t)3 * N + n];
    float s1 = scoreP[(size_t)N + n]      + scoreP[(size_t)4 * N + n];
    float s2 = scoreP[(size_t)2 * N + n]  + scoreP[(size_t)5 * N + n];
    float m = fmaxf(s0, fmaxf(s1, s2));
    float e0 = __expf(s0 - m), e1 = __expf(s1 - m), e2 = __expf(s2 - m);
    float inv = 1.f / (e0 + e1 + e2);
    e0 *= inv; e1 *= inv; e2 *= inv;
    const size_t nb = (size_t)n * 128 + ch;
    const size_t L1o = (size_t)N * 128, L2o = 2 * (size_t)N * 128;
    hJK[nb] = e0 * xs[nb] + e1 * xs[L1o + nb] + e2 * xs[L2o + nb];
}

// ---------------- node classifier ------------------------------------------
__global__ __launch_bounds__(256) void k_nodemlp(
    const float* __restrict__ hJK, const float* __restrict__ W1, const float* __restrict__ b1,
    const float* __restrict__ W2, const float* __restrict__ b2,
    float* __restrict__ out, int N) {
    __shared__ float xl[4][128];
    const int wid = threadIdx.x >> 6, lane = threadIdx.x & 63;
    const int n = blockIdx.x * 4 + wid;
    if (n < N) {
        xl[wid][lane]      = hJK[(size_t)n * 128 + lane];
        xl[wid][lane + 64] = hJK[(size_t)n * 128 + lane + 64];
    }
    __syncthreads();
    if (n >= N) return;
    const int c0 = lane, c1 = lane + 64;
    float h0 = 0.f, h1 = 0.f;
    #pragma unroll 4
    for (int k = 0; k < 128; ++k) {
        float xv = xl[wid][k];
        h0 += xv * W1[k * 128 + c0];
        h1 += xv * W1[k * 128 + c1];
    }
    h0 = fmaxf(h0 + b1[c0], 0.f);
    h1 = fmaxf(h1 + b1[c1], 0.f);
    float p0 = h0 * W2[c0 * 2 + 0] + h1 * W2[c1 * 2 + 0];
    float p1 = h0 * W2[c0 * 2 + 1] + h1 * W2[c1 * 2 + 1];
    for (int o = 32; o; o >>= 1) { p0 += __shfl_down(p0, o); p1 += __shfl_down(p1, o); }
    if (lane == 0) {
        float l0 = p0 + b2[0], l1 = p1 + b2[1];
        float mm = fmaxf(l0, l1);
        float e0 = __expf(l0 - mm), e1 = __expf(l1 - mm);
        float inv = 1.f / (e0 + e1);
        out[2 * (size_t)n]     = e0 * inv;
        out[2 * (size_t)n + 1] = e1 * inv;
    }
}

// ---------------- edge classifier: 8 edges per wave ------------------------
__global__ __launch_bounds__(256) void k_edgemlp(
    const float* __restrict__ hJK, const int* __restrict__ row, const int* __restrict__ col,
    const float* __restrict__ W1, const float* __restrict__ b1,
    const float* __restrict__ W2, const float* __restrict__ b2,
    float* __restrict__ out, int E, int N) {
    __shared__ float rep[4][8][256];
    const int wid = threadIdx.x >> 6, lane = threadIdx.x & 63;
    const long long base = ((long long)blockIdx.x * 4 + wid) * 8;
    for (int e = 0; e < 8; ++e) {
        long long ei = base + e;
        int r = 0, cc = 0;
        if (ei < E) { r = row[ei]; cc = col[ei]; }
        const float* pr = hJK + (size_t)r * 128;
        const float* pc = hJK + (size_t)cc * 128;
        #pragma unroll
        for (int j = 0; j < 4; ++j) {
            int idx = lane + 64 * j;
            rep[wid][e][idx] = (idx < 128) ? pr[idx] : pc[idx - 128];
        }
    }
    __syncthreads();
    const int c0 = lane, c1 = lane + 64;
    float acc0[8], acc1[8];
    #pragma unroll
    for (int e = 0; e < 8; ++e) { acc0[e] = 0.f; acc1[e] = 0.f; }
    #pragma unroll 2
    for (int k = 0; k < 256; k += 4) {
        float w00 = W1[(k + 0) * 128 + c0], w01 = W1[(k + 0) * 128 + c1];
        float w10 = W1[(k + 1) * 128 + c0], w11 = W1[(k + 1) * 128 + c1];
        float w20 = W1[(k + 2) * 128 + c0], w21 = W1[(k + 2) * 128 + c1];
        float w30 = W1[(k + 3) * 128 + c0], w31 = W1[(k + 3) * 128 + c1];
        #pragma unroll
        for (int e = 0; e < 8; ++e) {
            float4 v = *(const float4*)&rep[wid][e][k];
            acc0[e] += v.x * w00 + v.y * w10 + v.z * w20 + v.w * w30;
            acc1[e] += v.x * w01 + v.y * w11 + v.z * w21 + v.w * w31;
        }
    }
    float p0[8], p1[8];
    #pragma unroll
    for (int e = 0; e < 8; ++e) {
        float h0 = fmaxf(acc0[e] + b1[c0], 0.f);
        float h1 = fmaxf(acc1[e] + b1[c1], 0.f);
        p0[e] = h0 * W2[c0 * 2 + 0] + h1 * W2[c1 * 2 + 0];
        p1[e] = h0 * W2[c0 * 2 + 1] + h1 * W2[c1 * 2 + 1];
    }
    #pragma unroll
    for (int st = 0; st < 6; ++st) {
        int o = 32 >> st;
        #pragma unroll
        for (int e = 0; e < 8; ++e) {
            p0[e] += __shfl_xor(p0[e], o);
            p1[e] += __shfl_xor(p1[e], o);
        }
    }
    float l0 = 0.f, l1 = 0.f;
    #pragma unroll
    for (int e = 0; e < 8; ++e)
        if (lane == e) { l0 = p0[e]; l1 = p1[e]; }
    if (lane < 8) {
        long long ei = base + lane;
        if (ei < E) {
            l0 += b2[0]; l1 += b2[1];
            float mm = fmaxf(l0, l1);
            float e0 = __expf(l0 - mm), e1 = __expf(l1 - mm);
            float inv = 1.f / (e0 + e1);
            out[2 * (long long)N + 2 * ei]     = e0 * inv;
            out[2 * (long long)N + 2 * ei + 1] = e1 * inv;
        }
    }
}

// ---------------------------------------------------------------------------
extern "C" void kernel_launch(void* const* d_in, const int* in_sizes, int n_in,
                              void* d_out, int out_size, void* d_ws, size_t ws_size,
                              hipStream_t stream) {
    if (n_in < NIN) return;
    const int N = in_sizes[0] / 3;
    const int E = in_sizes[1] / 2;

    char* ws = (char*)d_ws;
    size_t off = 0;
    auto alloc = [&](size_t bytes) -> char* {
        char* p = ws + off;
        off = (off + bytes + 255) & ~(size_t)255;
        return p;
    };
    int* flags = (int*)alloc(32 * sizeof(int));
    float* canon[NIN];
    for (int i = 0; i < NIN; ++i) canon[i] = nullptr;
    for (int i = 0; i < NIN; ++i) {
        if (i == 1 || (i >= 10 && i <= 17)) continue;   // LSTM weights read raw
        canon[i] = (float*)alloc((size_t)in_sizes[i] * 4);
    }
    int* row32  = (int*)alloc((size_t)E * 4);
    int* col32  = (int*)alloc((size_t)E * 4);
    int* indptr = (int*)alloc((size_t)(N + 1) * 4);
    int* cnt    = (int*)alloc((size_t)N * 4);
    int* colS   = (int*)alloc((size_t)E * 4);
    float* hs   = (float*)alloc((size_t)N * 4);
    float* hd   = (float*)alloc((size_t)N * 4);
    float* hlin = (float*)alloc((size_t)N * 128 * 4);   // reused as hJK later
    float* xs   = (float*)alloc((size_t)3 * N * 128 * 4);
    float* Wt   = (float*)alloc((size_t)2 * 320 * 768 * 4);
    float* bsum = (float*)alloc((size_t)2 * 768 * 4);
    // scoreP [2][3][N] aliases colS (dead after last k_aggr) when it fits
    float* scoreP;
    if ((size_t)E >= (size_t)6 * N) scoreP = (float*)colS;
    else                            scoreP = (float*)alloc((size_t)6 * N * 4);
    if (off > ws_size) return;

    InPtrs ip;
    for (int i = 0; i < NIN; ++i) { ip.p[i] = d_in[i]; ip.n[i] = in_sizes[i]; }

    k_sniff<<<NIN, 256, 0, stream>>>(ip, flags);
    for (int i = 0; i < NIN; ++i) {
        if (i == 1 || (i >= 10 && i <= 17)) continue;
        int n = in_sizes[i];
        k_convf<<<(n + 255) / 256, 256, 0, stream>>>(d_in[i], canon[i], n, flags, i);
    }
    k_conve<<<(E + 255) / 256, 256, 0, stream>>>(d_in[1], row32, col32, E, flags);
    k_wtrans2<<<(2 * 320 * 768 + 255) / 256, 256, 0, stream>>>(
        d_in[10], d_in[11], d_in[14], d_in[15],
        d_in[12], d_in[13], d_in[16], d_in[17], flags, Wt, bsum);

    // CSR by row (shared across all 3 GAT layers)
    k_zeroi<<<(N + 255) / 256, 256, 0, stream>>>(cnt, N);
    k_hist<<<(E + 255) / 256, 256, 0, stream>>>(row32, cnt, E);
    k_scan<<<1, 1024, 0, stream>>>(cnt, indptr, N);
    k_zeroi<<<(N + 255) / 256, 256, 0, stream>>>(cnt, N);
    k_fill<<<(E + 255) / 256, 256, 0, stream>>>(row32, col32, indptr, cnt, colS, E);

    // GAT layer 0 (in=3)
    k_lin0<<<(N + 3) / 4, 256, 0, stream>>>(canon[0], canon[2], canon[4], canon[5],
                                            hlin, hs, hd, N);
    k_aggr<<<(N + 3) / 4, 256, 0, stream>>>(hlin, hs, hd, indptr, colS, canon[3], xs, N);
    // GAT layers 1..2 (in=128)
    for (int l = 1; l < 3; ++l) {
        const float* W  = canon[6] + (size_t)(l - 1) * 128 * 128;
        const float* bb = canon[7] + (size_t)(l - 1) * 128;
        const float* as = canon[8] + (size_t)(l - 1) * 128;
        const float* ad = canon[9] + (size_t)(l - 1) * 128;
        k_lin<<<(N + 3) / 4, 256, 0, stream>>>(xs + (size_t)(l - 1) * N * 128, W, as, ad,
                                               hlin, hs, hd, N);
        k_aggr<<<(N + 3) / 4, 256, 0, stream>>>(hlin, hs, hd, indptr, colS, bb,
                                                xs + (size_t)l * N * 128, N);
    }

    // fused bidirectional LSTM over layer axis + JK attention finish
    dim3 lgrid((N + 15) / 16, 2);
    k_lstm_fused<<<lgrid, 192, 0, stream>>>(xs, Wt, bsum, canon[18], scoreP, N);
    k_jkfin<<<(N + 1) / 2, 256, 0, stream>>>(xs, scoreP, hlin, N);

    float* out = (float*)d_out;
    k_nodemlp<<<(N + 3) / 4, 256, 0, stream>>>(hlin, canon[20], canon[21], canon[22],
                                               canon[23], out, N);
    k_edgemlp<<<(E + 31) / 32, 256, 0, stream>>>(hlin, row32, col32, canon[24], canon[25],
                                                 canon[26], canon[27], out, E, N);
}

// Round 4
// 2265.211 us; speedup vs baseline: 15.3346x; 2.0472x over previous
//
#include <hip/hip_runtime.h>
#include <cstdint>
#include <cstddef>

// ---------------------------------------------------------------------------
// ParityGameGATNetwork: 3x GATConv -> JK bidirectional LSTM -> node/edge MLPs
// Round 4: LSTM GEMM moved to bf16 MFMA (16x16x32). Weights pre-packed into
// exact fragment order; A-tile + h-state in LDS; c-state in registers; cell
// epilogue pure-register (gate cols of one unit live in one wave/lane).
// ---------------------------------------------------------------------------

#define NIN 28

struct InPtrs { const void* p[NIN]; int n[NIN]; };

typedef short s16x4 __attribute__((ext_vector_type(4)));
typedef short s16x8 __attribute__((ext_vector_type(8)));
typedef float f32x4 __attribute__((ext_vector_type(4)));

__device__ __forceinline__ float bf2f(unsigned short v) {
    unsigned int u = ((unsigned int)v) << 16;
    return __uint_as_float(u);
}

__device__ __forceinline__ unsigned short f2bf(float x) {
    unsigned int u = __float_as_uint(x);
    unsigned int r = u + 0x7fffu + ((u >> 16) & 1u);
    return (unsigned short)(r >> 16);
}

__device__ __forceinline__ float rdx(const void* p, size_t i, int isf32) {
    return isf32 ? ((const float*)p)[i] : bf2f(((const unsigned short*)p)[i]);
}

// ---------------- dtype sniffing -------------------------------------------
__global__ void k_sniff(InPtrs in, int* flags) {
    int ai = blockIdx.x;
    if (ai >= NIN) return;
    __shared__ int cnt;
    if (threadIdx.x == 0) cnt = 0;
    __syncthreads();
    if (ai == 1) {
        const int* w = (const int*)in.p[1];
        int nw = in.n[1] < 512 ? in.n[1] : 512;
        int local = 0;
        for (int i = threadIdx.x; i < nw; i += blockDim.x)
            if ((i & 1) && w[i] != 0) local++;
        atomicAdd(&cnt, local);
        __syncthreads();
        if (threadIdx.x == 0) flags[1] = (cnt < 4) ? 1 : 0;
        return;
    }
    const unsigned short* u = (const unsigned short*)in.p[ai];
    int ns = in.n[ai] < 256 ? in.n[ai] : 256;
    int local = 0;
    for (int i = threadIdx.x; i < ns; i += blockDim.x) {
        if (i & 1) continue;
        unsigned short v = u[i];
        int e = (v >> 7) & 0xff;
        if ((v & 0x7fff) != 0 && (e < 100 || e > 154)) local++;
    }
    atomicAdd(&cnt, local);
    __syncthreads();
    if (threadIdx.x == 0) flags[ai] = (cnt * 4 >= ns) ? 1 : 0;
}

__global__ void k_convf(const void* src, float* dst, int n, const int* flags, int ai) {
    int i = blockIdx.x * blockDim.x + threadIdx.x;
    if (i >= n) return;
    if (flags[ai]) dst[i] = ((const float*)src)[i];
    else           dst[i] = bf2f(((const unsigned short*)src)[i]);
}

__global__ void k_conve(const void* src, int* row, int* col, int E, const int* flags) {
    int i = blockIdx.x * blockDim.x + threadIdx.x;
    if (i >= E) return;
    if (flags[1]) {
        const long long* s = (const long long*)src;
        row[i] = (int)s[i];
        col[i] = (int)s[(size_t)E + i];
    } else {
        const int* s = (const int*)src;
        row[i] = s[i];
        col[i] = s[(size_t)E + i];
    }
}

// ---------------- CSR build ------------------------------------------------
__global__ void k_zeroi(int* p, int n) {
    int i = blockIdx.x * blockDim.x + threadIdx.x;
    if (i < n) p[i] = 0;
}

__global__ void k_hist(const int* __restrict__ row, int* __restrict__ cnt, int E) {
    int i = blockIdx.x * blockDim.x + threadIdx.x;
    if (i < E) atomicAdd(&cnt[row[i]], 1);
}

__global__ void k_scan(const int* __restrict__ deg, int* __restrict__ indptr, int N) {
    __shared__ int buf[1024];
    __shared__ int carryS;
    const int t = threadIdx.x;
    if (t == 0) carryS = 0;
    __syncthreads();
    for (int base = 0; base < N; base += 1024) {
        int v = (base + t < N) ? deg[base + t] : 0;
        buf[t] = v;
        __syncthreads();
        for (int ofs = 1; ofs < 1024; ofs <<= 1) {
            int add = (t >= ofs) ? buf[t - ofs] : 0;
            __syncthreads();
            buf[t] += add;
            __syncthreads();
        }
        int carry = carryS;
        if (base + t < N) indptr[base + t] = carry + buf[t] - v;
        __syncthreads();
        if (t == 1023) carryS = carry + buf[1023];
        __syncthreads();
    }
    if (t == 0) indptr[N] = carryS;
}

__global__ void k_fill(const int* __restrict__ row, const int* __restrict__ col,
                       const int* __restrict__ indptr, int* __restrict__ cur,
                       int* __restrict__ colS, int E) {
    int i = blockIdx.x * blockDim.x + threadIdx.x;
    if (i >= E) return;
    int r = row[i];
    int p = indptr[r] + atomicAdd(&cur[r], 1);
    colS[p] = col[i];
}

// ---------------- GAT linear (h = x @ W) + a_src/a_dst epilogue ------------
__global__ __launch_bounds__(256) void k_lin0(
    const float* __restrict__ x, const float* __restrict__ W0,
    const float* __restrict__ asrc, const float* __restrict__ adst,
    float* __restrict__ hlin, float* __restrict__ hs, float* __restrict__ hd, int N) {
    const int wid = threadIdx.x >> 6, lane = threadIdx.x & 63;
    const int n = blockIdx.x * 4 + wid;
    if (n >= N) return;
    float x0 = x[(size_t)n * 3], x1 = x[(size_t)n * 3 + 1], x2 = x[(size_t)n * 3 + 2];
    const int c0 = lane, c1 = lane + 64;
    float h0 = x0 * W0[c0] + x1 * W0[128 + c0] + x2 * W0[256 + c0];
    float h1 = x0 * W0[c1] + x1 * W0[128 + c1] + x2 * W0[256 + c1];
    hlin[(size_t)n * 128 + c0] = h0;
    hlin[(size_t)n * 128 + c1] = h1;
    float sp = h0 * asrc[c0] + h1 * asrc[c1];
    float dp = h0 * adst[c0] + h1 * adst[c1];
    for (int o = 32; o; o >>= 1) { sp += __shfl_down(sp, o); dp += __shfl_down(dp, o); }
    if (lane == 0) { hs[n] = sp; hd[n] = dp; }
}

__global__ __launch_bounds__(256) void k_lin(
    const float* __restrict__ xin, const float* __restrict__ W,
    const float* __restrict__ asrc, const float* __restrict__ adst,
    float* __restrict__ hlin, float* __restrict__ hs, float* __restrict__ hd, int N) {
    __shared__ float xl[4][128];
    const int wid = threadIdx.x >> 6, lane = threadIdx.x & 63;
    const int n = blockIdx.x * 4 + wid;
    if (n < N) {
        xl[wid][lane]      = xin[(size_t)n * 128 + lane];
        xl[wid][lane + 64] = xin[(size_t)n * 128 + lane + 64];
    }
    __syncthreads();
    if (n >= N) return;
    const int c0 = lane, c1 = lane + 64;
    float h0 = 0.f, h1 = 0.f;
    #pragma unroll 4
    for (int k = 0; k < 128; ++k) {
        float xv = xl[wid][k];
        h0 += xv * W[k * 128 + c0];
        h1 += xv * W[k * 128 + c1];
    }
    hlin[(size_t)n * 128 + c0] = h0;
    hlin[(size_t)n * 128 + c1] = h1;
    float sp = h0 * asrc[c0] + h1 * asrc[c1];
    float dp = h0 * adst[c0] + h1 * adst[c1];
    for (int o = 32; o; o >>= 1) { sp += __shfl_down(sp, o); dp += __shfl_down(dp, o); }
    if (lane == 0) { hs[n] = sp; hd[n] = dp; }
}

// ---------------- GAT aggregation: online segment softmax + weighted sum ---
__global__ __launch_bounds__(256) void k_aggr(
    const float* __restrict__ hlin, const float* __restrict__ hs, const float* __restrict__ hd,
    const int* __restrict__ indptr, const int* __restrict__ colS,
    const float* __restrict__ b, float* __restrict__ xout, int N) {
    const int wid = threadIdx.x >> 6, lane = threadIdx.x & 63;
    const int n = blockIdx.x * 4 + wid;
    if (n >= N) return;
    const int s = indptr[n], epos = indptr[n + 1];
    const float hdv = hd[n];
    const int c0 = lane, c1 = lane + 64;
    float m = -1e30f, d = 0.f, a0 = 0.f, a1 = 0.f;
    for (int idx = s; idx < epos; ++idx) {
        int col = colS[idx];
        float e = hs[col] + hdv;
        e = (e > 0.f) ? e : 0.2f * e;
        const float* hr = hlin + (size_t)col * 128;
        float v0 = hr[c0], v1 = hr[c1];
        if (e > m) {
            float sc = __expf(m - e);
            a0 = a0 * sc + v0;
            a1 = a1 * sc + v1;
            d  = d * sc + 1.f;
            m  = e;
        } else {
            float w = __expf(e - m);
            a0 += w * v0;
            a1 += w * v1;
            d  += w;
        }
    }
    float inv = 1.f / (d + 1e-16f);
    float r0 = a0 * inv + b[c0];
    float r1 = a1 * inv + b[c1];
    xout[(size_t)n * 128 + c0] = fmaxf(r0, 0.f);
    xout[(size_t)n * 128 + c1] = fmaxf(r1, 0.f);
}

// ---------------- LSTM weight pack into MFMA fragment order ----------------
// Bpack[dir][kb][frag][lane][j] (bf16), value = Wt[dir][k][col] with
// k = kb*32 + (j>>2)*16 + (lane>>4)*4 + (j&3), col = frag*16 + (lane&15).
// Wt[k][col]: k<128 -> Wih[col][k], else Whh[col][k-128].
__global__ void k_wpack(const void* Wihf, const void* Whhf,
                        const void* Wihb, const void* Whhb,
                        const void* bihf, const void* bhhf,
                        const void* bihb, const void* bhhb,
                        const int* __restrict__ flags,
                        unsigned short* __restrict__ Bpack, float* __restrict__ bsum) {
    int idx = blockIdx.x * blockDim.x + threadIdx.x;
    const int TOT = 2 * 10 * 48 * 512;
    if (idx < TOT) {
        int dir = idx / (10 * 48 * 512);
        int r   = idx % (10 * 48 * 512);
        int kb  = r / (48 * 512);
        int r2  = r % (48 * 512);
        int f   = r2 / 512;
        int q   = r2 % 512;
        int lane = q >> 3, j = q & 7;
        int k   = kb * 32 + ((j >> 2) * 16) + ((lane >> 4) * 4) + (j & 3);
        int col = f * 16 + (lane & 15);
        float v;
        if (k < 128)
            v = dir ? rdx(Wihb, (size_t)col * 128 + k, flags[14])
                    : rdx(Wihf, (size_t)col * 128 + k, flags[10]);
        else
            v = dir ? rdx(Whhb, (size_t)col * 192 + (k - 128), flags[15])
                    : rdx(Whhf, (size_t)col * 192 + (k - 128), flags[11]);
        Bpack[idx] = f2bf(v);
    }
    if (idx < 2 * 768) {
        int d = idx / 768, j = idx % 768;
        bsum[idx] = d ? rdx(bihb, j, flags[16]) + rdx(bhhb, j, flags[17])
                      : rdx(bihf, j, flags[12]) + rdx(bhhf, j, flags[13]);
    }
}

// ---------------- fused bidirectional LSTM, MFMA GEMM ----------------------
// Grid (ceil(N/32), 2); 256 threads = 4 waves. Per step: C[32][768] =
// A[32][Keff] * B[Keff][768] via 16x16x32 bf16 MFMA. Wave w owns col-frags
// {w, w+4, ..., w+44} so gates i/f/g/o of unit m=16*(w+4a)+(lane&15) are all
// in this wave at local frags a, 3+a, 6+a, 9+a. c-state in regs, h -> LDS.
__global__ __launch_bounds__(256, 2) void k_lstm_mfma(
    const float* __restrict__ xs,            // [3][N][128] f32
    const unsigned short* __restrict__ Bpack,// [2][10][48][512] bf16
    const float* __restrict__ bsum,          // [2][768]
    const float* __restrict__ attW,          // [384]
    float* __restrict__ scoreP,              // [2][3][N]
    int N) {
    __shared__ unsigned short AS[32][328];   // bf16 A-tile: x in [0,128), h in [128,320)
    __shared__ float scoreS[32];
    const int t = threadIdx.x;
    const int w = t >> 6, lane = t & 63;
    const int dir = blockIdx.y;
    const int n0 = blockIdx.x * 32;
    const int ccol = lane & 15;              // C col & A row within tile
    const int lrow = (lane >> 4) * 4;        // C row base
    const int akl = (lane >> 4) * 4;         // A/B k sub-offset

    float bI[3], bF[3], bG[3], bO[3], awt[3];
    #pragma unroll
    for (int a = 0; a < 3; ++a) {
        int m = 16 * (w + 4 * a) + ccol;
        bI[a] = bsum[dir * 768 + m];
        bF[a] = bsum[dir * 768 + 192 + m];
        bG[a] = bsum[dir * 768 + 384 + m];
        bO[a] = bsum[dir * 768 + 576 + m];
        awt[a] = attW[dir * 192 + m];
    }
    float cst[24];
    #pragma unroll
    for (int i = 0; i < 24; ++i) cst[i] = 0.f;

    for (int s = 0; s < 3; ++s) {
        const int l = dir ? (2 - s) : s;
        // ---- stage x tile (f32 -> bf16), 4 cols per thread-item ----
        {
            const float* xsrc = xs + ((size_t)l * N + n0) * 128;
            #pragma unroll
            for (int it = 0; it < 4; ++it) {
                int i = t + it * 256;                // 0..1023
                int r = i >> 5, kq = (i & 31) * 4;
                float4 v = make_float4(0.f, 0.f, 0.f, 0.f);
                if (n0 + r < N) v = *(const float4*)&xsrc[(size_t)r * 128 + kq];
                ushort4 b4;
                b4.x = f2bf(v.x); b4.y = f2bf(v.y); b4.z = f2bf(v.z); b4.w = f2bf(v.w);
                *(ushort4*)&AS[r][kq] = b4;
            }
        }
        if (t < 32) scoreS[t] = 0.f;
        __syncthreads();

        // ---- MFMA GEMM over K ----
        const int KB = s ? 10 : 4;
        f32x4 acc0[12], acc1[12];
        #pragma unroll
        for (int f = 0; f < 12; ++f) {
            acc0[f] = (f32x4)(0.f);
            acc1[f] = (f32x4)(0.f);
        }
        for (int kb = 0; kb < KB; ++kb) {
            const int k0 = kb * 32 + akl;
            s16x4 a0lo = *(const s16x4*)&AS[ccol][k0];
            s16x4 a0hi = *(const s16x4*)&AS[ccol][k0 + 16];
            s16x4 a1lo = *(const s16x4*)&AS[16 + ccol][k0];
            s16x4 a1hi = *(const s16x4*)&AS[16 + ccol][k0 + 16];
            s16x8 a0 = __builtin_shufflevector(a0lo, a0hi, 0, 1, 2, 3, 4, 5, 6, 7);
            s16x8 a1 = __builtin_shufflevector(a1lo, a1hi, 0, 1, 2, 3, 4, 5, 6, 7);
            const unsigned short* bb =
                Bpack + (((size_t)dir * 10 + kb) * 48 + w) * 512 + lane * 8;
            #pragma unroll
            for (int f = 0; f < 12; ++f) {
                s16x8 b = *(const s16x8*)(bb + (size_t)f * 2048);
                acc0[f] = __builtin_amdgcn_mfma_f32_16x16x32_bf16(a0, b, acc0[f], 0, 0, 0);
                acc1[f] = __builtin_amdgcn_mfma_f32_16x16x32_bf16(a1, b, acc1[f], 0, 0, 0);
            }
        }
        __syncthreads();   // all A reads done before h overwrite

        // ---- cell epilogue (pure-register gates) ----
        float sprow[8];
        #pragma unroll
        for (int i = 0; i < 8; ++i) sprow[i] = 0.f;
        auto cell = [&](f32x4 (&accT)[12], int tile) {
            #pragma unroll
            for (int a = 0; a < 3; ++a) {
                #pragma unroll
                for (int reg = 0; reg < 4; ++reg) {
                    float gI = accT[a][reg]     + bI[a];
                    float gF = accT[3 + a][reg] + bF[a];
                    float gG = accT[6 + a][reg] + bG[a];
                    float gO = accT[9 + a][reg] + bO[a];
                    float ig = 1.f / (1.f + __expf(-gI));
                    float fg = 1.f / (1.f + __expf(-gF));
                    float gt = tanhf(gG);
                    float og = 1.f / (1.f + __expf(-gO));
                    int ci = tile * 12 + a * 4 + reg;
                    float cn = fg * cst[ci] + ig * gt;
                    cst[ci] = cn;
                    float hh = og * tanhf(cn);
                    int row = tile * 16 + lrow + reg;
                    int m = 16 * (w + 4 * a) + ccol;
                    AS[row][128 + m] = f2bf(hh);
                    sprow[tile * 4 + reg] += hh * awt[a];
                }
            }
        };
        cell(acc0, 0);
        cell(acc1, 1);
        #pragma unroll
        for (int o = 1; o < 16; o <<= 1) {
            #pragma unroll
            for (int i = 0; i < 8; ++i) sprow[i] += __shfl_xor(sprow[i], o);
        }
        if (ccol == 0) {
            #pragma unroll
            for (int i = 0; i < 8; ++i)
                atomicAdd(&scoreS[(i >> 2) * 16 + lrow + (i & 3)], sprow[i]);
        }
        __syncthreads();
        if (t < 32 && n0 + t < N)
            scoreP[(size_t)(dir * 3 + l) * N + n0 + t] = scoreS[t];
        // next stage overwrites AS[.][0..127] (disjoint from h) and each
        // thread re-zeroes its own scoreS slot after its global write.
    }
}

// ---------------- JK finish: layer softmax + weighted sum ------------------
__global__ __launch_bounds__(256) void k_jkfin(
    const float* __restrict__ xs, const float* __restrict__ scoreP,
    float* __restrict__ hJK, int N) {
    const int nl = threadIdx.x >> 7;           // 2 nodes per block
    const int ch = threadIdx.x & 127;
    const int n = blockIdx.x * 2 + nl;
    if (n >= N) return;
    float s0 = scoreP[n]                  + scoreP[(size_t)3 * N + n];
    float s1 = scoreP[(size_t)N + n]      + scoreP[(size_t)4 * N + n];
    float s2 = scoreP[(size_t)2 * N + n]  + scoreP[(size_t)5 * N + n];
    float m = fmaxf(s0, fmaxf(s1, s2));
    float e0 = __expf(s0 - m), e1 = __expf(s1 - m), e2 = __expf(s2 - m);
    float inv = 1.f / (e0 + e1 + e2);
    e0 *= inv; e1 *= inv; e2 *= inv;
    const size_t nb = (size_t)n * 128 + ch;
    const size_t L1o = (size_t)N * 128, L2o = 2 * (size_t)N * 128;
    hJK[nb] = e0 * xs[nb] + e1 * xs[L1o + nb] + e2 * xs[L2o + nb];
}

// ---------------- node classifier ------------------------------------------
__global__ __launch_bounds__(256) void k_nodemlp(
    const float* __restrict__ hJK, const float* __restrict__ W1, const float* __restrict__ b1,
    const float* __restrict__ W2, const float* __restrict__ b2,
    float* __restrict__ out, int N) {
    __shared__ float xl[4][128];
    const int wid = threadIdx.x >> 6, lane = threadIdx.x & 63;
    const int n = blockIdx.x * 4 + wid;
    if (n < N) {
        xl[wid][lane]      = hJK[(size_t)n * 128 + lane];
        xl[wid][lane + 64] = hJK[(size_t)n * 128 + lane + 64];
    }
    __syncthreads();
    if (n >= N) return;
    const int c0 = lane, c1 = lane + 64;
    float h0 = 0.f, h1 = 0.f;
    #pragma unroll 4
    for (int k = 0; k < 128; ++k) {
        float xv = xl[wid][k];
        h0 += xv * W1[k * 128 + c0];
        h1 += xv * W1[k * 128 + c1];
    }
    h0 = fmaxf(h0 + b1[c0], 0.f);
    h1 = fmaxf(h1 + b1[c1], 0.f);
    float p0 = h0 * W2[c0 * 2 + 0] + h1 * W2[c1 * 2 + 0];
    float p1 = h0 * W2[c0 * 2 + 1] + h1 * W2[c1 * 2 + 1];
    for (int o = 32; o; o >>= 1) { p0 += __shfl_down(p0, o); p1 += __shfl_down(p1, o); }
    if (lane == 0) {
        float l0 = p0 + b2[0], l1 = p1 + b2[1];
        float mm = fmaxf(l0, l1);
        float e0 = __expf(l0 - mm), e1 = __expf(l1 - mm);
        float inv = 1.f / (e0 + e1);
        out[2 * (size_t)n]     = e0 * inv;
        out[2 * (size_t)n + 1] = e1 * inv;
    }
}

// ---------------- edge classifier: 8 edges per wave ------------------------
__global__ __launch_bounds__(256) void k_edgemlp(
    const float* __restrict__ hJK, const int* __restrict__ row, const int* __restrict__ col,
    const float* __restrict__ W1, const float* __restrict__ b1,
    const float* __restrict__ W2, const float* __restrict__ b2,
    float* __restrict__ out, int E, int N) {
    __shared__ float rep[4][8][256];
    const int wid = threadIdx.x >> 6, lane = threadIdx.x & 63;
    const long long base = ((long long)blockIdx.x * 4 + wid) * 8;
    for (int e = 0; e < 8; ++e) {
        long long ei = base + e;
        int r = 0, cc = 0;
        if (ei < E) { r = row[ei]; cc = col[ei]; }
        const float* pr = hJK + (size_t)r * 128;
        const float* pc = hJK + (size_t)cc * 128;
        #pragma unroll
        for (int j = 0; j < 4; ++j) {
            int idx = lane + 64 * j;
            rep[wid][e][idx] = (idx < 128) ? pr[idx] : pc[idx - 128];
        }
    }
    __syncthreads();
    const int c0 = lane, c1 = lane + 64;
    float acc0[8], acc1[8];
    #pragma unroll
    for (int e = 0; e < 8; ++e) { acc0[e] = 0.f; acc1[e] = 0.f; }
    #pragma unroll 2
    for (int k = 0; k < 256; k += 4) {
        float w00 = W1[(k + 0) * 128 + c0], w01 = W1[(k + 0) * 128 + c1];
        float w10 = W1[(k + 1) * 128 + c0], w11 = W1[(k + 1) * 128 + c1];
        float w20 = W1[(k + 2) * 128 + c0], w21 = W1[(k + 2) * 128 + c1];
        float w30 = W1[(k + 3) * 128 + c0], w31 = W1[(k + 3) * 128 + c1];
        #pragma unroll
        for (int e = 0; e < 8; ++e) {
            float4 v = *(const float4*)&rep[wid][e][k];
            acc0[e] += v.x * w00 + v.y * w10 + v.z * w20 + v.w * w30;
            acc1[e] += v.x * w01 + v.y * w11 + v.z * w21 + v.w * w31;
        }
    }
    float p0[8], p1[8];
    #pragma unroll
    for (int e = 0; e < 8; ++e) {
        float h0 = fmaxf(acc0[e] + b1[c0], 0.f);
        float h1 = fmaxf(acc1[e] + b1[c1], 0.f);
        p0[e] = h0 * W2[c0 * 2 + 0] + h1 * W2[c1 * 2 + 0];
        p1[e] = h0 * W2[c0 * 2 + 1] + h1 * W2[c1 * 2 + 1];
    }
    #pragma unroll
    for (int st = 0; st < 6; ++st) {
        int o = 32 >> st;
        #pragma unroll
        for (int e = 0; e < 8; ++e) {
            p0[e] += __shfl_xor(p0[e], o);
            p1[e] += __shfl_xor(p1[e], o);
        }
    }
    float l0 = 0.f, l1 = 0.f;
    #pragma unroll
    for (int e = 0; e < 8; ++e)
        if (lane == e) { l0 = p0[e]; l1 = p1[e]; }
    if (lane < 8) {
        long long ei = base + lane;
        if (ei < E) {
            l0 += b2[0]; l1 += b2[1];
            float mm = fmaxf(l0, l1);
            float e0 = __expf(l0 - mm), e1 = __expf(l1 - mm);
            float inv = 1.f / (e0 + e1);
            out[2 * (long long)N + 2 * ei]     = e0 * inv;
            out[2 * (long long)N + 2 * ei + 1] = e1 * inv;
        }
    }
}

// ---------------------------------------------------------------------------
extern "C" void kernel_launch(void* const* d_in, const int* in_sizes, int n_in,
                              void* d_out, int out_size, void* d_ws, size_t ws_size,
                              hipStream_t stream) {
    if (n_in < NIN) return;
    const int N = in_sizes[0] / 3;
    const int E = in_sizes[1] / 2;

    char* ws = (char*)d_ws;
    size_t off = 0;
    auto alloc = [&](size_t bytes) -> char* {
        char* p = ws + off;
        off = (off + bytes + 255) & ~(size_t)255;
        return p;
    };
    int* flags = (int*)alloc(32 * sizeof(int));
    float* canon[NIN];
    for (int i = 0; i < NIN; ++i) canon[i] = nullptr;
    for (int i = 0; i < NIN; ++i) {
        if (i == 1 || (i >= 10 && i <= 17)) continue;   // LSTM weights read raw
        canon[i] = (float*)alloc((size_t)in_sizes[i] * 4);
    }
    int* row32  = (int*)alloc((size_t)E * 4);
    int* col32  = (int*)alloc((size_t)E * 4);
    int* indptr = (int*)alloc((size_t)(N + 1) * 4);
    int* cnt    = (int*)alloc((size_t)N * 4);
    int* colS   = (int*)alloc((size_t)E * 4);
    float* hs   = (float*)alloc((size_t)N * 4);
    float* hd   = (float*)alloc((size_t)N * 4);
    float* hlin = (float*)alloc((size_t)N * 128 * 4);   // reused as hJK later
    float* xs   = (float*)alloc((size_t)3 * N * 128 * 4);
    unsigned short* Bpack = (unsigned short*)alloc((size_t)2 * 10 * 48 * 512 * 2);
    float* bsum = (float*)alloc((size_t)2 * 768 * 4);
    // scoreP [2][3][N] aliases colS (dead after last k_aggr) when it fits
    float* scoreP;
    if ((size_t)E >= (size_t)6 * N) scoreP = (float*)colS;
    else                            scoreP = (float*)alloc((size_t)6 * N * 4);
    if (off > ws_size) return;

    InPtrs ip;
    for (int i = 0; i < NIN; ++i) { ip.p[i] = d_in[i]; ip.n[i] = in_sizes[i]; }

    k_sniff<<<NIN, 256, 0, stream>>>(ip, flags);
    for (int i = 0; i < NIN; ++i) {
        if (i == 1 || (i >= 10 && i <= 17)) continue;
        int n = in_sizes[i];
        k_convf<<<(n + 255) / 256, 256, 0, stream>>>(d_in[i], canon[i], n, flags, i);
    }
    k_conve<<<(E + 255) / 256, 256, 0, stream>>>(d_in[1], row32, col32, E, flags);
    k_wpack<<<(2 * 10 * 48 * 512 + 255) / 256, 256, 0, stream>>>(
        d_in[10], d_in[11], d_in[14], d_in[15],
        d_in[12], d_in[13], d_in[16], d_in[17], flags, Bpack, bsum);

    // CSR by row (shared across all 3 GAT layers)
    k_zeroi<<<(N + 255) / 256, 256, 0, stream>>>(cnt, N);
    k_hist<<<(E + 255) / 256, 256, 0, stream>>>(row32, cnt, E);
    k_scan<<<1, 1024, 0, stream>>>(cnt, indptr, N);
    k_zeroi<<<(N + 255) / 256, 256, 0, stream>>>(cnt, N);
    k_fill<<<(E + 255) / 256, 256, 0, stream>>>(row32, col32, indptr, cnt, colS, E);

    // GAT layer 0 (in=3)
    k_lin0<<<(N + 3) / 4, 256, 0, stream>>>(canon[0], canon[2], canon[4], canon[5],
                                            hlin, hs, hd, N);
    k_aggr<<<(N + 3) / 4, 256, 0, stream>>>(hlin, hs, hd, indptr, colS, canon[3], xs, N);
    // GAT layers 1..2 (in=128)
    for (int l = 1; l < 3; ++l) {
        const float* W  = canon[6] + (size_t)(l - 1) * 128 * 128;
        const float* bb = canon[7] + (size_t)(l - 1) * 128;
        const float* as = canon[8] + (size_t)(l - 1) * 128;
        const float* ad = canon[9] + (size_t)(l - 1) * 128;
        k_lin<<<(N + 3) / 4, 256, 0, stream>>>(xs + (size_t)(l - 1) * N * 128, W, as, ad,
                                               hlin, hs, hd, N);
        k_aggr<<<(N + 3) / 4, 256, 0, stream>>>(hlin, hs, hd, indptr, colS, bb,
                                                xs + (size_t)l * N * 128, N);
    }

    // fused bidirectional LSTM (MFMA) + JK attention finish
    dim3 lgrid((N + 31) / 32, 2);
    k_lstm_mfma<<<lgrid, 256, 0, stream>>>(xs, Bpack, bsum, canon[18], scoreP, N);
    k_jkfin<<<(N + 1) / 2, 256, 0, stream>>>(xs, scoreP, hlin, N);

    float* out = (float*)d_out;
    k_nodemlp<<<(N + 3) / 4, 256, 0, stream>>>(hlin, canon[20], canon[21], canon[22],
                                               canon[23], out, N);
    k_edgemlp<<<(E + 31) / 32, 256, 0, stream>>>(hlin, row32, col32, canon[24], canon[25],
                                                 canon[26], canon[27], out, E, N);
}

// Round 5
// 1506.010 us; speedup vs baseline: 23.0650x; 1.5041x over previous
//
#include <hip/hip_runtime.h>
#include <cstdint>
#include <cstddef>

// ---------------------------------------------------------------------------
// ParityGameGATNetwork: 3x GATConv -> JK bidirectional LSTM -> node/edge MLPs
// Round 5: edge MLP decomposed algebraically: P = hJK@W1top + b1, Q = hJK@W1bot
// precomputed per node; per-edge work = relu(P[row]+Q[col]) . W2 (gather-bound,
// 250x fewer FLOPs than the per-edge GEMM). LSTM stays MFMA (round 4).
// ---------------------------------------------------------------------------

#define NIN 28

struct InPtrs { const void* p[NIN]; int n[NIN]; };

typedef short s16x4 __attribute__((ext_vector_type(4)));
typedef short s16x8 __attribute__((ext_vector_type(8)));
typedef float f32x4 __attribute__((ext_vector_type(4)));

__device__ __forceinline__ float bf2f(unsigned short v) {
    unsigned int u = ((unsigned int)v) << 16;
    return __uint_as_float(u);
}

__device__ __forceinline__ unsigned short f2bf(float x) {
    unsigned int u = __float_as_uint(x);
    unsigned int r = u + 0x7fffu + ((u >> 16) & 1u);
    return (unsigned short)(r >> 16);
}

__device__ __forceinline__ float rdx(const void* p, size_t i, int isf32) {
    return isf32 ? ((const float*)p)[i] : bf2f(((const unsigned short*)p)[i]);
}

// ---------------- dtype sniffing -------------------------------------------
__global__ void k_sniff(InPtrs in, int* flags) {
    int ai = blockIdx.x;
    if (ai >= NIN) return;
    __shared__ int cnt;
    if (threadIdx.x == 0) cnt = 0;
    __syncthreads();
    if (ai == 1) {
        const int* w = (const int*)in.p[1];
        int nw = in.n[1] < 512 ? in.n[1] : 512;
        int local = 0;
        for (int i = threadIdx.x; i < nw; i += blockDim.x)
            if ((i & 1) && w[i] != 0) local++;
        atomicAdd(&cnt, local);
        __syncthreads();
        if (threadIdx.x == 0) flags[1] = (cnt < 4) ? 1 : 0;
        return;
    }
    const unsigned short* u = (const unsigned short*)in.p[ai];
    int ns = in.n[ai] < 256 ? in.n[ai] : 256;
    int local = 0;
    for (int i = threadIdx.x; i < ns; i += blockDim.x) {
        if (i & 1) continue;
        unsigned short v = u[i];
        int e = (v >> 7) & 0xff;
        if ((v & 0x7fff) != 0 && (e < 100 || e > 154)) local++;
    }
    atomicAdd(&cnt, local);
    __syncthreads();
    if (threadIdx.x == 0) flags[ai] = (cnt * 4 >= ns) ? 1 : 0;
}

__global__ void k_convf(const void* src, float* dst, int n, const int* flags, int ai) {
    int i = blockIdx.x * blockDim.x + threadIdx.x;
    if (i >= n) return;
    if (flags[ai]) dst[i] = ((const float*)src)[i];
    else           dst[i] = bf2f(((const unsigned short*)src)[i]);
}

__global__ void k_conve(const void* src, int* row, int* col, int E, const int* flags) {
    int i = blockIdx.x * blockDim.x + threadIdx.x;
    if (i >= E) return;
    if (flags[1]) {
        const long long* s = (const long long*)src;
        row[i] = (int)s[i];
        col[i] = (int)s[(size_t)E + i];
    } else {
        const int* s = (const int*)src;
        row[i] = s[i];
        col[i] = s[(size_t)E + i];
    }
}

// ---------------- CSR build ------------------------------------------------
__global__ void k_zeroi(int* p, int n) {
    int i = blockIdx.x * blockDim.x + threadIdx.x;
    if (i < n) p[i] = 0;
}

__global__ void k_hist(const int* __restrict__ row, int* __restrict__ cnt, int E) {
    int i = blockIdx.x * blockDim.x + threadIdx.x;
    if (i < E) atomicAdd(&cnt[row[i]], 1);
}

__global__ void k_scan(const int* __restrict__ deg, int* __restrict__ indptr, int N) {
    __shared__ int buf[1024];
    __shared__ int carryS;
    const int t = threadIdx.x;
    if (t == 0) carryS = 0;
    __syncthreads();
    for (int base = 0; base < N; base += 1024) {
        int v = (base + t < N) ? deg[base + t] : 0;
        buf[t] = v;
        __syncthreads();
        for (int ofs = 1; ofs < 1024; ofs <<= 1) {
            int add = (t >= ofs) ? buf[t - ofs] : 0;
            __syncthreads();
            buf[t] += add;
            __syncthreads();
        }
        int carry = carryS;
        if (base + t < N) indptr[base + t] = carry + buf[t] - v;
        __syncthreads();
        if (t == 1023) carryS = carry + buf[1023];
        __syncthreads();
    }
    if (t == 0) indptr[N] = carryS;
}

__global__ void k_fill(const int* __restrict__ row, const int* __restrict__ col,
                       const int* __restrict__ indptr, int* __restrict__ cur,
                       int* __restrict__ colS, int E) {
    int i = blockIdx.x * blockDim.x + threadIdx.x;
    if (i >= E) return;
    int r = row[i];
    int p = indptr[r] + atomicAdd(&cur[r], 1);
    colS[p] = col[i];
}

// ---------------- GAT linear (h = x @ W) + a_src/a_dst epilogue ------------
__global__ __launch_bounds__(256) void k_lin0(
    const float* __restrict__ x, const float* __restrict__ W0,
    const float* __restrict__ asrc, const float* __restrict__ adst,
    float* __restrict__ hlin, float* __restrict__ hs, float* __restrict__ hd, int N) {
    const int wid = threadIdx.x >> 6, lane = threadIdx.x & 63;
    const int n = blockIdx.x * 4 + wid;
    if (n >= N) return;
    float x0 = x[(size_t)n * 3], x1 = x[(size_t)n * 3 + 1], x2 = x[(size_t)n * 3 + 2];
    const int c0 = lane, c1 = lane + 64;
    float h0 = x0 * W0[c0] + x1 * W0[128 + c0] + x2 * W0[256 + c0];
    float h1 = x0 * W0[c1] + x1 * W0[128 + c1] + x2 * W0[256 + c1];
    hlin[(size_t)n * 128 + c0] = h0;
    hlin[(size_t)n * 128 + c1] = h1;
    float sp = h0 * asrc[c0] + h1 * asrc[c1];
    float dp = h0 * adst[c0] + h1 * adst[c1];
    for (int o = 32; o; o >>= 1) { sp += __shfl_down(sp, o); dp += __shfl_down(dp, o); }
    if (lane == 0) { hs[n] = sp; hd[n] = dp; }
}

__global__ __launch_bounds__(256) void k_lin(
    const float* __restrict__ xin, const float* __restrict__ W,
    const float* __restrict__ asrc, const float* __restrict__ adst,
    float* __restrict__ hlin, float* __restrict__ hs, float* __restrict__ hd, int N) {
    __shared__ float xl[4][128];
    const int wid = threadIdx.x >> 6, lane = threadIdx.x & 63;
    const int n = blockIdx.x * 4 + wid;
    if (n < N) {
        xl[wid][lane]      = xin[(size_t)n * 128 + lane];
        xl[wid][lane + 64] = xin[(size_t)n * 128 + lane + 64];
    }
    __syncthreads();
    if (n >= N) return;
    const int c0 = lane, c1 = lane + 64;
    float h0 = 0.f, h1 = 0.f;
    #pragma unroll 4
    for (int k = 0; k < 128; ++k) {
        float xv = xl[wid][k];
        h0 += xv * W[k * 128 + c0];
        h1 += xv * W[k * 128 + c1];
    }
    hlin[(size_t)n * 128 + c0] = h0;
    hlin[(size_t)n * 128 + c1] = h1;
    float sp = h0 * asrc[c0] + h1 * asrc[c1];
    float dp = h0 * adst[c0] + h1 * adst[c1];
    for (int o = 32; o; o >>= 1) { sp += __shfl_down(sp, o); dp += __shfl_down(dp, o); }
    if (lane == 0) { hs[n] = sp; hd[n] = dp; }
}

// ---------------- GAT aggregation: online segment softmax + weighted sum ---
__global__ __launch_bounds__(256) void k_aggr(
    const float* __restrict__ hlin, const float* __restrict__ hs, const float* __restrict__ hd,
    const int* __restrict__ indptr, const int* __restrict__ colS,
    const float* __restrict__ b, float* __restrict__ xout, int N) {
    const int wid = threadIdx.x >> 6, lane = threadIdx.x & 63;
    const int n = blockIdx.x * 4 + wid;
    if (n >= N) return;
    const int s = indptr[n], epos = indptr[n + 1];
    const float hdv = hd[n];
    const int c0 = lane, c1 = lane + 64;
    float m = -1e30f, d = 0.f, a0 = 0.f, a1 = 0.f;
    for (int idx = s; idx < epos; ++idx) {
        int col = colS[idx];
        float e = hs[col] + hdv;
        e = (e > 0.f) ? e : 0.2f * e;
        const float* hr = hlin + (size_t)col * 128;
        float v0 = hr[c0], v1 = hr[c1];
        if (e > m) {
            float sc = __expf(m - e);
            a0 = a0 * sc + v0;
            a1 = a1 * sc + v1;
            d  = d * sc + 1.f;
            m  = e;
        } else {
            float w = __expf(e - m);
            a0 += w * v0;
            a1 += w * v1;
            d  += w;
        }
    }
    float inv = 1.f / (d + 1e-16f);
    float r0 = a0 * inv + b[c0];
    float r1 = a1 * inv + b[c1];
    xout[(size_t)n * 128 + c0] = fmaxf(r0, 0.f);
    xout[(size_t)n * 128 + c1] = fmaxf(r1, 0.f);
}

// ---------------- LSTM weight pack into MFMA fragment order ----------------
__global__ void k_wpack(const void* Wihf, const void* Whhf,
                        const void* Wihb, const void* Whhb,
                        const void* bihf, const void* bhhf,
                        const void* bihb, const void* bhhb,
                        const int* __restrict__ flags,
                        unsigned short* __restrict__ Bpack, float* __restrict__ bsum) {
    int idx = blockIdx.x * blockDim.x + threadIdx.x;
    const int TOT = 2 * 10 * 48 * 512;
    if (idx < TOT) {
        int dir = idx / (10 * 48 * 512);
        int r   = idx % (10 * 48 * 512);
        int kb  = r / (48 * 512);
        int r2  = r % (48 * 512);
        int f   = r2 / 512;
        int q   = r2 % 512;
        int lane = q >> 3, j = q & 7;
        int k   = kb * 32 + ((j >> 2) * 16) + ((lane >> 4) * 4) + (j & 3);
        int col = f * 16 + (lane & 15);
        float v;
        if (k < 128)
            v = dir ? rdx(Wihb, (size_t)col * 128 + k, flags[14])
                    : rdx(Wihf, (size_t)col * 128 + k, flags[10]);
        else
            v = dir ? rdx(Whhb, (size_t)col * 192 + (k - 128), flags[15])
                    : rdx(Whhf, (size_t)col * 192 + (k - 128), flags[11]);
        Bpack[idx] = f2bf(v);
    }
    if (idx < 2 * 768) {
        int d = idx / 768, j = idx % 768;
        bsum[idx] = d ? rdx(bihb, j, flags[16]) + rdx(bhhb, j, flags[17])
                      : rdx(bihf, j, flags[12]) + rdx(bhhf, j, flags[13]);
    }
}

// ---------------- fused bidirectional LSTM, MFMA GEMM ----------------------
__global__ __launch_bounds__(256, 2) void k_lstm_mfma(
    const float* __restrict__ xs,            // [3][N][128] f32
    const unsigned short* __restrict__ Bpack,// [2][10][48][512] bf16
    const float* __restrict__ bsum,          // [2][768]
    const float* __restrict__ attW,          // [384]
    float* __restrict__ scoreP,              // [2][3][N]
    int N) {
    __shared__ unsigned short AS[32][328];   // bf16 A-tile: x in [0,128), h in [128,320)
    __shared__ float scoreS[32];
    const int t = threadIdx.x;
    const int w = t >> 6, lane = t & 63;
    const int dir = blockIdx.y;
    const int n0 = blockIdx.x * 32;
    const int ccol = lane & 15;
    const int lrow = (lane >> 4) * 4;
    const int akl = (lane >> 4) * 4;

    float bI[3], bF[3], bG[3], bO[3], awt[3];
    #pragma unroll
    for (int a = 0; a < 3; ++a) {
        int m = 16 * (w + 4 * a) + ccol;
        bI[a] = bsum[dir * 768 + m];
        bF[a] = bsum[dir * 768 + 192 + m];
        bG[a] = bsum[dir * 768 + 384 + m];
        bO[a] = bsum[dir * 768 + 576 + m];
        awt[a] = attW[dir * 192 + m];
    }
    float cst[24];
    #pragma unroll
    for (int i = 0; i < 24; ++i) cst[i] = 0.f;

    for (int s = 0; s < 3; ++s) {
        const int l = dir ? (2 - s) : s;
        {
            const float* xsrc = xs + ((size_t)l * N + n0) * 128;
            #pragma unroll
            for (int it = 0; it < 4; ++it) {
                int i = t + it * 256;
                int r = i >> 5, kq = (i & 31) * 4;
                float4 v = make_float4(0.f, 0.f, 0.f, 0.f);
                if (n0 + r < N) v = *(const float4*)&xsrc[(size_t)r * 128 + kq];
                ushort4 b4;
                b4.x = f2bf(v.x); b4.y = f2bf(v.y); b4.z = f2bf(v.z); b4.w = f2bf(v.w);
                *(ushort4*)&AS[r][kq] = b4;
            }
        }
        if (t < 32) scoreS[t] = 0.f;
        __syncthreads();

        const int KB = s ? 10 : 4;
        f32x4 acc0[12], acc1[12];
        #pragma unroll
        for (int f = 0; f < 12; ++f) {
            acc0[f] = (f32x4)(0.f);
            acc1[f] = (f32x4)(0.f);
        }
        for (int kb = 0; kb < KB; ++kb) {
            const int k0 = kb * 32 + akl;
            s16x4 a0lo = *(const s16x4*)&AS[ccol][k0];
            s16x4 a0hi = *(const s16x4*)&AS[ccol][k0 + 16];
            s16x4 a1lo = *(const s16x4*)&AS[16 + ccol][k0];
            s16x4 a1hi = *(const s16x4*)&AS[16 + ccol][k0 + 16];
            s16x8 a0 = __builtin_shufflevector(a0lo, a0hi, 0, 1, 2, 3, 4, 5, 6, 7);
            s16x8 a1 = __builtin_shufflevector(a1lo, a1hi, 0, 1, 2, 3, 4, 5, 6, 7);
            const unsigned short* bb =
                Bpack + (((size_t)dir * 10 + kb) * 48 + w) * 512 + lane * 8;
            #pragma unroll
            for (int f = 0; f < 12; ++f) {
                s16x8 b = *(const s16x8*)(bb + (size_t)f * 2048);
                acc0[f] = __builtin_amdgcn_mfma_f32_16x16x32_bf16(a0, b, acc0[f], 0, 0, 0);
                acc1[f] = __builtin_amdgcn_mfma_f32_16x16x32_bf16(a1, b, acc1[f], 0, 0, 0);
            }
        }
        __syncthreads();

        float sprow[8];
        #pragma unroll
        for (int i = 0; i < 8; ++i) sprow[i] = 0.f;
        auto cell = [&](f32x4 (&accT)[12], int tile) {
            #pragma unroll
            for (int a = 0; a < 3; ++a) {
                #pragma unroll
                for (int reg = 0; reg < 4; ++reg) {
                    float gI = accT[a][reg]     + bI[a];
                    float gF = accT[3 + a][reg] + bF[a];
                    float gG = accT[6 + a][reg] + bG[a];
                    float gO = accT[9 + a][reg] + bO[a];
                    float ig = 1.f / (1.f + __expf(-gI));
                    float fg = 1.f / (1.f + __expf(-gF));
                    float gt = tanhf(gG);
                    float og = 1.f / (1.f + __expf(-gO));
                    int ci = tile * 12 + a * 4 + reg;
                    float cn = fg * cst[ci] + ig * gt;
                    cst[ci] = cn;
                    float hh = og * tanhf(cn);
                    int row = tile * 16 + lrow + reg;
                    int m = 16 * (w + 4 * a) + ccol;
                    AS[row][128 + m] = f2bf(hh);
                    sprow[tile * 4 + reg] += hh * awt[a];
                }
            }
        };
        cell(acc0, 0);
        cell(acc1, 1);
        #pragma unroll
        for (int o = 1; o < 16; o <<= 1) {
            #pragma unroll
            for (int i = 0; i < 8; ++i) sprow[i] += __shfl_xor(sprow[i], o);
        }
        if (ccol == 0) {
            #pragma unroll
            for (int i = 0; i < 8; ++i)
                atomicAdd(&scoreS[(i >> 2) * 16 + lrow + (i & 3)], sprow[i]);
        }
        __syncthreads();
        if (t < 32 && n0 + t < N)
            scoreP[(size_t)(dir * 3 + l) * N + n0 + t] = scoreS[t];
    }
}

// ---------------- JK finish: layer softmax + weighted sum ------------------
__global__ __launch_bounds__(256) void k_jkfin(
    const float* __restrict__ xs, const float* __restrict__ scoreP,
    float* __restrict__ hJK, int N) {
    const int nl = threadIdx.x >> 7;           // 2 nodes per block
    const int ch = threadIdx.x & 127;
    const int n = blockIdx.x * 2 + nl;
    if (n >= N) return;
    float s0 = scoreP[n]                  + scoreP[(size_t)3 * N + n];
    float s1 = scoreP[(size_t)N + n]      + scoreP[(size_t)4 * N + n];
    float s2 = scoreP[(size_t)2 * N + n]  + scoreP[(size_t)5 * N + n];
    float m = fmaxf(s0, fmaxf(s1, s2));
    float e0 = __expf(s0 - m), e1 = __expf(s1 - m), e2 = __expf(s2 - m);
    float inv = 1.f / (e0 + e1 + e2);
    e0 *= inv; e1 *= inv; e2 *= inv;
    const size_t nb = (size_t)n * 128 + ch;
    const size_t L1o = (size_t)N * 128, L2o = 2 * (size_t)N * 128;
    hJK[nb] = e0 * xs[nb] + e1 * xs[L1o + nb] + e2 * xs[L2o + nb];
}

// ---------------- node classifier ------------------------------------------
__global__ __launch_bounds__(256) void k_nodemlp(
    const float* __restrict__ hJK, const float* __restrict__ W1, const float* __restrict__ b1,
    const float* __restrict__ W2, const float* __restrict__ b2,
    float* __restrict__ out, int N) {
    __shared__ float xl[4][128];
    const int wid = threadIdx.x >> 6, lane = threadIdx.x & 63;
    const int n = blockIdx.x * 4 + wid;
    if (n < N) {
        xl[wid][lane]      = hJK[(size_t)n * 128 + lane];
        xl[wid][lane + 64] = hJK[(size_t)n * 128 + lane + 64];
    }
    __syncthreads();
    if (n >= N) return;
    const int c0 = lane, c1 = lane + 64;
    float h0 = 0.f, h1 = 0.f;
    #pragma unroll 4
    for (int k = 0; k < 128; ++k) {
        float xv = xl[wid][k];
        h0 += xv * W1[k * 128 + c0];
        h1 += xv * W1[k * 128 + c1];
    }
    h0 = fmaxf(h0 + b1[c0], 0.f);
    h1 = fmaxf(h1 + b1[c1], 0.f);
    float p0 = h0 * W2[c0 * 2 + 0] + h1 * W2[c1 * 2 + 0];
    float p1 = h0 * W2[c0 * 2 + 1] + h1 * W2[c1 * 2 + 1];
    for (int o = 32; o; o >>= 1) { p0 += __shfl_down(p0, o); p1 += __shfl_down(p1, o); }
    if (lane == 0) {
        float l0 = p0 + b2[0], l1 = p1 + b2[1];
        float mm = fmaxf(l0, l1);
        float e0 = __expf(l0 - mm), e1 = __expf(l1 - mm);
        float inv = 1.f / (e0 + e1);
        out[2 * (size_t)n]     = e0 * inv;
        out[2 * (size_t)n + 1] = e1 * inv;
    }
}

// ---------------- edge MLP: per-node P/Q precompute ------------------------
// P[n] = hJK[n] @ eW1[0:128,:] + eb1 ;  Q[n] = hJK[n] @ eW1[128:256,:]
__global__ __launch_bounds__(256) void k_pqlin(
    const float* __restrict__ hJK, const float* __restrict__ W1,
    const float* __restrict__ b1,
    float* __restrict__ P, float* __restrict__ Q, int N) {
    __shared__ float xl[4][128];
    const int wid = threadIdx.x >> 6, lane = threadIdx.x & 63;
    const int n = blockIdx.x * 4 + wid;
    if (n < N) {
        xl[wid][lane]      = hJK[(size_t)n * 128 + lane];
        xl[wid][lane + 64] = hJK[(size_t)n * 128 + lane + 64];
    }
    __syncthreads();
    if (n >= N) return;
    const int c0 = lane, c1 = lane + 64;
    float p0 = 0.f, p1 = 0.f, q0 = 0.f, q1 = 0.f;
    #pragma unroll 4
    for (int k = 0; k < 128; ++k) {
        float xv = xl[wid][k];
        p0 += xv * W1[k * 128 + c0];
        p1 += xv * W1[k * 128 + c1];
        q0 += xv * W1[(128 + k) * 128 + c0];
        q1 += xv * W1[(128 + k) * 128 + c1];
    }
    P[(size_t)n * 128 + c0] = p0 + b1[c0];
    P[(size_t)n * 128 + c1] = p1 + b1[c1];
    Q[(size_t)n * 128 + c0] = q0;
    Q[(size_t)n * 128 + c1] = q1;
}

// ---------------- edge MLP finish: gather-add-relu-dot ---------------------
// One edge per 16-lane group; lane sl owns channels [8*sl, 8*sl+8).
__global__ __launch_bounds__(256) void k_edge2(
    const float* __restrict__ P, const float* __restrict__ Q,
    const int* __restrict__ row, const int* __restrict__ col,
    const float* __restrict__ W2, const float* __restrict__ b2,
    float* __restrict__ out, long long E, int N) {
    long long g = (((long long)blockIdx.x * blockDim.x) + threadIdx.x) >> 4;
    const int sl = threadIdx.x & 15;
    if (g >= E) return;
    int r = row[g], c = col[g];
    const float4* pr = (const float4*)(P + (size_t)r * 128) + sl * 2;
    const float4* qr = (const float4*)(Q + (size_t)c * 128) + sl * 2;
    const float4* w2 = (const float4*)W2 + sl * 4;   // [128][2] f32, 16 floats/lane
    float l0 = 0.f, l1 = 0.f;
    #pragma unroll
    for (int j = 0; j < 2; ++j) {
        float4 p = pr[j], q = qr[j];
        float4 wA = w2[2 * j], wB = w2[2 * j + 1];
        float h0 = fmaxf(p.x + q.x, 0.f), h1 = fmaxf(p.y + q.y, 0.f);
        float h2 = fmaxf(p.z + q.z, 0.f), h3 = fmaxf(p.w + q.w, 0.f);
        l0 += h0 * wA.x + h1 * wA.z + h2 * wB.x + h3 * wB.z;
        l1 += h0 * wA.y + h1 * wA.w + h2 * wB.y + h3 * wB.w;
    }
    #pragma unroll
    for (int o = 1; o < 16; o <<= 1) { l0 += __shfl_xor(l0, o); l1 += __shfl_xor(l1, o); }
    if (sl == 0) {
        l0 += b2[0]; l1 += b2[1];
        float mm = fmaxf(l0, l1);
        float e0 = __expf(l0 - mm), e1 = __expf(l1 - mm);
        float inv = 1.f / (e0 + e1);
        out[2 * (long long)N + 2 * g]     = e0 * inv;
        out[2 * (long long)N + 2 * g + 1] = e1 * inv;
    }
}

// ---------------------------------------------------------------------------
extern "C" void kernel_launch(void* const* d_in, const int* in_sizes, int n_in,
                              void* d_out, int out_size, void* d_ws, size_t ws_size,
                              hipStream_t stream) {
    if (n_in < NIN) return;
    const int N = in_sizes[0] / 3;
    const int E = in_sizes[1] / 2;

    char* ws = (char*)d_ws;
    size_t off = 0;
    auto alloc = [&](size_t bytes) -> char* {
        char* p = ws + off;
        off = (off + bytes + 255) & ~(size_t)255;
        return p;
    };
    int* flags = (int*)alloc(32 * sizeof(int));
    float* canon[NIN];
    for (int i = 0; i < NIN; ++i) canon[i] = nullptr;
    for (int i = 0; i < NIN; ++i) {
        if (i == 1 || (i >= 10 && i <= 17)) continue;   // LSTM weights read raw
        canon[i] = (float*)alloc((size_t)in_sizes[i] * 4);
    }
    int* row32  = (int*)alloc((size_t)E * 4);
    int* col32  = (int*)alloc((size_t)E * 4);
    int* indptr = (int*)alloc((size_t)(N + 1) * 4);
    int* cnt    = (int*)alloc((size_t)N * 4);
    int* colS   = (int*)alloc((size_t)E * 4);
    float* hs   = (float*)alloc((size_t)N * 4);
    float* hd   = (float*)alloc((size_t)N * 4);
    float* hlin = (float*)alloc((size_t)N * 128 * 4);   // reused as hJK later
    float* xs   = (float*)alloc((size_t)3 * N * 128 * 4);
    unsigned short* Bpack = (unsigned short*)alloc((size_t)2 * 10 * 48 * 512 * 2);
    float* bsum = (float*)alloc((size_t)2 * 768 * 4);
    // scoreP [2][3][N] aliases colS (dead after last k_aggr) when it fits
    float* scoreP;
    if ((size_t)E >= (size_t)6 * N) scoreP = (float*)colS;
    else                            scoreP = (float*)alloc((size_t)6 * N * 4);
    if (off > ws_size) return;
    // P/Q alias xs (dead after k_jkfin): 2*N*128 floats <= 3*N*128 floats
    float* P = xs;
    float* Q = xs + (size_t)N * 128;

    InPtrs ip;
    for (int i = 0; i < NIN; ++i) { ip.p[i] = d_in[i]; ip.n[i] = in_sizes[i]; }

    k_sniff<<<NIN, 256, 0, stream>>>(ip, flags);
    for (int i = 0; i < NIN; ++i) {
        if (i == 1 || (i >= 10 && i <= 17)) continue;
        int n = in_sizes[i];
        k_convf<<<(n + 255) / 256, 256, 0, stream>>>(d_in[i], canon[i], n, flags, i);
    }
    k_conve<<<(E + 255) / 256, 256, 0, stream>>>(d_in[1], row32, col32, E, flags);
    k_wpack<<<(2 * 10 * 48 * 512 + 255) / 256, 256, 0, stream>>>(
        d_in[10], d_in[11], d_in[14], d_in[15],
        d_in[12], d_in[13], d_in[16], d_in[17], flags, Bpack, bsum);

    // CSR by row (shared across all 3 GAT layers)
    k_zeroi<<<(N + 255) / 256, 256, 0, stream>>>(cnt, N);
    k_hist<<<(E + 255) / 256, 256, 0, stream>>>(row32, cnt, E);
    k_scan<<<1, 1024, 0, stream>>>(cnt, indptr, N);
    k_zeroi<<<(N + 255) / 256, 256, 0, stream>>>(cnt, N);
    k_fill<<<(E + 255) / 256, 256, 0, stream>>>(row32, col32, indptr, cnt, colS, E);

    // GAT layer 0 (in=3)
    k_lin0<<<(N + 3) / 4, 256, 0, stream>>>(canon[0], canon[2], canon[4], canon[5],
                                            hlin, hs, hd, N);
    k_aggr<<<(N + 3) / 4, 256, 0, stream>>>(hlin, hs, hd, indptr, colS, canon[3], xs, N);
    // GAT layers 1..2 (in=128)
    for (int l = 1; l < 3; ++l) {
        const float* W  = canon[6] + (size_t)(l - 1) * 128 * 128;
        const float* bb = canon[7] + (size_t)(l - 1) * 128;
        const float* as = canon[8] + (size_t)(l - 1) * 128;
        const float* ad = canon[9] + (size_t)(l - 1) * 128;
        k_lin<<<(N + 3) / 4, 256, 0, stream>>>(xs + (size_t)(l - 1) * N * 128, W, as, ad,
                                               hlin, hs, hd, N);
        k_aggr<<<(N + 3) / 4, 256, 0, stream>>>(hlin, hs, hd, indptr, colS, bb,
                                                xs + (size_t)l * N * 128, N);
    }

    // fused bidirectional LSTM (MFMA) + JK attention finish
    dim3 lgrid((N + 31) / 32, 2);
    k_lstm_mfma<<<lgrid, 256, 0, stream>>>(xs, Bpack, bsum, canon[18], scoreP, N);
    k_jkfin<<<(N + 1) / 2, 256, 0, stream>>>(xs, scoreP, hlin, N);

    float* out = (float*)d_out;
    k_nodemlp<<<(N + 3) / 4, 256, 0, stream>>>(hlin, canon[20], canon[21], canon[22],
                                               canon[23], out, N);
    // edge MLP: P/Q precompute (overwrites dead xs), then gather-add-relu-dot
    k_pqlin<<<(N + 3) / 4, 256, 0, stream>>>(hlin, canon[24], canon[25], P, Q, N);
    {
        long long tot = (long long)E * 16;
        int blocks = (int)((tot + 255) / 256);
        k_edge2<<<blocks, 256, 0, stream>>>(P, Q, row32, col32, canon[26], canon[27],
                                            out, (long long)E, N);
    }
}

// Round 6
// 1340.577 us; speedup vs baseline: 25.9113x; 1.1234x over previous
//
#include <hip/hip_runtime.h>
#include <cstdint>
#include <cstddef>

// ---------------------------------------------------------------------------
// ParityGameGATNetwork: 3x GATConv -> JK bidirectional LSTM -> node/edge MLPs
// Round 6: (a) LSTM cell epilogue fast-tanh (libm tanhf was ~half the kernel's
// VALU work), (b) P/Q edge buffers in bf16 (halves 800MB gather traffic),
// (c) GAT aggregation edge-loop unrolled x4 (4 gathers in flight vs 1).
// ---------------------------------------------------------------------------

#define NIN 28

struct InPtrs { const void* p[NIN]; int n[NIN]; };

typedef short s16x4 __attribute__((ext_vector_type(4)));
typedef short s16x8 __attribute__((ext_vector_type(8)));
typedef float f32x4 __attribute__((ext_vector_type(4)));
typedef unsigned short u16x8 __attribute__((ext_vector_type(8)));

__device__ __forceinline__ float bf2f(unsigned short v) {
    unsigned int u = ((unsigned int)v) << 16;
    return __uint_as_float(u);
}

__device__ __forceinline__ unsigned short f2bf(float x) {
    unsigned int u = __float_as_uint(x);
    unsigned int r = u + 0x7fffu + ((u >> 16) & 1u);
    return (unsigned short)(r >> 16);
}

__device__ __forceinline__ float rdx(const void* p, size_t i, int isf32) {
    return isf32 ? ((const float*)p)[i] : bf2f(((const unsigned short*)p)[i]);
}

__device__ __forceinline__ float fast_tanh(float x) {
    // 1 - 2/(e^{2x}+1); exact at +-inf saturation, ~2ulp from __expf
    float e = __expf(2.f * x);
    return 1.f - 2.f / (e + 1.f);
}

// ---------------- dtype sniffing -------------------------------------------
__global__ void k_sniff(InPtrs in, int* flags) {
    int ai = blockIdx.x;
    if (ai >= NIN) return;
    __shared__ int cnt;
    if (threadIdx.x == 0) cnt = 0;
    __syncthreads();
    if (ai == 1) {
        const int* w = (const int*)in.p[1];
        int nw = in.n[1] < 512 ? in.n[1] : 512;
        int local = 0;
        for (int i = threadIdx.x; i < nw; i += blockDim.x)
            if ((i & 1) && w[i] != 0) local++;
        atomicAdd(&cnt, local);
        __syncthreads();
        if (threadIdx.x == 0) flags[1] = (cnt < 4) ? 1 : 0;
        return;
    }
    const unsigned short* u = (const unsigned short*)in.p[ai];
    int ns = in.n[ai] < 256 ? in.n[ai] : 256;
    int local = 0;
    for (int i = threadIdx.x; i < ns; i += blockDim.x) {
        if (i & 1) continue;
        unsigned short v = u[i];
        int e = (v >> 7) & 0xff;
        if ((v & 0x7fff) != 0 && (e < 100 || e > 154)) local++;
    }
    atomicAdd(&cnt, local);
    __syncthreads();
    if (threadIdx.x == 0) flags[ai] = (cnt * 4 >= ns) ? 1 : 0;
}

__global__ void k_convf(const void* src, float* dst, int n, const int* flags, int ai) {
    int i = blockIdx.x * blockDim.x + threadIdx.x;
    if (i >= n) return;
    if (flags[ai]) dst[i] = ((const float*)src)[i];
    else           dst[i] = bf2f(((const unsigned short*)src)[i]);
}

__global__ void k_conve(const void* src, int* row, int* col, int E, const int* flags) {
    int i = blockIdx.x * blockDim.x + threadIdx.x;
    if (i >= E) return;
    if (flags[1]) {
        const long long* s = (const long long*)src;
        row[i] = (int)s[i];
        col[i] = (int)s[(size_t)E + i];
    } else {
        const int* s = (const int*)src;
        row[i] = s[i];
        col[i] = s[(size_t)E + i];
    }
}

// ---------------- CSR build ------------------------------------------------
__global__ void k_zeroi(int* p, int n) {
    int i = blockIdx.x * blockDim.x + threadIdx.x;
    if (i < n) p[i] = 0;
}

__global__ void k_hist(const int* __restrict__ row, int* __restrict__ cnt, int E) {
    int i = blockIdx.x * blockDim.x + threadIdx.x;
    if (i < E) atomicAdd(&cnt[row[i]], 1);
}

__global__ void k_scan(const int* __restrict__ deg, int* __restrict__ indptr, int N) {
    __shared__ int buf[1024];
    __shared__ int carryS;
    const int t = threadIdx.x;
    if (t == 0) carryS = 0;
    __syncthreads();
    for (int base = 0; base < N; base += 1024) {
        int v = (base + t < N) ? deg[base + t] : 0;
        buf[t] = v;
        __syncthreads();
        for (int ofs = 1; ofs < 1024; ofs <<= 1) {
            int add = (t >= ofs) ? buf[t - ofs] : 0;
            __syncthreads();
            buf[t] += add;
            __syncthreads();
        }
        int carry = carryS;
        if (base + t < N) indptr[base + t] = carry + buf[t] - v;
        __syncthreads();
        if (t == 1023) carryS = carry + buf[1023];
        __syncthreads();
    }
    if (t == 0) indptr[N] = carryS;
}

__global__ void k_fill(const int* __restrict__ row, const int* __restrict__ col,
                       const int* __restrict__ indptr, int* __restrict__ cur,
                       int* __restrict__ colS, int E) {
    int i = blockIdx.x * blockDim.x + threadIdx.x;
    if (i >= E) return;
    int r = row[i];
    int p = indptr[r] + atomicAdd(&cur[r], 1);
    colS[p] = col[i];
}

// ---------------- GAT linear (h = x @ W) + a_src/a_dst epilogue ------------
__global__ __launch_bounds__(256) void k_lin0(
    const float* __restrict__ x, const float* __restrict__ W0,
    const float* __restrict__ asrc, const float* __restrict__ adst,
    float* __restrict__ hlin, float* __restrict__ hs, float* __restrict__ hd, int N) {
    const int wid = threadIdx.x >> 6, lane = threadIdx.x & 63;
    const int n = blockIdx.x * 4 + wid;
    if (n >= N) return;
    float x0 = x[(size_t)n * 3], x1 = x[(size_t)n * 3 + 1], x2 = x[(size_t)n * 3 + 2];
    const int c0 = lane, c1 = lane + 64;
    float h0 = x0 * W0[c0] + x1 * W0[128 + c0] + x2 * W0[256 + c0];
    float h1 = x0 * W0[c1] + x1 * W0[128 + c1] + x2 * W0[256 + c1];
    hlin[(size_t)n * 128 + c0] = h0;
    hlin[(size_t)n * 128 + c1] = h1;
    float sp = h0 * asrc[c0] + h1 * asrc[c1];
    float dp = h0 * adst[c0] + h1 * adst[c1];
    for (int o = 32; o; o >>= 1) { sp += __shfl_down(sp, o); dp += __shfl_down(dp, o); }
    if (lane == 0) { hs[n] = sp; hd[n] = dp; }
}

__global__ __launch_bounds__(256) void k_lin(
    const float* __restrict__ xin, const float* __restrict__ W,
    const float* __restrict__ asrc, const float* __restrict__ adst,
    float* __restrict__ hlin, float* __restrict__ hs, float* __restrict__ hd, int N) {
    __shared__ float xl[4][128];
    const int wid = threadIdx.x >> 6, lane = threadIdx.x & 63;
    const int n = blockIdx.x * 4 + wid;
    if (n < N) {
        xl[wid][lane]      = xin[(size_t)n * 128 + lane];
        xl[wid][lane + 64] = xin[(size_t)n * 128 + lane + 64];
    }
    __syncthreads();
    if (n >= N) return;
    const int c0 = lane, c1 = lane + 64;
    float h0 = 0.f, h1 = 0.f;
    #pragma unroll 4
    for (int k = 0; k < 128; ++k) {
        float xv = xl[wid][k];
        h0 += xv * W[k * 128 + c0];
        h1 += xv * W[k * 128 + c1];
    }
    hlin[(size_t)n * 128 + c0] = h0;
    hlin[(size_t)n * 128 + c1] = h1;
    float sp = h0 * asrc[c0] + h1 * asrc[c1];
    float dp = h0 * adst[c0] + h1 * adst[c1];
    for (int o = 32; o; o >>= 1) { sp += __shfl_down(sp, o); dp += __shfl_down(dp, o); }
    if (lane == 0) { hs[n] = sp; hd[n] = dp; }
}

// ---------------- GAT aggregation: online segment softmax, 4-way unrolled --
__global__ __launch_bounds__(256) void k_aggr(
    const float* __restrict__ hlin, const float* __restrict__ hs, const float* __restrict__ hd,
    const int* __restrict__ indptr, const int* __restrict__ colS,
    const float* __restrict__ b, float* __restrict__ xout, int N) {
    const int wid = threadIdx.x >> 6, lane = threadIdx.x & 63;
    const int n = blockIdx.x * 4 + wid;
    if (n >= N) return;
    const int s = indptr[n], epos = indptr[n + 1];
    const float hdv = hd[n];
    const int c0 = lane, c1 = lane + 64;
    float m = -1e30f, d = 0.f, a0 = 0.f, a1 = 0.f;
    int idx = s;
    for (; idx + 4 <= epos; idx += 4) {
        int col0 = colS[idx], col1 = colS[idx + 1], col2 = colS[idx + 2], col3 = colS[idx + 3];
        float e0 = hs[col0] + hdv, e1 = hs[col1] + hdv;
        float e2 = hs[col2] + hdv, e3 = hs[col3] + hdv;
        e0 = (e0 > 0.f) ? e0 : 0.2f * e0;
        e1 = (e1 > 0.f) ? e1 : 0.2f * e1;
        e2 = (e2 > 0.f) ? e2 : 0.2f * e2;
        e3 = (e3 > 0.f) ? e3 : 0.2f * e3;
        const float* h0p = hlin + (size_t)col0 * 128;
        const float* h1p = hlin + (size_t)col1 * 128;
        const float* h2p = hlin + (size_t)col2 * 128;
        const float* h3p = hlin + (size_t)col3 * 128;
        float v00 = h0p[c0], v01 = h0p[c1];
        float v10 = h1p[c0], v11 = h1p[c1];
        float v20 = h2p[c0], v21 = h2p[c1];
        float v30 = h3p[c0], v31 = h3p[c1];
        float m4 = fmaxf(fmaxf(e0, e1), fmaxf(e2, e3));
        if (m4 > m) {                        // wave-uniform (e per-edge scalar)
            float sc = __expf(m - m4);
            a0 *= sc; a1 *= sc; d *= sc; m = m4;
        }
        float w0 = __expf(e0 - m), w1 = __expf(e1 - m);
        float w2 = __expf(e2 - m), w3 = __expf(e3 - m);
        a0 += w0 * v00 + w1 * v10 + w2 * v20 + w3 * v30;
        a1 += w0 * v01 + w1 * v11 + w2 * v21 + w3 * v31;
        d  += w0 + w1 + w2 + w3;
    }
    for (; idx < epos; ++idx) {
        int col = colS[idx];
        float e = hs[col] + hdv;
        e = (e > 0.f) ? e : 0.2f * e;
        const float* hr = hlin + (size_t)col * 128;
        float v0 = hr[c0], v1 = hr[c1];
        if (e > m) {
            float sc = __expf(m - e);
            a0 = a0 * sc + v0;
            a1 = a1 * sc + v1;
            d  = d * sc + 1.f;
            m  = e;
        } else {
            float w = __expf(e - m);
            a0 += w * v0;
            a1 += w * v1;
            d  += w;
        }
    }
    float inv = 1.f / (d + 1e-16f);
    float r0 = a0 * inv + b[c0];
    float r1 = a1 * inv + b[c1];
    xout[(size_t)n * 128 + c0] = fmaxf(r0, 0.f);
    xout[(size_t)n * 128 + c1] = fmaxf(r1, 0.f);
}

// ---------------- LSTM weight pack into MFMA fragment order ----------------
__global__ void k_wpack(const void* Wihf, const void* Whhf,
                        const void* Wihb, const void* Whhb,
                        const void* bihf, const void* bhhf,
                        const void* bihb, const void* bhhb,
                        const int* __restrict__ flags,
                        unsigned short* __restrict__ Bpack, float* __restrict__ bsum) {
    int idx = blockIdx.x * blockDim.x + threadIdx.x;
    const int TOT = 2 * 10 * 48 * 512;
    if (idx < TOT) {
        int dir = idx / (10 * 48 * 512);
        int r   = idx % (10 * 48 * 512);
        int kb  = r / (48 * 512);
        int r2  = r % (48 * 512);
        int f   = r2 / 512;
        int q   = r2 % 512;
        int lane = q >> 3, j = q & 7;
        int k   = kb * 32 + ((j >> 2) * 16) + ((lane >> 4) * 4) + (j & 3);
        int col = f * 16 + (lane & 15);
        float v;
        if (k < 128)
            v = dir ? rdx(Wihb, (size_t)col * 128 + k, flags[14])
                    : rdx(Wihf, (size_t)col * 128 + k, flags[10]);
        else
            v = dir ? rdx(Whhb, (size_t)col * 192 + (k - 128), flags[15])
                    : rdx(Whhf, (size_t)col * 192 + (k - 128), flags[11]);
        Bpack[idx] = f2bf(v);
    }
    if (idx < 2 * 768) {
        int d = idx / 768, j = idx % 768;
        bsum[idx] = d ? rdx(bihb, j, flags[16]) + rdx(bhhb, j, flags[17])
                      : rdx(bihf, j, flags[12]) + rdx(bhhf, j, flags[13]);
    }
}

// ---------------- fused bidirectional LSTM, MFMA GEMM ----------------------
__global__ __launch_bounds__(256, 2) void k_lstm_mfma(
    const float* __restrict__ xs,            // [3][N][128] f32
    const unsigned short* __restrict__ Bpack,// [2][10][48][512] bf16
    const float* __restrict__ bsum,          // [2][768]
    const float* __restrict__ attW,          // [384]
    float* __restrict__ scoreP,              // [2][3][N]
    int N) {
    __shared__ unsigned short AS[32][328];   // bf16 A-tile: x in [0,128), h in [128,320)
    __shared__ float scoreS[32];
    const int t = threadIdx.x;
    const int w = t >> 6, lane = t & 63;
    const int dir = blockIdx.y;
    const int n0 = blockIdx.x * 32;
    const int ccol = lane & 15;
    const int lrow = (lane >> 4) * 4;
    const int akl = (lane >> 4) * 4;

    float bI[3], bF[3], bG[3], bO[3], awt[3];
    #pragma unroll
    for (int a = 0; a < 3; ++a) {
        int m = 16 * (w + 4 * a) + ccol;
        bI[a] = bsum[dir * 768 + m];
        bF[a] = bsum[dir * 768 + 192 + m];
        bG[a] = bsum[dir * 768 + 384 + m];
        bO[a] = bsum[dir * 768 + 576 + m];
        awt[a] = attW[dir * 192 + m];
    }
    float cst[24];
    #pragma unroll
    for (int i = 0; i < 24; ++i) cst[i] = 0.f;

    for (int s = 0; s < 3; ++s) {
        const int l = dir ? (2 - s) : s;
        {
            const float* xsrc = xs + ((size_t)l * N + n0) * 128;
            #pragma unroll
            for (int it = 0; it < 4; ++it) {
                int i = t + it * 256;
                int r = i >> 5, kq = (i & 31) * 4;
                float4 v = make_float4(0.f, 0.f, 0.f, 0.f);
                if (n0 + r < N) v = *(const float4*)&xsrc[(size_t)r * 128 + kq];
                ushort4 b4;
                b4.x = f2bf(v.x); b4.y = f2bf(v.y); b4.z = f2bf(v.z); b4.w = f2bf(v.w);
                *(ushort4*)&AS[r][kq] = b4;
            }
        }
        if (t < 32) scoreS[t] = 0.f;
        __syncthreads();

        const int KB = s ? 10 : 4;
        f32x4 acc0[12], acc1[12];
        #pragma unroll
        for (int f = 0; f < 12; ++f) {
            acc0[f] = (f32x4)(0.f);
            acc1[f] = (f32x4)(0.f);
        }
        for (int kb = 0; kb < KB; ++kb) {
            const int k0 = kb * 32 + akl;
            s16x4 a0lo = *(const s16x4*)&AS[ccol][k0];
            s16x4 a0hi = *(const s16x4*)&AS[ccol][k0 + 16];
            s16x4 a1lo = *(const s16x4*)&AS[16 + ccol][k0];
            s16x4 a1hi = *(const s16x4*)&AS[16 + ccol][k0 + 16];
            s16x8 a0 = __builtin_shufflevector(a0lo, a0hi, 0, 1, 2, 3, 4, 5, 6, 7);
            s16x8 a1 = __builtin_shufflevector(a1lo, a1hi, 0, 1, 2, 3, 4, 5, 6, 7);
            const unsigned short* bb =
                Bpack + (((size_t)dir * 10 + kb) * 48 + w) * 512 + lane * 8;
            #pragma unroll
            for (int f = 0; f < 12; ++f) {
                s16x8 b = *(const s16x8*)(bb + (size_t)f * 2048);
                acc0[f] = __builtin_amdgcn_mfma_f32_16x16x32_bf16(a0, b, acc0[f], 0, 0, 0);
                acc1[f] = __builtin_amdgcn_mfma_f32_16x16x32_bf16(a1, b, acc1[f], 0, 0, 0);
            }
        }
        __syncthreads();

        float sprow[8];
        #pragma unroll
        for (int i = 0; i < 8; ++i) sprow[i] = 0.f;
        auto cell = [&](f32x4 (&accT)[12], int tile) {
            #pragma unroll
            for (int a = 0; a < 3; ++a) {
                #pragma unroll
                for (int reg = 0; reg < 4; ++reg) {
                    float gI = accT[a][reg]     + bI[a];
                    float gF = accT[3 + a][reg] + bF[a];
                    float gG = accT[6 + a][reg] + bG[a];
                    float gO = accT[9 + a][reg] + bO[a];
                    float ig = 1.f / (1.f + __expf(-gI));
                    float fg = 1.f / (1.f + __expf(-gF));
                    float gt = fast_tanh(gG);
                    float og = 1.f / (1.f + __expf(-gO));
                    int ci = tile * 12 + a * 4 + reg;
                    float cn = fg * cst[ci] + ig * gt;
                    cst[ci] = cn;
                    float hh = og * fast_tanh(cn);
                    int row = tile * 16 + lrow + reg;
                    int m = 16 * (w + 4 * a) + ccol;
                    AS[row][128 + m] = f2bf(hh);
                    sprow[tile * 4 + reg] += hh * awt[a];
                }
            }
        };
        cell(acc0, 0);
        cell(acc1, 1);
        #pragma unroll
        for (int o = 1; o < 16; o <<= 1) {
            #pragma unroll
            for (int i = 0; i < 8; ++i) sprow[i] += __shfl_xor(sprow[i], o);
        }
        if (ccol == 0) {
            #pragma unroll
            for (int i = 0; i < 8; ++i)
                atomicAdd(&scoreS[(i >> 2) * 16 + lrow + (i & 3)], sprow[i]);
        }
        __syncthreads();
        if (t < 32 && n0 + t < N)
            scoreP[(size_t)(dir * 3 + l) * N + n0 + t] = scoreS[t];
    }
}

// ---------------- JK finish: layer softmax + weighted sum ------------------
__global__ __launch_bounds__(256) void k_jkfin(
    const float* __restrict__ xs, const float* __restrict__ scoreP,
    float* __restrict__ hJK, int N) {
    const int nl = threadIdx.x >> 7;           // 2 nodes per block
    const int ch = threadIdx.x & 127;
    const int n = blockIdx.x * 2 + nl;
    if (n >= N) return;
    float s0 = scoreP[n]                  + scoreP[(size_t)3 * N + n];
    float s1 = scoreP[(size_t)N + n]      + scoreP[(size_t)4 * N + n];
    float s2 = scoreP[(size_t)2 * N + n]  + scoreP[(size_t)5 * N + n];
    float m = fmaxf(s0, fmaxf(s1, s2));
    float e0 = __expf(s0 - m), e1 = __expf(s1 - m), e2 = __expf(s2 - m);
    float inv = 1.f / (e0 + e1 + e2);
    e0 *= inv; e1 *= inv; e2 *= inv;
    const size_t nb = (size_t)n * 128 + ch;
    const size_t L1o = (size_t)N * 128, L2o = 2 * (size_t)N * 128;
    hJK[nb] = e0 * xs[nb] + e1 * xs[L1o + nb] + e2 * xs[L2o + nb];
}

// ---------------- node classifier ------------------------------------------
__global__ __launch_bounds__(256) void k_nodemlp(
    const float* __restrict__ hJK, const float* __restrict__ W1, const float* __restrict__ b1,
    const float* __restrict__ W2, const float* __restrict__ b2,
    float* __restrict__ out, int N) {
    __shared__ float xl[4][128];
    const int wid = threadIdx.x >> 6, lane = threadIdx.x & 63;
    const int n = blockIdx.x * 4 + wid;
    if (n < N) {
        xl[wid][lane]      = hJK[(size_t)n * 128 + lane];
        xl[wid][lane + 64] = hJK[(size_t)n * 128 + lane + 64];
    }
    __syncthreads();
    if (n >= N) return;
    const int c0 = lane, c1 = lane + 64;
    float h0 = 0.f, h1 = 0.f;
    #pragma unroll 4
    for (int k = 0; k < 128; ++k) {
        float xv = xl[wid][k];
        h0 += xv * W1[k * 128 + c0];
        h1 += xv * W1[k * 128 + c1];
    }
    h0 = fmaxf(h0 + b1[c0], 0.f);
    h1 = fmaxf(h1 + b1[c1], 0.f);
    float p0 = h0 * W2[c0 * 2 + 0] + h1 * W2[c1 * 2 + 0];
    float p1 = h0 * W2[c0 * 2 + 1] + h1 * W2[c1 * 2 + 1];
    for (int o = 32; o; o >>= 1) { p0 += __shfl_down(p0, o); p1 += __shfl_down(p1, o); }
    if (lane == 0) {
        float l0 = p0 + b2[0], l1 = p1 + b2[1];
        float mm = fmaxf(l0, l1);
        float e0 = __expf(l0 - mm), e1 = __expf(l1 - mm);
        float inv = 1.f / (e0 + e1);
        out[2 * (size_t)n]     = e0 * inv;
        out[2 * (size_t)n + 1] = e1 * inv;
    }
}

// ---------------- edge MLP: per-node P/Q precompute (bf16 out) -------------
// P[n] = hJK[n] @ eW1[0:128,:] + eb1 ;  Q[n] = hJK[n] @ eW1[128:256,:]
__global__ __launch_bounds__(256) void k_pqlin(
    const float* __restrict__ hJK, const float* __restrict__ W1,
    const float* __restrict__ b1,
    unsigned short* __restrict__ P, unsigned short* __restrict__ Q, int N) {
    __shared__ float xl[4][128];
    const int wid = threadIdx.x >> 6, lane = threadIdx.x & 63;
    const int n = blockIdx.x * 4 + wid;
    if (n < N) {
        xl[wid][lane]      = hJK[(size_t)n * 128 + lane];
        xl[wid][lane + 64] = hJK[(size_t)n * 128 + lane + 64];
    }
    __syncthreads();
    if (n >= N) return;
    const int c0 = lane, c1 = lane + 64;
    float p0 = 0.f, p1 = 0.f, q0 = 0.f, q1 = 0.f;
    #pragma unroll 4
    for (int k = 0; k < 128; ++k) {
        float xv = xl[wid][k];
        p0 += xv * W1[k * 128 + c0];
        p1 += xv * W1[k * 128 + c1];
        q0 += xv * W1[(128 + k) * 128 + c0];
        q1 += xv * W1[(128 + k) * 128 + c1];
    }
    P[(size_t)n * 128 + c0] = f2bf(p0 + b1[c0]);
    P[(size_t)n * 128 + c1] = f2bf(p1 + b1[c1]);
    Q[(size_t)n * 128 + c0] = f2bf(q0);
    Q[(size_t)n * 128 + c1] = f2bf(q1);
}

// ---------------- edge MLP finish: gather-add-relu-dot (bf16 P/Q) ----------
// One edge per 16-lane group; lane sl owns channels [8*sl, 8*sl+8).
__global__ __launch_bounds__(256) void k_edge2(
    const unsigned short* __restrict__ P, const unsigned short* __restrict__ Q,
    const int* __restrict__ row, const int* __restrict__ col,
    const float* __restrict__ W2, const float* __restrict__ b2,
    float* __restrict__ out, long long E, int N) {
    long long g = (((long long)blockIdx.x * blockDim.x) + threadIdx.x) >> 4;
    const int sl = threadIdx.x & 15;
    if (g >= E) return;
    int r = row[g], c = col[g];
    u16x8 pv = *(const u16x8*)(P + (size_t)r * 128 + sl * 8);
    u16x8 qv = *(const u16x8*)(Q + (size_t)c * 128 + sl * 8);
    const float4* w2 = (const float4*)W2 + sl * 4;   // [128][2] f32, 16 floats/lane
    float l0 = 0.f, l1 = 0.f;
    #pragma unroll
    for (int jj = 0; jj < 4; ++jj) {
        float h0 = fmaxf(bf2f(pv[2 * jj])     + bf2f(qv[2 * jj]), 0.f);
        float h1 = fmaxf(bf2f(pv[2 * jj + 1]) + bf2f(qv[2 * jj + 1]), 0.f);
        float4 wv = w2[jj];
        l0 += h0 * wv.x + h1 * wv.z;
        l1 += h0 * wv.y + h1 * wv.w;
    }
    #pragma unroll
    for (int o = 1; o < 16; o <<= 1) { l0 += __shfl_xor(l0, o); l1 += __shfl_xor(l1, o); }
    if (sl == 0) {
        l0 += b2[0]; l1 += b2[1];
        float mm = fmaxf(l0, l1);
        float e0 = __expf(l0 - mm), e1 = __expf(l1 - mm);
        float inv = 1.f / (e0 + e1);
        out[2 * (long long)N + 2 * g]     = e0 * inv;
        out[2 * (long long)N + 2 * g + 1] = e1 * inv;
    }
}

// ---------------------------------------------------------------------------
extern "C" void kernel_launch(void* const* d_in, const int* in_sizes, int n_in,
                              void* d_out, int out_size, void* d_ws, size_t ws_size,
                              hipStream_t stream) {
    if (n_in < NIN) return;
    const int N = in_sizes[0] / 3;
    const int E = in_sizes[1] / 2;

    char* ws = (char*)d_ws;
    size_t off = 0;
    auto alloc = [&](size_t bytes) -> char* {
        char* p = ws + off;
        off = (off + bytes + 255) & ~(size_t)255;
        return p;
    };
    int* flags = (int*)alloc(32 * sizeof(int));
    float* canon[NIN];
    for (int i = 0; i < NIN; ++i) canon[i] = nullptr;
    for (int i = 0; i < NIN; ++i) {
        if (i == 1 || (i >= 10 && i <= 17)) continue;   // LSTM weights read raw
        canon[i] = (float*)alloc((size_t)in_sizes[i] * 4);
    }
    int* row32  = (int*)alloc((size_t)E * 4);
    int* col32  = (int*)alloc((size_t)E * 4);
    int* indptr = (int*)alloc((size_t)(N + 1) * 4);
    int* cnt    = (int*)alloc((size_t)N * 4);
    int* colS   = (int*)alloc((size_t)E * 4);
    float* hs   = (float*)alloc((size_t)N * 4);
    float* hd   = (float*)alloc((size_t)N * 4);
    float* hlin = (float*)alloc((size_t)N * 128 * 4);   // reused as hJK later
    float* xs   = (float*)alloc((size_t)3 * N * 128 * 4);
    unsigned short* Bpack = (unsigned short*)alloc((size_t)2 * 10 * 48 * 512 * 2);
    float* bsum = (float*)alloc((size_t)2 * 768 * 4);
    // scoreP [2][3][N] aliases colS (dead after last k_aggr) when it fits
    float* scoreP;
    if ((size_t)E >= (size_t)6 * N) scoreP = (float*)colS;
    else                            scoreP = (float*)alloc((size_t)6 * N * 4);
    if (off > ws_size) return;
    // P/Q (bf16, N*128 each) alias xs (dead after k_jkfin)
    unsigned short* P = (unsigned short*)xs;
    unsigned short* Q = (unsigned short*)xs + (size_t)N * 128;

    InPtrs ip;
    for (int i = 0; i < NIN; ++i) { ip.p[i] = d_in[i]; ip.n[i] = in_sizes[i]; }

    k_sniff<<<NIN, 256, 0, stream>>>(ip, flags);
    for (int i = 0; i < NIN; ++i) {
        if (i == 1 || (i >= 10 && i <= 17)) continue;
        int n = in_sizes[i];
        k_convf<<<(n + 255) / 256, 256, 0, stream>>>(d_in[i], canon[i], n, flags, i);
    }
    k_conve<<<(E + 255) / 256, 256, 0, stream>>>(d_in[1], row32, col32, E, flags);
    k_wpack<<<(2 * 10 * 48 * 512 + 255) / 256, 256, 0, stream>>>(
        d_in[10], d_in[11], d_in[14], d_in[15],
        d_in[12], d_in[13], d_in[16], d_in[17], flags, Bpack, bsum);

    // CSR by row (shared across all 3 GAT layers)
    k_zeroi<<<(N + 255) / 256, 256, 0, stream>>>(cnt, N);
    k_hist<<<(E + 255) / 256, 256, 0, stream>>>(row32, cnt, E);
    k_scan<<<1, 1024, 0, stream>>>(cnt, indptr, N);
    k_zeroi<<<(N + 255) / 256, 256, 0, stream>>>(cnt, N);
    k_fill<<<(E + 255) / 256, 256, 0, stream>>>(row32, col32, indptr, cnt, colS, E);

    // GAT layer 0 (in=3)
    k_lin0<<<(N + 3) / 4, 256, 0, stream>>>(canon[0], canon[2], canon[4], canon[5],
                                            hlin, hs, hd, N);
    k_aggr<<<(N + 3) / 4, 256, 0, stream>>>(hlin, hs, hd, indptr, colS, canon[3], xs, N);
    // GAT layers 1..2 (in=128)
    for (int l = 1; l < 3; ++l) {
        const float* W  = canon[6] + (size_t)(l - 1) * 128 * 128;
        const float* bb = canon[7] + (size_t)(l - 1) * 128;
        const float* as = canon[8] + (size_t)(l - 1) * 128;
        const float* ad = canon[9] + (size_t)(l - 1) * 128;
        k_lin<<<(N + 3) / 4, 256, 0, stream>>>(xs + (size_t)(l - 1) * N * 128, W, as, ad,
                                               hlin, hs, hd, N);
        k_aggr<<<(N + 3) / 4, 256, 0, stream>>>(hlin, hs, hd, indptr, colS, bb,
                                                xs + (size_t)l * N * 128, N);
    }

    // fused bidirectional LSTM (MFMA) + JK attention finish
    dim3 lgrid((N + 31) / 32, 2);
    k_lstm_mfma<<<lgrid, 256, 0, stream>>>(xs, Bpack, bsum, canon[18], scoreP, N);
    k_jkfin<<<(N + 1) / 2, 256, 0, stream>>>(xs, scoreP, hlin, N);

    float* out = (float*)d_out;
    k_nodemlp<<<(N + 3) / 4, 256, 0, stream>>>(hlin, canon[20], canon[21], canon[22],
                                               canon[23], out, N);
    // edge MLP: P/Q precompute (bf16, overwrites dead xs), then gather-dot
    k_pqlin<<<(N + 3) / 4, 256, 0, stream>>>(hlin, canon[24], canon[25], P, Q, N);
    {
        long long tot = (long long)E * 16;
        int blocks = (int)((tot + 255) / 256);
        k_edge2<<<blocks, 256, 0, stream>>>(P, Q, row32, col32, canon[26], canon[27],
                                            out, (long long)E, N);
    }
}

// Round 7
// 1299.999 us; speedup vs baseline: 26.7202x; 1.0312x over previous
//
#include <hip/hip_runtime.h>
#include <cstdint>
#include <cstddef>

// ---------------------------------------------------------------------------
// ParityGameGATNetwork: 3x GATConv -> JK bidirectional LSTM -> node/edge MLPs
// Round 7: (a) LSTM GEMM loop gets explicit B-fragment ping-pong prefetch
// (L2 latency was exposed serially; VGPR headroom freed by dropping min-wave
// bound), (b) xs pipeline stored bf16 end-to-end (halves staging traffic,
// staging becomes pure copy), (c) LSTM A-tile stride 332 (bank-conflict-free).
// ---------------------------------------------------------------------------

#define NIN 28

struct InPtrs { const void* p[NIN]; int n[NIN]; };

typedef short s16x4 __attribute__((ext_vector_type(4)));
typedef short s16x8 __attribute__((ext_vector_type(8)));
typedef float f32x4 __attribute__((ext_vector_type(4)));
typedef unsigned short u16x8 __attribute__((ext_vector_type(8)));

__device__ __forceinline__ float bf2f(unsigned short v) {
    unsigned int u = ((unsigned int)v) << 16;
    return __uint_as_float(u);
}

__device__ __forceinline__ unsigned short f2bf(float x) {
    unsigned int u = __float_as_uint(x);
    unsigned int r = u + 0x7fffu + ((u >> 16) & 1u);
    return (unsigned short)(r >> 16);
}

__device__ __forceinline__ float rdx(const void* p, size_t i, int isf32) {
    return isf32 ? ((const float*)p)[i] : bf2f(((const unsigned short*)p)[i]);
}

__device__ __forceinline__ float fast_tanh(float x) {
    float e = __expf(2.f * x);
    return 1.f - 2.f / (e + 1.f);
}

// ---------------- dtype sniffing -------------------------------------------
__global__ void k_sniff(InPtrs in, int* flags) {
    int ai = blockIdx.x;
    if (ai >= NIN) return;
    __shared__ int cnt;
    if (threadIdx.x == 0) cnt = 0;
    __syncthreads();
    if (ai == 1) {
        const int* w = (const int*)in.p[1];
        int nw = in.n[1] < 512 ? in.n[1] : 512;
        int local = 0;
        for (int i = threadIdx.x; i < nw; i += blockDim.x)
            if ((i & 1) && w[i] != 0) local++;
        atomicAdd(&cnt, local);
        __syncthreads();
        if (threadIdx.x == 0) flags[1] = (cnt < 4) ? 1 : 0;
        return;
    }
    const unsigned short* u = (const unsigned short*)in.p[ai];
    int ns = in.n[ai] < 256 ? in.n[ai] : 256;
    int local = 0;
    for (int i = threadIdx.x; i < ns; i += blockDim.x) {
        if (i & 1) continue;
        unsigned short v = u[i];
        int e = (v >> 7) & 0xff;
        if ((v & 0x7fff) != 0 && (e < 100 || e > 154)) local++;
    }
    atomicAdd(&cnt, local);
    __syncthreads();
    if (threadIdx.x == 0) flags[ai] = (cnt * 4 >= ns) ? 1 : 0;
}

__global__ void k_convf(const void* src, float* dst, int n, const int* flags, int ai) {
    int i = blockIdx.x * blockDim.x + threadIdx.x;
    if (i >= n) return;
    if (flags[ai]) dst[i] = ((const float*)src)[i];
    else           dst[i] = bf2f(((const unsigned short*)src)[i]);
}

__global__ void k_conve(const void* src, int* row, int* col, int E, const int* flags) {
    int i = blockIdx.x * blockDim.x + threadIdx.x;
    if (i >= E) return;
    if (flags[1]) {
        const long long* s = (const long long*)src;
        row[i] = (int)s[i];
        col[i] = (int)s[(size_t)E + i];
    } else {
        const int* s = (const int*)src;
        row[i] = s[i];
        col[i] = s[(size_t)E + i];
    }
}

// ---------------- CSR build ------------------------------------------------
__global__ void k_zeroi(int* p, int n) {
    int i = blockIdx.x * blockDim.x + threadIdx.x;
    if (i < n) p[i] = 0;
}

__global__ void k_hist(const int* __restrict__ row, int* __restrict__ cnt, int E) {
    int i = blockIdx.x * blockDim.x + threadIdx.x;
    if (i < E) atomicAdd(&cnt[row[i]], 1);
}

__global__ void k_scan(const int* __restrict__ deg, int* __restrict__ indptr, int N) {
    __shared__ int buf[1024];
    __shared__ int carryS;
    const int t = threadIdx.x;
    if (t == 0) carryS = 0;
    __syncthreads();
    for (int base = 0; base < N; base += 1024) {
        int v = (base + t < N) ? deg[base + t] : 0;
        buf[t] = v;
        __syncthreads();
        for (int ofs = 1; ofs < 1024; ofs <<= 1) {
            int add = (t >= ofs) ? buf[t - ofs] : 0;
            __syncthreads();
            buf[t] += add;
            __syncthreads();
        }
        int carry = carryS;
        if (base + t < N) indptr[base + t] = carry + buf[t] - v;
        __syncthreads();
        if (t == 1023) carryS = carry + buf[1023];
        __syncthreads();
    }
    if (t == 0) indptr[N] = carryS;
}

__global__ void k_fill(const int* __restrict__ row, const int* __restrict__ col,
                       const int* __restrict__ indptr, int* __restrict__ cur,
                       int* __restrict__ colS, int E) {
    int i = blockIdx.x * blockDim.x + threadIdx.x;
    if (i >= E) return;
    int r = row[i];
    int p = indptr[r] + atomicAdd(&cur[r], 1);
    colS[p] = col[i];
}

// ---------------- GAT linear (h = x @ W) + a_src/a_dst epilogue ------------
__global__ __launch_bounds__(256) void k_lin0(
    const float* __restrict__ x, const float* __restrict__ W0,
    const float* __restrict__ asrc, const float* __restrict__ adst,
    float* __restrict__ hlin, float* __restrict__ hs, float* __restrict__ hd, int N) {
    const int wid = threadIdx.x >> 6, lane = threadIdx.x & 63;
    const int n = blockIdx.x * 4 + wid;
    if (n >= N) return;
    float x0 = x[(size_t)n * 3], x1 = x[(size_t)n * 3 + 1], x2 = x[(size_t)n * 3 + 2];
    const int c0 = lane, c1 = lane + 64;
    float h0 = x0 * W0[c0] + x1 * W0[128 + c0] + x2 * W0[256 + c0];
    float h1 = x0 * W0[c1] + x1 * W0[128 + c1] + x2 * W0[256 + c1];
    hlin[(size_t)n * 128 + c0] = h0;
    hlin[(size_t)n * 128 + c1] = h1;
    float sp = h0 * asrc[c0] + h1 * asrc[c1];
    float dp = h0 * adst[c0] + h1 * adst[c1];
    for (int o = 32; o; o >>= 1) { sp += __shfl_down(sp, o); dp += __shfl_down(dp, o); }
    if (lane == 0) { hs[n] = sp; hd[n] = dp; }
}

// xin is bf16 now
__global__ __launch_bounds__(256) void k_lin(
    const unsigned short* __restrict__ xin, const float* __restrict__ W,
    const float* __restrict__ asrc, const float* __restrict__ adst,
    float* __restrict__ hlin, float* __restrict__ hs, float* __restrict__ hd, int N) {
    __shared__ float xl[4][128];
    const int wid = threadIdx.x >> 6, lane = threadIdx.x & 63;
    const int n = blockIdx.x * 4 + wid;
    if (n < N) {
        xl[wid][lane]      = bf2f(xin[(size_t)n * 128 + lane]);
        xl[wid][lane + 64] = bf2f(xin[(size_t)n * 128 + lane + 64]);
    }
    __syncthreads();
    if (n >= N) return;
    const int c0 = lane, c1 = lane + 64;
    float h0 = 0.f, h1 = 0.f;
    #pragma unroll 4
    for (int k = 0; k < 128; ++k) {
        float xv = xl[wid][k];
        h0 += xv * W[k * 128 + c0];
        h1 += xv * W[k * 128 + c1];
    }
    hlin[(size_t)n * 128 + c0] = h0;
    hlin[(size_t)n * 128 + c1] = h1;
    float sp = h0 * asrc[c0] + h1 * asrc[c1];
    float dp = h0 * adst[c0] + h1 * adst[c1];
    for (int o = 32; o; o >>= 1) { sp += __shfl_down(sp, o); dp += __shfl_down(dp, o); }
    if (lane == 0) { hs[n] = sp; hd[n] = dp; }
}

// ---------------- GAT aggregation: online segment softmax, 4-way unrolled --
// Output written as bf16 (xsb layer).
__global__ __launch_bounds__(256) void k_aggr(
    const float* __restrict__ hlin, const float* __restrict__ hs, const float* __restrict__ hd,
    const int* __restrict__ indptr, const int* __restrict__ colS,
    const float* __restrict__ b, unsigned short* __restrict__ xout, int N) {
    const int wid = threadIdx.x >> 6, lane = threadIdx.x & 63;
    const int n = blockIdx.x * 4 + wid;
    if (n >= N) return;
    const int s = indptr[n], epos = indptr[n + 1];
    const float hdv = hd[n];
    const int c0 = lane, c1 = lane + 64;
    float m = -1e30f, d = 0.f, a0 = 0.f, a1 = 0.f;
    int idx = s;
    for (; idx + 4 <= epos; idx += 4) {
        int col0 = colS[idx], col1 = colS[idx + 1], col2 = colS[idx + 2], col3 = colS[idx + 3];
        float e0 = hs[col0] + hdv, e1 = hs[col1] + hdv;
        float e2 = hs[col2] + hdv, e3 = hs[col3] + hdv;
        e0 = (e0 > 0.f) ? e0 : 0.2f * e0;
        e1 = (e1 > 0.f) ? e1 : 0.2f * e1;
        e2 = (e2 > 0.f) ? e2 : 0.2f * e2;
        e3 = (e3 > 0.f) ? e3 : 0.2f * e3;
        const float* h0p = hlin + (size_t)col0 * 128;
        const float* h1p = hlin + (size_t)col1 * 128;
        const float* h2p = hlin + (size_t)col2 * 128;
        const float* h3p = hlin + (size_t)col3 * 128;
        float v00 = h0p[c0], v01 = h0p[c1];
        float v10 = h1p[c0], v11 = h1p[c1];
        float v20 = h2p[c0], v21 = h2p[c1];
        float v30 = h3p[c0], v31 = h3p[c1];
        float m4 = fmaxf(fmaxf(e0, e1), fmaxf(e2, e3));
        if (m4 > m) {
            float sc = __expf(m - m4);
            a0 *= sc; a1 *= sc; d *= sc; m = m4;
        }
        float w0 = __expf(e0 - m), w1 = __expf(e1 - m);
        float w2 = __expf(e2 - m), w3 = __expf(e3 - m);
        a0 += w0 * v00 + w1 * v10 + w2 * v20 + w3 * v30;
        a1 += w0 * v01 + w1 * v11 + w2 * v21 + w3 * v31;
        d  += w0 + w1 + w2 + w3;
    }
    for (; idx < epos; ++idx) {
        int col = colS[idx];
        float e = hs[col] + hdv;
        e = (e > 0.f) ? e : 0.2f * e;
        const float* hr = hlin + (size_t)col * 128;
        float v0 = hr[c0], v1 = hr[c1];
        if (e > m) {
            float sc = __expf(m - e);
            a0 = a0 * sc + v0;
            a1 = a1 * sc + v1;
            d  = d * sc + 1.f;
            m  = e;
        } else {
            float w = __expf(e - m);
            a0 += w * v0;
            a1 += w * v1;
            d  += w;
        }
    }
    float inv = 1.f / (d + 1e-16f);
    float r0 = a0 * inv + b[c0];
    float r1 = a1 * inv + b[c1];
    xout[(size_t)n * 128 + c0] = f2bf(fmaxf(r0, 0.f));
    xout[(size_t)n * 128 + c1] = f2bf(fmaxf(r1, 0.f));
}

// ---------------- LSTM weight pack into MFMA fragment order ----------------
__global__ void k_wpack(const void* Wihf, const void* Whhf,
                        const void* Wihb, const void* Whhb,
                        const void* bihf, const void* bhhf,
                        const void* bihb, const void* bhhb,
                        const int* __restrict__ flags,
                        unsigned short* __restrict__ Bpack, float* __restrict__ bsum) {
    int idx = blockIdx.x * blockDim.x + threadIdx.x;
    const int TOT = 2 * 10 * 48 * 512;
    if (idx < TOT) {
        int dir = idx / (10 * 48 * 512);
        int r   = idx % (10 * 48 * 512);
        int kb  = r / (48 * 512);
        int r2  = r % (48 * 512);
        int f   = r2 / 512;
        int q   = r2 % 512;
        int lane = q >> 3, j = q & 7;
        int k   = kb * 32 + ((j >> 2) * 16) + ((lane >> 4) * 4) + (j & 3);
        int col = f * 16 + (lane & 15);
        float v;
        if (k < 128)
            v = dir ? rdx(Wihb, (size_t)col * 128 + k, flags[14])
                    : rdx(Wihf, (size_t)col * 128 + k, flags[10]);
        else
            v = dir ? rdx(Whhb, (size_t)col * 192 + (k - 128), flags[15])
                    : rdx(Whhf, (size_t)col * 192 + (k - 128), flags[11]);
        Bpack[idx] = f2bf(v);
    }
    if (idx < 2 * 768) {
        int d = idx / 768, j = idx % 768;
        bsum[idx] = d ? rdx(bihb, j, flags[16]) + rdx(bhhb, j, flags[17])
                      : rdx(bihf, j, flags[12]) + rdx(bhhf, j, flags[13]);
    }
}

// ---------------- fused bidirectional LSTM, MFMA GEMM ----------------------
// Grid (ceil(N/32), 2); 256 threads = 4 waves. B fragments ping-pong
// prefetched in registers (kb+1's 12 loads issued before kb's 24 MFMAs).
__global__ __launch_bounds__(256) void k_lstm_mfma(
    const unsigned short* __restrict__ xsb,  // [3][N][128] bf16
    const unsigned short* __restrict__ Bpack,// [2][10][48][512] bf16
    const float* __restrict__ bsum,          // [2][768]
    const float* __restrict__ attW,          // [384]
    float* __restrict__ scoreP,              // [2][3][N]
    int N) {
    __shared__ unsigned short AS[32][332];   // x in [0,128), h in [128,320); stride 332
    __shared__ float scoreS[32];
    const int t = threadIdx.x;
    const int w = t >> 6, lane = t & 63;
    const int dir = blockIdx.y;
    const int n0 = blockIdx.x * 32;
    const int ccol = lane & 15;
    const int lrow = (lane >> 4) * 4;
    const int akl = (lane >> 4) * 4;

    float bI[3], bF[3], bG[3], bO[3], awt[3];
    #pragma unroll
    for (int a = 0; a < 3; ++a) {
        int m = 16 * (w + 4 * a) + ccol;
        bI[a] = bsum[dir * 768 + m];
        bF[a] = bsum[dir * 768 + 192 + m];
        bG[a] = bsum[dir * 768 + 384 + m];
        bO[a] = bsum[dir * 768 + 576 + m];
        awt[a] = attW[dir * 192 + m];
    }
    float cst[24];
    #pragma unroll
    for (int i = 0; i < 24; ++i) cst[i] = 0.f;

    const unsigned short* Bd = Bpack + (size_t)dir * 10 * 48 * 512;

    for (int s = 0; s < 3; ++s) {
        const int l = dir ? (2 - s) : s;
        // ---- stage x tile: pure bf16 copy, 2 x 16B per thread ----
        {
            const unsigned short* xsrc = xsb + ((size_t)l * N + n0) * 128;
            #pragma unroll
            for (int it = 0; it < 2; ++it) {
                int i = t + it * 256;            // 0..511
                int r = i >> 4, kq = (i & 15) * 8;
                u16x8 v = (u16x8)(0);
                if (n0 + r < N) v = *(const u16x8*)(xsrc + (size_t)r * 128 + kq);
                *(u16x8*)&AS[r][kq] = v;
            }
        }
        if (t < 32) scoreS[t] = 0.f;
        __syncthreads();

        // ---- MFMA GEMM over K with B ping-pong prefetch ----
        const int KB = s ? 10 : 4;
        f32x4 acc0[12], acc1[12];
        #pragma unroll
        for (int f = 0; f < 12; ++f) {
            acc0[f] = (f32x4)(0.f);
            acc1[f] = (f32x4)(0.f);
        }
        s16x8 bA[12], bB[12];
        {
            const unsigned short* bb = Bd + ((size_t)0 * 48 + w) * 512 + lane * 8;
            #pragma unroll
            for (int f = 0; f < 12; ++f) bA[f] = *(const s16x8*)(bb + (size_t)f * 2048);
        }
        for (int kb = 0; kb < KB; kb += 2) {
            {   // prefetch kb+1 into bB (kb+1 <= KB-1 since KB even)
                const unsigned short* bb = Bd + ((size_t)(kb + 1) * 48 + w) * 512 + lane * 8;
                #pragma unroll
                for (int f = 0; f < 12; ++f) bB[f] = *(const s16x8*)(bb + (size_t)f * 2048);
            }
            {   // A frags for kb, MFMA on bA
                const int k0 = kb * 32 + akl;
                s16x4 a0lo = *(const s16x4*)&AS[ccol][k0];
                s16x4 a0hi = *(const s16x4*)&AS[ccol][k0 + 16];
                s16x4 a1lo = *(const s16x4*)&AS[16 + ccol][k0];
                s16x4 a1hi = *(const s16x4*)&AS[16 + ccol][k0 + 16];
                s16x8 a0 = __builtin_shufflevector(a0lo, a0hi, 0, 1, 2, 3, 4, 5, 6, 7);
                s16x8 a1 = __builtin_shufflevector(a1lo, a1hi, 0, 1, 2, 3, 4, 5, 6, 7);
                #pragma unroll
                for (int f = 0; f < 12; ++f) {
                    acc0[f] = __builtin_amdgcn_mfma_f32_16x16x32_bf16(a0, bA[f], acc0[f], 0, 0, 0);
                    acc1[f] = __builtin_amdgcn_mfma_f32_16x16x32_bf16(a1, bA[f], acc1[f], 0, 0, 0);
                }
            }
            if (kb + 2 < KB) {  // prefetch kb+2 into bA
                const unsigned short* bb = Bd + ((size_t)(kb + 2) * 48 + w) * 512 + lane * 8;
                #pragma unroll
                for (int f = 0; f < 12; ++f) bA[f] = *(const s16x8*)(bb + (size_t)f * 2048);
            }
            {   // A frags for kb+1, MFMA on bB
                const int k0 = (kb + 1) * 32 + akl;
                s16x4 a0lo = *(const s16x4*)&AS[ccol][k0];
                s16x4 a0hi = *(const s16x4*)&AS[ccol][k0 + 16];
                s16x4 a1lo = *(const s16x4*)&AS[16 + ccol][k0];
                s16x4 a1hi = *(const s16x4*)&AS[16 + ccol][k0 + 16];
                s16x8 a0 = __builtin_shufflevector(a0lo, a0hi, 0, 1, 2, 3, 4, 5, 6, 7);
                s16x8 a1 = __builtin_shufflevector(a1lo, a1hi, 0, 1, 2, 3, 4, 5, 6, 7);
                #pragma unroll
                for (int f = 0; f < 12; ++f) {
                    acc0[f] = __builtin_amdgcn_mfma_f32_16x16x32_bf16(a0, bB[f], acc0[f], 0, 0, 0);
                    acc1[f] = __builtin_amdgcn_mfma_f32_16x16x32_bf16(a1, bB[f], acc1[f], 0, 0, 0);
                }
            }
        }
        __syncthreads();   // all A reads done before h overwrite

        // ---- cell epilogue (pure-register gates) ----
        float sprow[8];
        #pragma unroll
        for (int i = 0; i < 8; ++i) sprow[i] = 0.f;
        auto cell = [&](f32x4 (&accT)[12], int tile) {
            #pragma unroll
            for (int a = 0; a < 3; ++a) {
                #pragma unroll
                for (int reg = 0; reg < 4; ++reg) {
                    float gI = accT[a][reg]     + bI[a];
                    float gF = accT[3 + a][reg] + bF[a];
                    float gG = accT[6 + a][reg] + bG[a];
                    float gO = accT[9 + a][reg] + bO[a];
                    float ig = 1.f / (1.f + __expf(-gI));
                    float fg = 1.f / (1.f + __expf(-gF));
                    float gt = fast_tanh(gG);
                    float og = 1.f / (1.f + __expf(-gO));
                    int ci = tile * 12 + a * 4 + reg;
                    float cn = fg * cst[ci] + ig * gt;
                    cst[ci] = cn;
                    float hh = og * fast_tanh(cn);
                    int row = tile * 16 + lrow + reg;
                    int m = 16 * (w + 4 * a) + ccol;
                    AS[row][128 + m] = f2bf(hh);
                    sprow[tile * 4 + reg] += hh * awt[a];
                }
            }
        };
        cell(acc0, 0);
        cell(acc1, 1);
        #pragma unroll
        for (int o = 1; o < 16; o <<= 1) {
            #pragma unroll
            for (int i = 0; i < 8; ++i) sprow[i] += __shfl_xor(sprow[i], o);
        }
        if (ccol == 0) {
            #pragma unroll
            for (int i = 0; i < 8; ++i)
                atomicAdd(&scoreS[(i >> 2) * 16 + lrow + (i & 3)], sprow[i]);
        }
        __syncthreads();
        if (t < 32 && n0 + t < N)
            scoreP[(size_t)(dir * 3 + l) * N + n0 + t] = scoreS[t];
    }
}

// ---------------- JK finish: layer softmax + weighted sum ------------------
__global__ __launch_bounds__(256) void k_jkfin(
    const unsigned short* __restrict__ xsb, const float* __restrict__ scoreP,
    float* __restrict__ hJK, int N) {
    const int nl = threadIdx.x >> 7;           // 2 nodes per block
    const int ch = threadIdx.x & 127;
    const int n = blockIdx.x * 2 + nl;
    if (n >= N) return;
    float s0 = scoreP[n]                  + scoreP[(size_t)3 * N + n];
    float s1 = scoreP[(size_t)N + n]      + scoreP[(size_t)4 * N + n];
    float s2 = scoreP[(size_t)2 * N + n]  + scoreP[(size_t)5 * N + n];
    float m = fmaxf(s0, fmaxf(s1, s2));
    float e0 = __expf(s0 - m), e1 = __expf(s1 - m), e2 = __expf(s2 - m);
    float inv = 1.f / (e0 + e1 + e2);
    e0 *= inv; e1 *= inv; e2 *= inv;
    const size_t nb = (size_t)n * 128 + ch;
    const size_t L1o = (size_t)N * 128, L2o = 2 * (size_t)N * 128;
    hJK[nb] = e0 * bf2f(xsb[nb]) + e1 * bf2f(xsb[L1o + nb]) + e2 * bf2f(xsb[L2o + nb]);
}

// ---------------- node classifier ------------------------------------------
__global__ __launch_bounds__(256) void k_nodemlp(
    const float* __restrict__ hJK, const float* __restrict__ W1, const float* __restrict__ b1,
    const float* __restrict__ W2, const float* __restrict__ b2,
    float* __restrict__ out, int N) {
    __shared__ float xl[4][128];
    const int wid = threadIdx.x >> 6, lane = threadIdx.x & 63;
    const int n = blockIdx.x * 4 + wid;
    if (n < N) {
        xl[wid][lane]      = hJK[(size_t)n * 128 + lane];
        xl[wid][lane + 64] = hJK[(size_t)n * 128 + lane + 64];
    }
    __syncthreads();
    if (n >= N) return;
    const int c0 = lane, c1 = lane + 64;
    float h0 = 0.f, h1 = 0.f;
    #pragma unroll 4
    for (int k = 0; k < 128; ++k) {
        float xv = xl[wid][k];
        h0 += xv * W1[k * 128 + c0];
        h1 += xv * W1[k * 128 + c1];
    }
    h0 = fmaxf(h0 + b1[c0], 0.f);
    h1 = fmaxf(h1 + b1[c1], 0.f);
    float p0 = h0 * W2[c0 * 2 + 0] + h1 * W2[c1 * 2 + 0];
    float p1 = h0 * W2[c0 * 2 + 1] + h1 * W2[c1 * 2 + 1];
    for (int o = 32; o; o >>= 1) { p0 += __shfl_down(p0, o); p1 += __shfl_down(p1, o); }
    if (lane == 0) {
        float l0 = p0 + b2[0], l1 = p1 + b2[1];
        float mm = fmaxf(l0, l1);
        float e0 = __expf(l0 - mm), e1 = __expf(l1 - mm);
        float inv = 1.f / (e0 + e1);
        out[2 * (size_t)n]     = e0 * inv;
        out[2 * (size_t)n + 1] = e1 * inv;
    }
}

// ---------------- edge MLP: per-node P/Q precompute (bf16 out) -------------
__global__ __launch_bounds__(256) void k_pqlin(
    const float* __restrict__ hJK, const float* __restrict__ W1,
    const float* __restrict__ b1,
    unsigned short* __restrict__ P, unsigned short* __restrict__ Q, int N) {
    __shared__ float xl[4][128];
    const int wid = threadIdx.x >> 6, lane = threadIdx.x & 63;
    const int n = blockIdx.x * 4 + wid;
    if (n < N) {
        xl[wid][lane]      = hJK[(size_t)n * 128 + lane];
        xl[wid][lane + 64] = hJK[(size_t)n * 128 + lane + 64];
    }
    __syncthreads();
    if (n >= N) return;
    const int c0 = lane, c1 = lane + 64;
    float p0 = 0.f, p1 = 0.f, q0 = 0.f, q1 = 0.f;
    #pragma unroll 4
    for (int k = 0; k < 128; ++k) {
        float xv = xl[wid][k];
        p0 += xv * W1[k * 128 + c0];
        p1 += xv * W1[k * 128 + c1];
        q0 += xv * W1[(128 + k) * 128 + c0];
        q1 += xv * W1[(128 + k) * 128 + c1];
    }
    P[(size_t)n * 128 + c0] = f2bf(p0 + b1[c0]);
    P[(size_t)n * 128 + c1] = f2bf(p1 + b1[c1]);
    Q[(size_t)n * 128 + c0] = f2bf(q0);
    Q[(size_t)n * 128 + c1] = f2bf(q1);
}

// ---------------- edge MLP finish: gather-add-relu-dot (bf16 P/Q) ----------
__global__ __launch_bounds__(256) void k_edge2(
    const unsigned short* __restrict__ P, const unsigned short* __restrict__ Q,
    const int* __restrict__ row, const int* __restrict__ col,
    const float* __restrict__ W2, const float* __restrict__ b2,
    float* __restrict__ out, long long E, int N) {
    long long g = (((long long)blockIdx.x * blockDim.x) + threadIdx.x) >> 4;
    const int sl = threadIdx.x & 15;
    if (g >= E) return;
    int r = row[g], c = col[g];
    u16x8 pv = *(const u16x8*)(P + (size_t)r * 128 + sl * 8);
    u16x8 qv = *(const u16x8*)(Q + (size_t)c * 128 + sl * 8);
    const float4* w2 = (const float4*)W2 + sl * 4;
    float l0 = 0.f, l1 = 0.f;
    #pragma unroll
    for (int jj = 0; jj < 4; ++jj) {
        float h0 = fmaxf(bf2f(pv[2 * jj])     + bf2f(qv[2 * jj]), 0.f);
        float h1 = fmaxf(bf2f(pv[2 * jj + 1]) + bf2f(qv[2 * jj + 1]), 0.f);
        float4 wv = w2[jj];
        l0 += h0 * wv.x + h1 * wv.z;
        l1 += h0 * wv.y + h1 * wv.w;
    }
    #pragma unroll
    for (int o = 1; o < 16; o <<= 1) { l0 += __shfl_xor(l0, o); l1 += __shfl_xor(l1, o); }
    if (sl == 0) {
        l0 += b2[0]; l1 += b2[1];
        float mm = fmaxf(l0, l1);
        float e0 = __expf(l0 - mm), e1 = __expf(l1 - mm);
        float inv = 1.f / (e0 + e1);
        out[2 * (long long)N + 2 * g]     = e0 * inv;
        out[2 * (long long)N + 2 * g + 1] = e1 * inv;
    }
}

// ---------------------------------------------------------------------------
extern "C" void kernel_launch(void* const* d_in, const int* in_sizes, int n_in,
                              void* d_out, int out_size, void* d_ws, size_t ws_size,
                              hipStream_t stream) {
    if (n_in < NIN) return;
    const int N = in_sizes[0] / 3;
    const int E = in_sizes[1] / 2;

    char* ws = (char*)d_ws;
    size_t off = 0;
    auto alloc = [&](size_t bytes) -> char* {
        char* p = ws + off;
        off = (off + bytes + 255) & ~(size_t)255;
        return p;
    };
    int* flags = (int*)alloc(32 * sizeof(int));
    float* canon[NIN];
    for (int i = 0; i < NIN; ++i) canon[i] = nullptr;
    for (int i = 0; i < NIN; ++i) {
        if (i == 1 || (i >= 10 && i <= 17)) continue;   // LSTM weights read raw
        canon[i] = (float*)alloc((size_t)in_sizes[i] * 4);
    }
    int* row32  = (int*)alloc((size_t)E * 4);
    int* col32  = (int*)alloc((size_t)E * 4);
    int* indptr = (int*)alloc((size_t)(N + 1) * 4);
    int* cnt    = (int*)alloc((size_t)N * 4);
    int* colS   = (int*)alloc((size_t)E * 4);
    float* hs   = (float*)alloc((size_t)N * 4);
    float* hd   = (float*)alloc((size_t)N * 4);
    float* hlin = (float*)alloc((size_t)N * 128 * 4);   // reused as hJK later
    unsigned short* xsb = (unsigned short*)alloc((size_t)3 * N * 128 * 2);  // bf16 xs
    unsigned short* Bpack = (unsigned short*)alloc((size_t)2 * 10 * 48 * 512 * 2);
    float* bsum = (float*)alloc((size_t)2 * 768 * 4);
    float* scoreP;
    if ((size_t)E >= (size_t)6 * N) scoreP = (float*)colS;   // dead after last aggr
    else                            scoreP = (float*)alloc((size_t)6 * N * 4);
    if (off > ws_size) return;
    // P/Q (bf16, N*128 each) alias xsb (dead after k_jkfin)
    unsigned short* P = xsb;
    unsigned short* Q = xsb + (size_t)N * 128;

    InPtrs ip;
    for (int i = 0; i < NIN; ++i) { ip.p[i] = d_in[i]; ip.n[i] = in_sizes[i]; }

    k_sniff<<<NIN, 256, 0, stream>>>(ip, flags);
    for (int i = 0; i < NIN; ++i) {
        if (i == 1 || (i >= 10 && i <= 17)) continue;
        int n = in_sizes[i];
        k_convf<<<(n + 255) / 256, 256, 0, stream>>>(d_in[i], canon[i], n, flags, i);
    }
    k_conve<<<(E + 255) / 256, 256, 0, stream>>>(d_in[1], row32, col32, E, flags);
    k_wpack<<<(2 * 10 * 48 * 512 + 255) / 256, 256, 0, stream>>>(
        d_in[10], d_in[11], d_in[14], d_in[15],
        d_in[12], d_in[13], d_in[16], d_in[17], flags, Bpack, bsum);

    // CSR by row (shared across all 3 GAT layers)
    k_zeroi<<<(N + 255) / 256, 256, 0, stream>>>(cnt, N);
    k_hist<<<(E + 255) / 256, 256, 0, stream>>>(row32, cnt, E);
    k_scan<<<1, 1024, 0, stream>>>(cnt, indptr, N);
    k_zeroi<<<(N + 255) / 256, 256, 0, stream>>>(cnt, N);
    k_fill<<<(E + 255) / 256, 256, 0, stream>>>(row32, col32, indptr, cnt, colS, E);

    // GAT layer 0 (in=3)
    k_lin0<<<(N + 3) / 4, 256, 0, stream>>>(canon[0], canon[2], canon[4], canon[5],
                                            hlin, hs, hd, N);
    k_aggr<<<(N + 3) / 4, 256, 0, stream>>>(hlin, hs, hd, indptr, colS, canon[3], xsb, N);
    // GAT layers 1..2 (in=128, bf16 input)
    for (int l = 1; l < 3; ++l) {
        const float* W  = canon[6] + (size_t)(l - 1) * 128 * 128;
        const float* bb = canon[7] + (size_t)(l - 1) * 128;
        const float* as = canon[8] + (size_t)(l - 1) * 128;
        const float* ad = canon[9] + (size_t)(l - 1) * 128;
        k_lin<<<(N + 3) / 4, 256, 0, stream>>>(xsb + (size_t)(l - 1) * N * 128, W, as, ad,
                                               hlin, hs, hd, N);
        k_aggr<<<(N + 3) / 4, 256, 0, stream>>>(hlin, hs, hd, indptr, colS, bb,
                                                xsb + (size_t)l * N * 128, N);
    }

    // fused bidirectional LSTM (MFMA, prefetched) + JK attention finish
    dim3 lgrid((N + 31) / 32, 2);
    k_lstm_mfma<<<lgrid, 256, 0, stream>>>(xsb, Bpack, bsum, canon[18], scoreP, N);
    k_jkfin<<<(N + 1) / 2, 256, 0, stream>>>(xsb, scoreP, hlin, N);

    float* out = (float*)d_out;
    k_nodemlp<<<(N + 3) / 4, 256, 0, stream>>>(hlin, canon[20], canon[21], canon[22],
                                               canon[23], out, N);
    // edge MLP: P/Q precompute (bf16, overwrites dead xsb), then gather-dot
    k_pqlin<<<(N + 3) / 4, 256, 0, stream>>>(hlin, canon[24], canon[25], P, Q, N);
    {
        long long tot = (long long)E * 16;
        int blocks = (int)((tot + 255) / 256);
        k_edge2<<<blocks, 256, 0, stream>>>(P, Q, row32, col32, canon[26], canon[27],
                                            out, (long long)E, N);
    }
}

// Round 8
// 1222.000 us; speedup vs baseline: 28.4257x; 1.0638x over previous
//
#include <hip/hip_runtime.h>
#include <cstdint>
#include <cstddef>

// ---------------------------------------------------------------------------
// ParityGameGATNetwork: 3x GATConv -> JK bidirectional LSTM -> node/edge MLPs
// Round 8: (a) LSTM GEMM split into 3 column passes (8 acc frags live at a
// time -> low VGPR -> occupancy) with h double-buffered in LDS (one less
// barrier/step), (b) hlin stored bf16 (halves aggr gather traffic),
// (c) k_lin / k_pqlin / k_nodemlp process 2 nodes per wave (halves W re-read).
// ---------------------------------------------------------------------------

#define NIN 28

struct InPtrs { const void* p[NIN]; int n[NIN]; };

typedef short s16x4 __attribute__((ext_vector_type(4)));
typedef short s16x8 __attribute__((ext_vector_type(8)));
typedef float f32x4 __attribute__((ext_vector_type(4)));
typedef unsigned short u16x8 __attribute__((ext_vector_type(8)));

__device__ __forceinline__ float bf2f(unsigned short v) {
    unsigned int u = ((unsigned int)v) << 16;
    return __uint_as_float(u);
}

__device__ __forceinline__ unsigned short f2bf(float x) {
    unsigned int u = __float_as_uint(x);
    unsigned int r = u + 0x7fffu + ((u >> 16) & 1u);
    return (unsigned short)(r >> 16);
}

__device__ __forceinline__ float rdx(const void* p, size_t i, int isf32) {
    return isf32 ? ((const float*)p)[i] : bf2f(((const unsigned short*)p)[i]);
}

__device__ __forceinline__ float fast_tanh(float x) {
    float e = __expf(2.f * x);
    return 1.f - 2.f / (e + 1.f);
}

// ---------------- dtype sniffing -------------------------------------------
__global__ void k_sniff(InPtrs in, int* flags) {
    int ai = blockIdx.x;
    if (ai >= NIN) return;
    __shared__ int cnt;
    if (threadIdx.x == 0) cnt = 0;
    __syncthreads();
    if (ai == 1) {
        const int* w = (const int*)in.p[1];
        int nw = in.n[1] < 512 ? in.n[1] : 512;
        int local = 0;
        for (int i = threadIdx.x; i < nw; i += blockDim.x)
            if ((i & 1) && w[i] != 0) local++;
        atomicAdd(&cnt, local);
        __syncthreads();
        if (threadIdx.x == 0) flags[1] = (cnt < 4) ? 1 : 0;
        return;
    }
    const unsigned short* u = (const unsigned short*)in.p[ai];
    int ns = in.n[ai] < 256 ? in.n[ai] : 256;
    int local = 0;
    for (int i = threadIdx.x; i < ns; i += blockDim.x) {
        if (i & 1) continue;
        unsigned short v = u[i];
        int e = (v >> 7) & 0xff;
        if ((v & 0x7fff) != 0 && (e < 100 || e > 154)) local++;
    }
    atomicAdd(&cnt, local);
    __syncthreads();
    if (threadIdx.x == 0) flags[ai] = (cnt * 4 >= ns) ? 1 : 0;
}

__global__ void k_convf(const void* src, float* dst, int n, const int* flags, int ai) {
    int i = blockIdx.x * blockDim.x + threadIdx.x;
    if (i >= n) return;
    if (flags[ai]) dst[i] = ((const float*)src)[i];
    else           dst[i] = bf2f(((const unsigned short*)src)[i]);
}

__global__ void k_conve(const void* src, int* row, int* col, int E, const int* flags) {
    int i = blockIdx.x * blockDim.x + threadIdx.x;
    if (i >= E) return;
    if (flags[1]) {
        const long long* s = (const long long*)src;
        row[i] = (int)s[i];
        col[i] = (int)s[(size_t)E + i];
    } else {
        const int* s = (const int*)src;
        row[i] = s[i];
        col[i] = s[(size_t)E + i];
    }
}

// ---------------- CSR build ------------------------------------------------
__global__ void k_zeroi(int* p, int n) {
    int i = blockIdx.x * blockDim.x + threadIdx.x;
    if (i < n) p[i] = 0;
}

__global__ void k_hist(const int* __restrict__ row, int* __restrict__ cnt, int E) {
    int i = blockIdx.x * blockDim.x + threadIdx.x;
    if (i < E) atomicAdd(&cnt[row[i]], 1);
}

__global__ void k_scan(const int* __restrict__ deg, int* __restrict__ indptr, int N) {
    __shared__ int buf[1024];
    __shared__ int carryS;
    const int t = threadIdx.x;
    if (t == 0) carryS = 0;
    __syncthreads();
    for (int base = 0; base < N; base += 1024) {
        int v = (base + t < N) ? deg[base + t] : 0;
        buf[t] = v;
        __syncthreads();
        for (int ofs = 1; ofs < 1024; ofs <<= 1) {
            int add = (t >= ofs) ? buf[t - ofs] : 0;
            __syncthreads();
            buf[t] += add;
            __syncthreads();
        }
        int carry = carryS;
        if (base + t < N) indptr[base + t] = carry + buf[t] - v;
        __syncthreads();
        if (t == 1023) carryS = carry + buf[1023];
        __syncthreads();
    }
    if (t == 0) indptr[N] = carryS;
}

__global__ void k_fill(const int* __restrict__ row, const int* __restrict__ col,
                       const int* __restrict__ indptr, int* __restrict__ cur,
                       int* __restrict__ colS, int E) {
    int i = blockIdx.x * blockDim.x + threadIdx.x;
    if (i >= E) return;
    int r = row[i];
    int p = indptr[r] + atomicAdd(&cur[r], 1);
    colS[p] = col[i];
}

// ---------------- GAT linear layer 0 (in=3), hlin out bf16 -----------------
__global__ __launch_bounds__(256) void k_lin0(
    const float* __restrict__ x, const float* __restrict__ W0,
    const float* __restrict__ asrc, const float* __restrict__ adst,
    unsigned short* __restrict__ hlin, float* __restrict__ hs, float* __restrict__ hd,
    int N) {
    const int wid = threadIdx.x >> 6, lane = threadIdx.x & 63;
    const int n = blockIdx.x * 4 + wid;
    if (n >= N) return;
    float x0 = x[(size_t)n * 3], x1 = x[(size_t)n * 3 + 1], x2 = x[(size_t)n * 3 + 2];
    const int c0 = lane, c1 = lane + 64;
    float h0 = x0 * W0[c0] + x1 * W0[128 + c0] + x2 * W0[256 + c0];
    float h1 = x0 * W0[c1] + x1 * W0[128 + c1] + x2 * W0[256 + c1];
    hlin[(size_t)n * 128 + c0] = f2bf(h0);
    hlin[(size_t)n * 128 + c1] = f2bf(h1);
    float sp = h0 * asrc[c0] + h1 * asrc[c1];
    float dp = h0 * adst[c0] + h1 * adst[c1];
    for (int o = 32; o; o >>= 1) { sp += __shfl_down(sp, o); dp += __shfl_down(dp, o); }
    if (lane == 0) { hs[n] = sp; hd[n] = dp; }
}

// ---------------- GAT linear (bf16 in, bf16 hlin out), 2 nodes/wave --------
__global__ __launch_bounds__(256) void k_lin(
    const unsigned short* __restrict__ xin, const float* __restrict__ W,
    const float* __restrict__ asrc, const float* __restrict__ adst,
    unsigned short* __restrict__ hlin, float* __restrict__ hs, float* __restrict__ hd,
    int N) {
    __shared__ float xl[8][128];
    const int t = threadIdx.x;
    const int wid = t >> 6, lane = t & 63;
    const int nb = blockIdx.x * 8;
    for (int i = t; i < 1024; i += 256) {
        int r = i >> 7, k = i & 127;
        int n = nb + r;
        xl[r][k] = (n < N) ? bf2f(xin[(size_t)n * 128 + k]) : 0.f;
    }
    __syncthreads();
    const int c0 = lane, c1 = lane + 64;
    const int ra = wid * 2, rb = wid * 2 + 1;
    float h0a = 0.f, h1a = 0.f, h0b = 0.f, h1b = 0.f;
    #pragma unroll 4
    for (int k = 0; k < 128; ++k) {
        float w0 = W[k * 128 + c0], w1 = W[k * 128 + c1];
        float xa = xl[ra][k], xb = xl[rb][k];
        h0a += xa * w0; h1a += xa * w1;
        h0b += xb * w0; h1b += xb * w1;
    }
    const int na = nb + ra, nb2 = nb + rb;
    float spa = h0a * asrc[c0] + h1a * asrc[c1];
    float dpa = h0a * adst[c0] + h1a * adst[c1];
    float spb = h0b * asrc[c0] + h1b * asrc[c1];
    float dpb = h0b * adst[c0] + h1b * adst[c1];
    for (int o = 32; o; o >>= 1) {
        spa += __shfl_down(spa, o); dpa += __shfl_down(dpa, o);
        spb += __shfl_down(spb, o); dpb += __shfl_down(dpb, o);
    }
    if (na < N) {
        hlin[(size_t)na * 128 + c0] = f2bf(h0a);
        hlin[(size_t)na * 128 + c1] = f2bf(h1a);
        if (lane == 0) { hs[na] = spa; hd[na] = dpa; }
    }
    if (nb2 < N) {
        hlin[(size_t)nb2 * 128 + c0] = f2bf(h0b);
        hlin[(size_t)nb2 * 128 + c1] = f2bf(h1b);
        if (lane == 0) { hs[nb2] = spb; hd[nb2] = dpb; }
    }
}

// ---------------- GAT aggregation: online segment softmax, bf16 hlin -------
__global__ __launch_bounds__(256) void k_aggr(
    const unsigned short* __restrict__ hlin, const float* __restrict__ hs,
    const float* __restrict__ hd,
    const int* __restrict__ indptr, const int* __restrict__ colS,
    const float* __restrict__ b, unsigned short* __restrict__ xout, int N) {
    const int wid = threadIdx.x >> 6, lane = threadIdx.x & 63;
    const int n = blockIdx.x * 4 + wid;
    if (n >= N) return;
    const int s = indptr[n], epos = indptr[n + 1];
    const float hdv = hd[n];
    const int c0 = lane, c1 = lane + 64;
    float m = -1e30f, d = 0.f, a0 = 0.f, a1 = 0.f;
    int idx = s;
    for (; idx + 4 <= epos; idx += 4) {
        int col0 = colS[idx], col1 = colS[idx + 1], col2 = colS[idx + 2], col3 = colS[idx + 3];
        float e0 = hs[col0] + hdv, e1 = hs[col1] + hdv;
        float e2 = hs[col2] + hdv, e3 = hs[col3] + hdv;
        e0 = (e0 > 0.f) ? e0 : 0.2f * e0;
        e1 = (e1 > 0.f) ? e1 : 0.2f * e1;
        e2 = (e2 > 0.f) ? e2 : 0.2f * e2;
        e3 = (e3 > 0.f) ? e3 : 0.2f * e3;
        const unsigned short* h0p = hlin + (size_t)col0 * 128;
        const unsigned short* h1p = hlin + (size_t)col1 * 128;
        const unsigned short* h2p = hlin + (size_t)col2 * 128;
        const unsigned short* h3p = hlin + (size_t)col3 * 128;
        float v00 = bf2f(h0p[c0]), v01 = bf2f(h0p[c1]);
        float v10 = bf2f(h1p[c0]), v11 = bf2f(h1p[c1]);
        float v20 = bf2f(h2p[c0]), v21 = bf2f(h2p[c1]);
        float v30 = bf2f(h3p[c0]), v31 = bf2f(h3p[c1]);
        float m4 = fmaxf(fmaxf(e0, e1), fmaxf(e2, e3));
        if (m4 > m) {
            float sc = __expf(m - m4);
            a0 *= sc; a1 *= sc; d *= sc; m = m4;
        }
        float w0 = __expf(e0 - m), w1 = __expf(e1 - m);
        float w2 = __expf(e2 - m), w3 = __expf(e3 - m);
        a0 += w0 * v00 + w1 * v10 + w2 * v20 + w3 * v30;
        a1 += w0 * v01 + w1 * v11 + w2 * v21 + w3 * v31;
        d  += w0 + w1 + w2 + w3;
    }
    for (; idx < epos; ++idx) {
        int col = colS[idx];
        float e = hs[col] + hdv;
        e = (e > 0.f) ? e : 0.2f * e;
        const unsigned short* hr = hlin + (size_t)col * 128;
        float v0 = bf2f(hr[c0]), v1 = bf2f(hr[c1]);
        if (e > m) {
            float sc = __expf(m - e);
            a0 = a0 * sc + v0;
            a1 = a1 * sc + v1;
            d  = d * sc + 1.f;
            m  = e;
        } else {
            float w = __expf(e - m);
            a0 += w * v0;
            a1 += w * v1;
            d  += w;
        }
    }
    float inv = 1.f / (d + 1e-16f);
    float r0 = a0 * inv + b[c0];
    float r1 = a1 * inv + b[c1];
    xout[(size_t)n * 128 + c0] = f2bf(fmaxf(r0, 0.f));
    xout[(size_t)n * 128 + c1] = f2bf(fmaxf(r1, 0.f));
}

// ---------------- LSTM weight pack into MFMA fragment order ----------------
__global__ void k_wpack(const void* Wihf, const void* Whhf,
                        const void* Wihb, const void* Whhb,
                        const void* bihf, const void* bhhf,
                        const void* bihb, const void* bhhb,
                        const int* __restrict__ flags,
                        unsigned short* __restrict__ Bpack, float* __restrict__ bsum) {
    int idx = blockIdx.x * blockDim.x + threadIdx.x;
    const int TOT = 2 * 10 * 48 * 512;
    if (idx < TOT) {
        int dir = idx / (10 * 48 * 512);
        int r   = idx % (10 * 48 * 512);
        int kb  = r / (48 * 512);
        int r2  = r % (48 * 512);
        int f   = r2 / 512;
        int q   = r2 % 512;
        int lane = q >> 3, j = q & 7;
        int k   = kb * 32 + ((j >> 2) * 16) + ((lane >> 4) * 4) + (j & 3);
        int col = f * 16 + (lane & 15);
        float v;
        if (k < 128)
            v = dir ? rdx(Wihb, (size_t)col * 128 + k, flags[14])
                    : rdx(Wihf, (size_t)col * 128 + k, flags[10]);
        else
            v = dir ? rdx(Whhb, (size_t)col * 192 + (k - 128), flags[15])
                    : rdx(Whhf, (size_t)col * 192 + (k - 128), flags[11]);
        Bpack[idx] = f2bf(v);
    }
    if (idx < 2 * 768) {
        int d = idx / 768, j = idx % 768;
        bsum[idx] = d ? rdx(bihb, j, flags[16]) + rdx(bhhb, j, flags[17])
                      : rdx(bihf, j, flags[12]) + rdx(bhhf, j, flags[13]);
    }
}

// ---------------- fused bidirectional LSTM, MFMA, 3-pass low-VGPR ----------
// Grid (ceil(N/32), 2); 256 threads = 4 waves. Each step's 768 output cols
// are computed in 3 passes of 8 acc-frags (all 4 gates of 1/3 of the units),
// keeping live VGPR low for occupancy. h double-buffered in LDS (x|hA|hB).
__global__ __launch_bounds__(256) void k_lstm_mfma(
    const unsigned short* __restrict__ xsb,  // [3][N][128] bf16
    const unsigned short* __restrict__ Bpack,// [2][10][48][512] bf16
    const float* __restrict__ bsum,          // [2][768]
    const float* __restrict__ attW,          // [384]
    float* __restrict__ scoreP,              // [2][3][N]
    int N) {
    __shared__ unsigned short AS[32][520];   // x:[0,128)  hA:[128,320)  hB:[320,512)
    __shared__ float scoreS[32];
    const int t = threadIdx.x;
    const int w = t >> 6, lane = t & 63;
    const int dir = blockIdx.y;
    const int n0 = blockIdx.x * 32;
    const int ccol = lane & 15;
    const int lrow = (lane >> 4) * 4;
    const int akl = (lane >> 4) * 4;

    float bI[3], bF[3], bG[3], bO[3], awt[3];
    #pragma unroll
    for (int a = 0; a < 3; ++a) {
        int m = 16 * (w + 4 * a) + ccol;
        bI[a] = bsum[dir * 768 + m];
        bF[a] = bsum[dir * 768 + 192 + m];
        bG[a] = bsum[dir * 768 + 384 + m];
        bO[a] = bsum[dir * 768 + 576 + m];
        awt[a] = attW[dir * 192 + m];
    }
    float cst[24];
    #pragma unroll
    for (int i = 0; i < 24; ++i) cst[i] = 0.f;

    const unsigned short* Bd = Bpack + (size_t)dir * 10 * 48 * 512;
    int hc = 128, hn = 320;   // current / next h region offsets

    for (int s = 0; s < 3; ++s) {
        const int l = dir ? (2 - s) : s;
        // ---- stage x tile (pure bf16 copy) ----
        {
            const unsigned short* xsrc = xsb + ((size_t)l * N + n0) * 128;
            #pragma unroll
            for (int it = 0; it < 2; ++it) {
                int i = t + it * 256;            // 0..511
                int r = i >> 4, kq = (i & 15) * 8;
                u16x8 v = (u16x8)(0);
                if (n0 + r < N) v = *(const u16x8*)(xsrc + (size_t)r * 128 + kq);
                *(u16x8*)&AS[r][kq] = v;
            }
        }
        if (t < 32) scoreS[t] = 0.f;
        __syncthreads();

        float sprow[8];
        #pragma unroll
        for (int i = 0; i < 8; ++i) sprow[i] = 0.f;

        #pragma unroll
        for (int a = 0; a < 3; ++a) {
            f32x4 acc[2][4];
            #pragma unroll
            for (int tl = 0; tl < 2; ++tl)
                #pragma unroll
                for (int g = 0; g < 4; ++g) acc[tl][g] = (f32x4)(0.f);

            // K over x region (kb 0..3)
            #pragma unroll
            for (int kb = 0; kb < 4; ++kb) {
                const int k0 = kb * 32 + akl;
                s16x4 a0lo = *(const s16x4*)&AS[ccol][k0];
                s16x4 a0hi = *(const s16x4*)&AS[ccol][k0 + 16];
                s16x4 a1lo = *(const s16x4*)&AS[16 + ccol][k0];
                s16x4 a1hi = *(const s16x4*)&AS[16 + ccol][k0 + 16];
                s16x8 a0 = __builtin_shufflevector(a0lo, a0hi, 0, 1, 2, 3, 4, 5, 6, 7);
                s16x8 a1 = __builtin_shufflevector(a1lo, a1hi, 0, 1, 2, 3, 4, 5, 6, 7);
                const unsigned short* bb =
                    Bd + ((size_t)kb * 48 + w + 4 * a) * 512 + lane * 8;
                #pragma unroll
                for (int g = 0; g < 4; ++g) {
                    s16x8 b = *(const s16x8*)(bb + (size_t)g * 6144);
                    acc[0][g] = __builtin_amdgcn_mfma_f32_16x16x32_bf16(a0, b, acc[0][g], 0, 0, 0);
                    acc[1][g] = __builtin_amdgcn_mfma_f32_16x16x32_bf16(a1, b, acc[1][g], 0, 0, 0);
                }
            }
            // K over h region (kb 4..9), only when s > 0
            if (s) {
                #pragma unroll
                for (int kb = 4; kb < 10; ++kb) {
                    const int k0 = kb * 32 + akl - 128 + hc;
                    s16x4 a0lo = *(const s16x4*)&AS[ccol][k0];
                    s16x4 a0hi = *(const s16x4*)&AS[ccol][k0 + 16];
                    s16x4 a1lo = *(const s16x4*)&AS[16 + ccol][k0];
                    s16x4 a1hi = *(const s16x4*)&AS[16 + ccol][k0 + 16];
                    s16x8 a0 = __builtin_shufflevector(a0lo, a0hi, 0, 1, 2, 3, 4, 5, 6, 7);
                    s16x8 a1 = __builtin_shufflevector(a1lo, a1hi, 0, 1, 2, 3, 4, 5, 6, 7);
                    const unsigned short* bb =
                        Bd + ((size_t)kb * 48 + w + 4 * a) * 512 + lane * 8;
                    #pragma unroll
                    for (int g = 0; g < 4; ++g) {
                        s16x8 b = *(const s16x8*)(bb + (size_t)g * 6144);
                        acc[0][g] = __builtin_amdgcn_mfma_f32_16x16x32_bf16(a0, b, acc[0][g], 0, 0, 0);
                        acc[1][g] = __builtin_amdgcn_mfma_f32_16x16x32_bf16(a1, b, acc[1][g], 0, 0, 0);
                    }
                }
            }
            // cell epilogue for this pass (writes h-next; disjoint from reads)
            const int m = 16 * (w + 4 * a) + ccol;
            #pragma unroll
            for (int tl = 0; tl < 2; ++tl) {
                #pragma unroll
                for (int reg = 0; reg < 4; ++reg) {
                    float gI = acc[tl][0][reg] + bI[a];
                    float gF = acc[tl][1][reg] + bF[a];
                    float gG = acc[tl][2][reg] + bG[a];
                    float gO = acc[tl][3][reg] + bO[a];
                    float ig = 1.f / (1.f + __expf(-gI));
                    float fg = 1.f / (1.f + __expf(-gF));
                    float gt = fast_tanh(gG);
                    float og = 1.f / (1.f + __expf(-gO));
                    int ci = tl * 12 + a * 4 + reg;
                    float cn = fg * cst[ci] + ig * gt;
                    cst[ci] = cn;
                    float hh = og * fast_tanh(cn);
                    AS[tl * 16 + lrow + reg][hn + m] = f2bf(hh);
                    sprow[tl * 4 + reg] += hh * awt[a];
                }
            }
        }

        #pragma unroll
        for (int o = 1; o < 16; o <<= 1) {
            #pragma unroll
            for (int i = 0; i < 8; ++i) sprow[i] += __shfl_xor(sprow[i], o);
        }
        if (ccol == 0) {
            #pragma unroll
            for (int i = 0; i < 8; ++i)
                atomicAdd(&scoreS[(i >> 2) * 16 + lrow + (i & 3)], sprow[i]);
        }
        __syncthreads();
        if (t < 32 && n0 + t < N)
            scoreP[(size_t)(dir * 3 + l) * N + n0 + t] = scoreS[t];
        int tmp = hc; hc = hn; hn = tmp;
    }
}

// ---------------- JK finish: layer softmax + weighted sum ------------------
__global__ __launch_bounds__(256) void k_jkfin(
    const unsigned short* __restrict__ xsb, const float* __restrict__ scoreP,
    float* __restrict__ hJK, int N) {
    const int nl = threadIdx.x >> 7;           // 2 nodes per block
    const int ch = threadIdx.x & 127;
    const int n = blockIdx.x * 2 + nl;
    if (n >= N) return;
    float s0 = scoreP[n]                  + scoreP[(size_t)3 * N + n];
    float s1 = scoreP[(size_t)N + n]      + scoreP[(size_t)4 * N + n];
    float s2 = scoreP[(size_t)2 * N + n]  + scoreP[(size_t)5 * N + n];
    float m = fmaxf(s0, fmaxf(s1, s2));
    float e0 = __expf(s0 - m), e1 = __expf(s1 - m), e2 = __expf(s2 - m);
    float inv = 1.f / (e0 + e1 + e2);
    e0 *= inv; e1 *= inv; e2 *= inv;
    const size_t nb = (size_t)n * 128 + ch;
    const size_t L1o = (size_t)N * 128, L2o = 2 * (size_t)N * 128;
    hJK[nb] = e0 * bf2f(xsb[nb]) + e1 * bf2f(xsb[L1o + nb]) + e2 * bf2f(xsb[L2o + nb]);
}

// ---------------- node classifier: 2 nodes/wave ----------------------------
__global__ __launch_bounds__(256) void k_nodemlp(
    const float* __restrict__ hJK, const float* __restrict__ W1, const float* __restrict__ b1,
    const float* __restrict__ W2, const float* __restrict__ b2,
    float* __restrict__ out, int N) {
    __shared__ float xl[8][128];
    const int t = threadIdx.x;
    const int wid = t >> 6, lane = t & 63;
    const int nb = blockIdx.x * 8;
    for (int i = t; i < 1024; i += 256) {
        int r = i >> 7, k = i & 127;
        int n = nb + r;
        xl[r][k] = (n < N) ? hJK[(size_t)n * 128 + k] : 0.f;
    }
    __syncthreads();
    const int c0 = lane, c1 = lane + 64;
    const int ra = wid * 2, rb = wid * 2 + 1;
    float h0a = 0.f, h1a = 0.f, h0b = 0.f, h1b = 0.f;
    #pragma unroll 4
    for (int k = 0; k < 128; ++k) {
        float w0 = W1[k * 128 + c0], w1 = W1[k * 128 + c1];
        float xa = xl[ra][k], xb = xl[rb][k];
        h0a += xa * w0; h1a += xa * w1;
        h0b += xb * w0; h1b += xb * w1;
    }
    h0a = fmaxf(h0a + b1[c0], 0.f); h1a = fmaxf(h1a + b1[c1], 0.f);
    h0b = fmaxf(h0b + b1[c0], 0.f); h1b = fmaxf(h1b + b1[c1], 0.f);
    float p0a = h0a * W2[c0 * 2 + 0] + h1a * W2[c1 * 2 + 0];
    float p1a = h0a * W2[c0 * 2 + 1] + h1a * W2[c1 * 2 + 1];
    float p0b = h0b * W2[c0 * 2 + 0] + h1b * W2[c1 * 2 + 0];
    float p1b = h0b * W2[c0 * 2 + 1] + h1b * W2[c1 * 2 + 1];
    for (int o = 32; o; o >>= 1) {
        p0a += __shfl_down(p0a, o); p1a += __shfl_down(p1a, o);
        p0b += __shfl_down(p0b, o); p1b += __shfl_down(p1b, o);
    }
    if (lane == 0) {
        int na = nb + ra, nb2 = nb + rb;
        if (na < N) {
            float l0 = p0a + b2[0], l1 = p1a + b2[1];
            float mm = fmaxf(l0, l1);
            float e0 = __expf(l0 - mm), e1 = __expf(l1 - mm);
            float inv = 1.f / (e0 + e1);
            out[2 * (size_t)na]     = e0 * inv;
            out[2 * (size_t)na + 1] = e1 * inv;
        }
        if (nb2 < N) {
            float l0 = p0b + b2[0], l1 = p1b + b2[1];
            float mm = fmaxf(l0, l1);
            float e0 = __expf(l0 - mm), e1 = __expf(l1 - mm);
            float inv = 1.f / (e0 + e1);
            out[2 * (size_t)nb2]     = e0 * inv;
            out[2 * (size_t)nb2 + 1] = e1 * inv;
        }
    }
}

// ---------------- edge MLP: per-node P/Q precompute, 2 nodes/wave ----------
__global__ __launch_bounds__(256) void k_pqlin(
    const float* __restrict__ hJK, const float* __restrict__ W1,
    const float* __restrict__ b1,
    unsigned short* __restrict__ P, unsigned short* __restrict__ Q, int N) {
    __shared__ float xl[8][128];
    const int t = threadIdx.x;
    const int wid = t >> 6, lane = t & 63;
    const int nb = blockIdx.x * 8;
    for (int i = t; i < 1024; i += 256) {
        int r = i >> 7, k = i & 127;
        int n = nb + r;
        xl[r][k] = (n < N) ? hJK[(size_t)n * 128 + k] : 0.f;
    }
    __syncthreads();
    const int c0 = lane, c1 = lane + 64;
    const int ra = wid * 2, rb = wid * 2 + 1;
    float p0a = 0.f, p1a = 0.f, q0a = 0.f, q1a = 0.f;
    float p0b = 0.f, p1b = 0.f, q0b = 0.f, q1b = 0.f;
    #pragma unroll 2
    for (int k = 0; k < 128; ++k) {
        float wp0 = W1[k * 128 + c0], wp1 = W1[k * 128 + c1];
        float wq0 = W1[(128 + k) * 128 + c0], wq1 = W1[(128 + k) * 128 + c1];
        float xa = xl[ra][k], xb = xl[rb][k];
        p0a += xa * wp0; p1a += xa * wp1; q0a += xa * wq0; q1a += xa * wq1;
        p0b += xb * wp0; p1b += xb * wp1; q0b += xb * wq0; q1b += xb * wq1;
    }
    const int na = nb + ra, nb2 = nb + rb;
    if (na < N) {
        P[(size_t)na * 128 + c0] = f2bf(p0a + b1[c0]);
        P[(size_t)na * 128 + c1] = f2bf(p1a + b1[c1]);
        Q[(size_t)na * 128 + c0] = f2bf(q0a);
        Q[(size_t)na * 128 + c1] = f2bf(q1a);
    }
    if (nb2 < N) {
        P[(size_t)nb2 * 128 + c0] = f2bf(p0b + b1[c0]);
        P[(size_t)nb2 * 128 + c1] = f2bf(p1b + b1[c1]);
        Q[(size_t)nb2 * 128 + c0] = f2bf(q0b);
        Q[(size_t)nb2 * 128 + c1] = f2bf(q1b);
    }
}

// ---------------- edge MLP finish: gather-add-relu-dot (bf16 P/Q) ----------
__global__ __launch_bounds__(256) void k_edge2(
    const unsigned short* __restrict__ P, const unsigned short* __restrict__ Q,
    const int* __restrict__ row, const int* __restrict__ col,
    const float* __restrict__ W2, const float* __restrict__ b2,
    float* __restrict__ out, long long E, int N) {
    long long g = (((long long)blockIdx.x * blockDim.x) + threadIdx.x) >> 4;
    const int sl = threadIdx.x & 15;
    if (g >= E) return;
    int r = row[g], c = col[g];
    u16x8 pv = *(const u16x8*)(P + (size_t)r * 128 + sl * 8);
    u16x8 qv = *(const u16x8*)(Q + (size_t)c * 128 + sl * 8);
    const float4* w2 = (const float4*)W2 + sl * 4;
    float l0 = 0.f, l1 = 0.f;
    #pragma unroll
    for (int jj = 0; jj < 4; ++jj) {
        float h0 = fmaxf(bf2f(pv[2 * jj])     + bf2f(qv[2 * jj]), 0.f);
        float h1 = fmaxf(bf2f(pv[2 * jj + 1]) + bf2f(qv[2 * jj + 1]), 0.f);
        float4 wv = w2[jj];
        l0 += h0 * wv.x + h1 * wv.z;
        l1 += h0 * wv.y + h1 * wv.w;
    }
    #pragma unroll
    for (int o = 1; o < 16; o <<= 1) { l0 += __shfl_xor(l0, o); l1 += __shfl_xor(l1, o); }
    if (sl == 0) {
        l0 += b2[0]; l1 += b2[1];
        float mm = fmaxf(l0, l1);
        float e0 = __expf(l0 - mm), e1 = __expf(l1 - mm);
        float inv = 1.f / (e0 + e1);
        out[2 * (long long)N + 2 * g]     = e0 * inv;
        out[2 * (long long)N + 2 * g + 1] = e1 * inv;
    }
}

// ---------------------------------------------------------------------------
extern "C" void kernel_launch(void* const* d_in, const int* in_sizes, int n_in,
                              void* d_out, int out_size, void* d_ws, size_t ws_size,
                              hipStream_t stream) {
    if (n_in < NIN) return;
    const int N = in_sizes[0] / 3;
    const int E = in_sizes[1] / 2;

    char* ws = (char*)d_ws;
    size_t off = 0;
    auto alloc = [&](size_t bytes) -> char* {
        char* p = ws + off;
        off = (off + bytes + 255) & ~(size_t)255;
        return p;
    };
    int* flags = (int*)alloc(32 * sizeof(int));
    float* canon[NIN];
    for (int i = 0; i < NIN; ++i) canon[i] = nullptr;
    for (int i = 0; i < NIN; ++i) {
        if (i == 1 || (i >= 10 && i <= 17)) continue;   // LSTM weights read raw
        canon[i] = (float*)alloc((size_t)in_sizes[i] * 4);
    }
    int* row32  = (int*)alloc((size_t)E * 4);
    int* col32  = (int*)alloc((size_t)E * 4);
    int* indptr = (int*)alloc((size_t)(N + 1) * 4);
    int* cnt    = (int*)alloc((size_t)N * 4);
    int* colS   = (int*)alloc((size_t)E * 4);
    float* hs   = (float*)alloc((size_t)N * 4);
    float* hd   = (float*)alloc((size_t)N * 4);
    // hlin: bf16 during GAT phase; same buffer reused as f32 hJK after LSTM
    float* hJK  = (float*)alloc((size_t)N * 128 * 4);
    unsigned short* hlin = (unsigned short*)hJK;
    unsigned short* xsb = (unsigned short*)alloc((size_t)3 * N * 128 * 2);  // bf16 xs
    unsigned short* Bpack = (unsigned short*)alloc((size_t)2 * 10 * 48 * 512 * 2);
    float* bsum = (float*)alloc((size_t)2 * 768 * 4);
    float* scoreP;
    if ((size_t)E >= (size_t)6 * N) scoreP = (float*)colS;   // dead after last aggr
    else                            scoreP = (float*)alloc((size_t)6 * N * 4);
    if (off > ws_size) return;
    // P/Q (bf16, N*128 each) alias xsb (dead after k_jkfin)
    unsigned short* P = xsb;
    unsigned short* Q = xsb + (size_t)N * 128;

    InPtrs ip;
    for (int i = 0; i < NIN; ++i) { ip.p[i] = d_in[i]; ip.n[i] = in_sizes[i]; }

    k_sniff<<<NIN, 256, 0, stream>>>(ip, flags);
    for (int i = 0; i < NIN; ++i) {
        if (i == 1 || (i >= 10 && i <= 17)) continue;
        int n = in_sizes[i];
        k_convf<<<(n + 255) / 256, 256, 0, stream>>>(d_in[i], canon[i], n, flags, i);
    }
    k_conve<<<(E + 255) / 256, 256, 0, stream>>>(d_in[1], row32, col32, E, flags);
    k_wpack<<<(2 * 10 * 48 * 512 + 255) / 256, 256, 0, stream>>>(
        d_in[10], d_in[11], d_in[14], d_in[15],
        d_in[12], d_in[13], d_in[16], d_in[17], flags, Bpack, bsum);

    // CSR by row (shared across all 3 GAT layers)
    k_zeroi<<<(N + 255) / 256, 256, 0, stream>>>(cnt, N);
    k_hist<<<(E + 255) / 256, 256, 0, stream>>>(row32, cnt, E);
    k_scan<<<1, 1024, 0, stream>>>(cnt, indptr, N);
    k_zeroi<<<(N + 255) / 256, 256, 0, stream>>>(cnt, N);
    k_fill<<<(E + 255) / 256, 256, 0, stream>>>(row32, col32, indptr, cnt, colS, E);

    // GAT layer 0 (in=3)
    k_lin0<<<(N + 3) / 4, 256, 0, stream>>>(canon[0], canon[2], canon[4], canon[5],
                                            hlin, hs, hd, N);
    k_aggr<<<(N + 3) / 4, 256, 0, stream>>>(hlin, hs, hd, indptr, colS, canon[3], xsb, N);
    // GAT layers 1..2 (in=128, bf16 in/out)
    for (int l = 1; l < 3; ++l) {
        const float* W  = canon[6] + (size_t)(l - 1) * 128 * 128;
        const float* bb = canon[7] + (size_t)(l - 1) * 128;
        const float* as = canon[8] + (size_t)(l - 1) * 128;
        const float* ad = canon[9] + (size_t)(l - 1) * 128;
        k_lin<<<(N + 7) / 8, 256, 0, stream>>>(xsb + (size_t)(l - 1) * N * 128, W, as, ad,
                                               hlin, hs, hd, N);
        k_aggr<<<(N + 3) / 4, 256, 0, stream>>>(hlin, hs, hd, indptr, colS, bb,
                                                xsb + (size_t)l * N * 128, N);
    }

    // fused bidirectional LSTM (MFMA, 3-pass) + JK attention finish
    dim3 lgrid((N + 31) / 32, 2);
    k_lstm_mfma<<<lgrid, 256, 0, stream>>>(xsb, Bpack, bsum, canon[18], scoreP, N);
    k_jkfin<<<(N + 1) / 2, 256, 0, stream>>>(xsb, scoreP, hJK, N);

    float* out = (float*)d_out;
    k_nodemlp<<<(N + 7) / 8, 256, 0, stream>>>(hJK, canon[20], canon[21], canon[22],
                                               canon[23], out, N);
    // edge MLP: P/Q precompute (bf16, overwrites dead xsb), then gather-dot
    k_pqlin<<<(N + 7) / 8, 256, 0, stream>>>(hJK, canon[24], canon[25], P, Q, N);
    {
        long long tot = (long long)E * 16;
        int blocks = (int)((tot + 255) / 256);
        k_edge2<<<blocks, 256, 0, stream>>>(P, Q, row32, col32, canon[26], canon[27],
                                            out, (long long)E, N);
    }
}

// Round 9
// 1074.169 us; speedup vs baseline: 32.3377x; 1.1376x over previous
//
#include <hip/hip_runtime.h>
#include <cstdint>
#include <cstddef>

// ---------------------------------------------------------------------------
// ParityGameGATNetwork: 3x GATConv -> JK bidirectional LSTM -> node/edge MLPs
// Round 9: LSTM back to round-7 12-frag GEMM but with 8 waves x 1 row-tile
// (acc halved to 12 f32x4/wave; launch_bounds(512,4) pins regs <=128 so
// 4 waves/SIMD are resident -- the 400-570us plateau was 1-wave/SIMD latency
// exposure from unified VGPR+AGPR pressure). Stride 332 (conflict-clean).
// Non-LSTM pipeline unchanged from round 8 (bf16 hlin, 2-node/wave MLPs).
// ---------------------------------------------------------------------------

#define NIN 28

struct InPtrs { const void* p[NIN]; int n[NIN]; };

typedef short s16x4 __attribute__((ext_vector_type(4)));
typedef short s16x8 __attribute__((ext_vector_type(8)));
typedef float f32x4 __attribute__((ext_vector_type(4)));
typedef unsigned short u16x8 __attribute__((ext_vector_type(8)));

__device__ __forceinline__ float bf2f(unsigned short v) {
    unsigned int u = ((unsigned int)v) << 16;
    return __uint_as_float(u);
}

__device__ __forceinline__ unsigned short f2bf(float x) {
    unsigned int u = __float_as_uint(x);
    unsigned int r = u + 0x7fffu + ((u >> 16) & 1u);
    return (unsigned short)(r >> 16);
}

__device__ __forceinline__ float rdx(const void* p, size_t i, int isf32) {
    return isf32 ? ((const float*)p)[i] : bf2f(((const unsigned short*)p)[i]);
}

__device__ __forceinline__ float fast_tanh(float x) {
    float e = __expf(2.f * x);
    return 1.f - 2.f / (e + 1.f);
}

// ---------------- dtype sniffing -------------------------------------------
__global__ void k_sniff(InPtrs in, int* flags) {
    int ai = blockIdx.x;
    if (ai >= NIN) return;
    __shared__ int cnt;
    if (threadIdx.x == 0) cnt = 0;
    __syncthreads();
    if (ai == 1) {
        const int* w = (const int*)in.p[1];
        int nw = in.n[1] < 512 ? in.n[1] : 512;
        int local = 0;
        for (int i = threadIdx.x; i < nw; i += blockDim.x)
            if ((i & 1) && w[i] != 0) local++;
        atomicAdd(&cnt, local);
        __syncthreads();
        if (threadIdx.x == 0) flags[1] = (cnt < 4) ? 1 : 0;
        return;
    }
    const unsigned short* u = (const unsigned short*)in.p[ai];
    int ns = in.n[ai] < 256 ? in.n[ai] : 256;
    int local = 0;
    for (int i = threadIdx.x; i < ns; i += blockDim.x) {
        if (i & 1) continue;
        unsigned short v = u[i];
        int e = (v >> 7) & 0xff;
        if ((v & 0x7fff) != 0 && (e < 100 || e > 154)) local++;
    }
    atomicAdd(&cnt, local);
    __syncthreads();
    if (threadIdx.x == 0) flags[ai] = (cnt * 4 >= ns) ? 1 : 0;
}

__global__ void k_convf(const void* src, float* dst, int n, const int* flags, int ai) {
    int i = blockIdx.x * blockDim.x + threadIdx.x;
    if (i >= n) return;
    if (flags[ai]) dst[i] = ((const float*)src)[i];
    else           dst[i] = bf2f(((const unsigned short*)src)[i]);
}

__global__ void k_conve(const void* src, int* row, int* col, int E, const int* flags) {
    int i = blockIdx.x * blockDim.x + threadIdx.x;
    if (i >= E) return;
    if (flags[1]) {
        const long long* s = (const long long*)src;
        row[i] = (int)s[i];
        col[i] = (int)s[(size_t)E + i];
    } else {
        const int* s = (const int*)src;
        row[i] = s[i];
        col[i] = s[(size_t)E + i];
    }
}

// ---------------- CSR build ------------------------------------------------
__global__ void k_zeroi(int* p, int n) {
    int i = blockIdx.x * blockDim.x + threadIdx.x;
    if (i < n) p[i] = 0;
}

__global__ void k_hist(const int* __restrict__ row, int* __restrict__ cnt, int E) {
    int i = blockIdx.x * blockDim.x + threadIdx.x;
    if (i < E) atomicAdd(&cnt[row[i]], 1);
}

__global__ void k_scan(const int* __restrict__ deg, int* __restrict__ indptr, int N) {
    __shared__ int buf[1024];
    __shared__ int carryS;
    const int t = threadIdx.x;
    if (t == 0) carryS = 0;
    __syncthreads();
    for (int base = 0; base < N; base += 1024) {
        int v = (base + t < N) ? deg[base + t] : 0;
        buf[t] = v;
        __syncthreads();
        for (int ofs = 1; ofs < 1024; ofs <<= 1) {
            int add = (t >= ofs) ? buf[t - ofs] : 0;
            __syncthreads();
            buf[t] += add;
            __syncthreads();
        }
        int carry = carryS;
        if (base + t < N) indptr[base + t] = carry + buf[t] - v;
        __syncthreads();
        if (t == 1023) carryS = carry + buf[1023];
        __syncthreads();
    }
    if (t == 0) indptr[N] = carryS;
}

__global__ void k_fill(const int* __restrict__ row, const int* __restrict__ col,
                       const int* __restrict__ indptr, int* __restrict__ cur,
                       int* __restrict__ colS, int E) {
    int i = blockIdx.x * blockDim.x + threadIdx.x;
    if (i >= E) return;
    int r = row[i];
    int p = indptr[r] + atomicAdd(&cur[r], 1);
    colS[p] = col[i];
}

// ---------------- GAT linear layer 0 (in=3), hlin out bf16 -----------------
__global__ __launch_bounds__(256) void k_lin0(
    const float* __restrict__ x, const float* __restrict__ W0,
    const float* __restrict__ asrc, const float* __restrict__ adst,
    unsigned short* __restrict__ hlin, float* __restrict__ hs, float* __restrict__ hd,
    int N) {
    const int wid = threadIdx.x >> 6, lane = threadIdx.x & 63;
    const int n = blockIdx.x * 4 + wid;
    if (n >= N) return;
    float x0 = x[(size_t)n * 3], x1 = x[(size_t)n * 3 + 1], x2 = x[(size_t)n * 3 + 2];
    const int c0 = lane, c1 = lane + 64;
    float h0 = x0 * W0[c0] + x1 * W0[128 + c0] + x2 * W0[256 + c0];
    float h1 = x0 * W0[c1] + x1 * W0[128 + c1] + x2 * W0[256 + c1];
    hlin[(size_t)n * 128 + c0] = f2bf(h0);
    hlin[(size_t)n * 128 + c1] = f2bf(h1);
    float sp = h0 * asrc[c0] + h1 * asrc[c1];
    float dp = h0 * adst[c0] + h1 * adst[c1];
    for (int o = 32; o; o >>= 1) { sp += __shfl_down(sp, o); dp += __shfl_down(dp, o); }
    if (lane == 0) { hs[n] = sp; hd[n] = dp; }
}

// ---------------- GAT linear (bf16 in, bf16 hlin out), 2 nodes/wave --------
__global__ __launch_bounds__(256) void k_lin(
    const unsigned short* __restrict__ xin, const float* __restrict__ W,
    const float* __restrict__ asrc, const float* __restrict__ adst,
    unsigned short* __restrict__ hlin, float* __restrict__ hs, float* __restrict__ hd,
    int N) {
    __shared__ float xl[8][128];
    const int t = threadIdx.x;
    const int wid = t >> 6, lane = t & 63;
    const int nb = blockIdx.x * 8;
    for (int i = t; i < 1024; i += 256) {
        int r = i >> 7, k = i & 127;
        int n = nb + r;
        xl[r][k] = (n < N) ? bf2f(xin[(size_t)n * 128 + k]) : 0.f;
    }
    __syncthreads();
    const int c0 = lane, c1 = lane + 64;
    const int ra = wid * 2, rb = wid * 2 + 1;
    float h0a = 0.f, h1a = 0.f, h0b = 0.f, h1b = 0.f;
    #pragma unroll 4
    for (int k = 0; k < 128; ++k) {
        float w0 = W[k * 128 + c0], w1 = W[k * 128 + c1];
        float xa = xl[ra][k], xb = xl[rb][k];
        h0a += xa * w0; h1a += xa * w1;
        h0b += xb * w0; h1b += xb * w1;
    }
    const int na = nb + ra, nb2 = nb + rb;
    float spa = h0a * asrc[c0] + h1a * asrc[c1];
    float dpa = h0a * adst[c0] + h1a * adst[c1];
    float spb = h0b * asrc[c0] + h1b * asrc[c1];
    float dpb = h0b * adst[c0] + h1b * adst[c1];
    for (int o = 32; o; o >>= 1) {
        spa += __shfl_down(spa, o); dpa += __shfl_down(dpa, o);
        spb += __shfl_down(spb, o); dpb += __shfl_down(dpb, o);
    }
    if (na < N) {
        hlin[(size_t)na * 128 + c0] = f2bf(h0a);
        hlin[(size_t)na * 128 + c1] = f2bf(h1a);
        if (lane == 0) { hs[na] = spa; hd[na] = dpa; }
    }
    if (nb2 < N) {
        hlin[(size_t)nb2 * 128 + c0] = f2bf(h0b);
        hlin[(size_t)nb2 * 128 + c1] = f2bf(h1b);
        if (lane == 0) { hs[nb2] = spb; hd[nb2] = dpb; }
    }
}

// ---------------- GAT aggregation: online segment softmax, bf16 hlin -------
__global__ __launch_bounds__(256) void k_aggr(
    const unsigned short* __restrict__ hlin, const float* __restrict__ hs,
    const float* __restrict__ hd,
    const int* __restrict__ indptr, const int* __restrict__ colS,
    const float* __restrict__ b, unsigned short* __restrict__ xout, int N) {
    const int wid = threadIdx.x >> 6, lane = threadIdx.x & 63;
    const int n = blockIdx.x * 4 + wid;
    if (n >= N) return;
    const int s = indptr[n], epos = indptr[n + 1];
    const float hdv = hd[n];
    const int c0 = lane, c1 = lane + 64;
    float m = -1e30f, d = 0.f, a0 = 0.f, a1 = 0.f;
    int idx = s;
    for (; idx + 4 <= epos; idx += 4) {
        int col0 = colS[idx], col1 = colS[idx + 1], col2 = colS[idx + 2], col3 = colS[idx + 3];
        float e0 = hs[col0] + hdv, e1 = hs[col1] + hdv;
        float e2 = hs[col2] + hdv, e3 = hs[col3] + hdv;
        e0 = (e0 > 0.f) ? e0 : 0.2f * e0;
        e1 = (e1 > 0.f) ? e1 : 0.2f * e1;
        e2 = (e2 > 0.f) ? e2 : 0.2f * e2;
        e3 = (e3 > 0.f) ? e3 : 0.2f * e3;
        const unsigned short* h0p = hlin + (size_t)col0 * 128;
        const unsigned short* h1p = hlin + (size_t)col1 * 128;
        const unsigned short* h2p = hlin + (size_t)col2 * 128;
        const unsigned short* h3p = hlin + (size_t)col3 * 128;
        float v00 = bf2f(h0p[c0]), v01 = bf2f(h0p[c1]);
        float v10 = bf2f(h1p[c0]), v11 = bf2f(h1p[c1]);
        float v20 = bf2f(h2p[c0]), v21 = bf2f(h2p[c1]);
        float v30 = bf2f(h3p[c0]), v31 = bf2f(h3p[c1]);
        float m4 = fmaxf(fmaxf(e0, e1), fmaxf(e2, e3));
        if (m4 > m) {
            float sc = __expf(m - m4);
            a0 *= sc; a1 *= sc; d *= sc; m = m4;
        }
        float w0 = __expf(e0 - m), w1 = __expf(e1 - m);
        float w2 = __expf(e2 - m), w3 = __expf(e3 - m);
        a0 += w0 * v00 + w1 * v10 + w2 * v20 + w3 * v30;
        a1 += w0 * v01 + w1 * v11 + w2 * v21 + w3 * v31;
        d  += w0 + w1 + w2 + w3;
    }
    for (; idx < epos; ++idx) {
        int col = colS[idx];
        float e = hs[col] + hdv;
        e = (e > 0.f) ? e : 0.2f * e;
        const unsigned short* hr = hlin + (size_t)col * 128;
        float v0 = bf2f(hr[c0]), v1 = bf2f(hr[c1]);
        if (e > m) {
            float sc = __expf(m - e);
            a0 = a0 * sc + v0;
            a1 = a1 * sc + v1;
            d  = d * sc + 1.f;
            m  = e;
        } else {
            float w = __expf(e - m);
            a0 += w * v0;
            a1 += w * v1;
            d  += w;
        }
    }
    float inv = 1.f / (d + 1e-16f);
    float r0 = a0 * inv + b[c0];
    float r1 = a1 * inv + b[c1];
    xout[(size_t)n * 128 + c0] = f2bf(fmaxf(r0, 0.f));
    xout[(size_t)n * 128 + c1] = f2bf(fmaxf(r1, 0.f));
}

// ---------------- LSTM weight pack into MFMA fragment order ----------------
__global__ void k_wpack(const void* Wihf, const void* Whhf,
                        const void* Wihb, const void* Whhb,
                        const void* bihf, const void* bhhf,
                        const void* bihb, const void* bhhb,
                        const int* __restrict__ flags,
                        unsigned short* __restrict__ Bpack, float* __restrict__ bsum) {
    int idx = blockIdx.x * blockDim.x + threadIdx.x;
    const int TOT = 2 * 10 * 48 * 512;
    if (idx < TOT) {
        int dir = idx / (10 * 48 * 512);
        int r   = idx % (10 * 48 * 512);
        int kb  = r / (48 * 512);
        int r2  = r % (48 * 512);
        int f   = r2 / 512;
        int q   = r2 % 512;
        int lane = q >> 3, j = q & 7;
        int k   = kb * 32 + ((j >> 2) * 16) + ((lane >> 4) * 4) + (j & 3);
        int col = f * 16 + (lane & 15);
        float v;
        if (k < 128)
            v = dir ? rdx(Wihb, (size_t)col * 128 + k, flags[14])
                    : rdx(Wihf, (size_t)col * 128 + k, flags[10]);
        else
            v = dir ? rdx(Whhb, (size_t)col * 192 + (k - 128), flags[15])
                    : rdx(Whhf, (size_t)col * 192 + (k - 128), flags[11]);
        Bpack[idx] = f2bf(v);
    }
    if (idx < 2 * 768) {
        int d = idx / 768, j = idx % 768;
        bsum[idx] = d ? rdx(bihb, j, flags[16]) + rdx(bhhb, j, flags[17])
                      : rdx(bihf, j, flags[12]) + rdx(bhhf, j, flags[13]);
    }
}

// ---------------- fused bidirectional LSTM, MFMA, 8-wave low-pressure ------
// Grid (ceil(N/32), 2); 512 threads = 8 waves. Wave w: col-group cg=w&3
// (frags {cg, cg+4, ..., cg+44}), row-tile rt=w>>2 (rows rt*16..rt*16+15).
// acc = 12 f32x4/wave; launch_bounds(512,4) pins regs <=128 for residency.
__global__ __launch_bounds__(512, 4) void k_lstm_mfma(
    const unsigned short* __restrict__ xsb,  // [3][N][128] bf16
    const unsigned short* __restrict__ Bpack,// [2][10][48][512] bf16
    const float* __restrict__ bsum,          // [2][768]
    const float* __restrict__ attW,          // [384]
    float* __restrict__ scoreP,              // [2][3][N]
    int N) {
    __shared__ unsigned short AS[32][332];   // x:[0,128)  h:[128,320)
    __shared__ float scoreS[32];
    const int t = threadIdx.x;
    const int w = t >> 6, lane = t & 63;
    const int cg = w & 3, rt = w >> 2;
    const int dir = blockIdx.y;
    const int n0 = blockIdx.x * 32;
    const int ccol = lane & 15;
    const int lrow = (lane >> 4) * 4;
    const int akl = (lane >> 4) * 4;
    const int arow = rt * 16 + ccol;

    float bI[3], bF[3], bG[3], bO[3], awt[3];
    #pragma unroll
    for (int a = 0; a < 3; ++a) {
        int m = 16 * (cg + 4 * a) + ccol;
        bI[a] = bsum[dir * 768 + m];
        bF[a] = bsum[dir * 768 + 192 + m];
        bG[a] = bsum[dir * 768 + 384 + m];
        bO[a] = bsum[dir * 768 + 576 + m];
        awt[a] = attW[dir * 192 + m];
    }
    float cst[12];
    #pragma unroll
    for (int i = 0; i < 12; ++i) cst[i] = 0.f;

    const unsigned short* Bd = Bpack + (size_t)dir * 10 * 48 * 512;

    for (int s = 0; s < 3; ++s) {
        const int l = dir ? (2 - s) : s;
        // ---- stage x tile: 512 threads x 16B = 32x128 bf16, one shot ----
        {
            const unsigned short* xsrc = xsb + ((size_t)l * N + n0) * 128;
            int r = t >> 4, kq = (t & 15) * 8;
            u16x8 v = (u16x8)(0);
            if (n0 + r < N) v = *(const u16x8*)(xsrc + (size_t)r * 128 + kq);
            *(u16x8*)&AS[r][kq] = v;
        }
        if (t < 32) scoreS[t] = 0.f;
        __syncthreads();

        // ---- MFMA GEMM over K ----
        const int KB = s ? 10 : 4;
        f32x4 acc[12];
        #pragma unroll
        for (int f = 0; f < 12; ++f) acc[f] = (f32x4)(0.f);
        for (int kb = 0; kb < KB; ++kb) {
            const int k0 = kb * 32 + akl;
            s16x4 alo = *(const s16x4*)&AS[arow][k0];
            s16x4 ahi = *(const s16x4*)&AS[arow][k0 + 16];
            s16x8 av = __builtin_shufflevector(alo, ahi, 0, 1, 2, 3, 4, 5, 6, 7);
            const unsigned short* bb = Bd + ((size_t)kb * 48 + cg) * 512 + lane * 8;
            #pragma unroll
            for (int f = 0; f < 12; ++f) {
                s16x8 b = *(const s16x8*)(bb + (size_t)f * 2048);
                acc[f] = __builtin_amdgcn_mfma_f32_16x16x32_bf16(av, b, acc[f], 0, 0, 0);
            }
        }
        __syncthreads();   // all A reads done before h overwrite

        // ---- cell epilogue (this wave's 12 units on its row-tile) ----
        float sprow[4] = {0.f, 0.f, 0.f, 0.f};
        #pragma unroll
        for (int a = 0; a < 3; ++a) {
            const int m = 16 * (cg + 4 * a) + ccol;
            #pragma unroll
            for (int reg = 0; reg < 4; ++reg) {
                float gI = acc[a][reg]     + bI[a];
                float gF = acc[3 + a][reg] + bF[a];
                float gG = acc[6 + a][reg] + bG[a];
                float gO = acc[9 + a][reg] + bO[a];
                float ig = 1.f / (1.f + __expf(-gI));
                float fg = 1.f / (1.f + __expf(-gF));
                float gt = fast_tanh(gG);
                float og = 1.f / (1.f + __expf(-gO));
                int ci = a * 4 + reg;
                float cn = fg * cst[ci] + ig * gt;
                cst[ci] = cn;
                float hh = og * fast_tanh(cn);
                AS[rt * 16 + lrow + reg][128 + m] = f2bf(hh);
                sprow[reg] += hh * awt[a];
            }
        }
        #pragma unroll
        for (int o = 1; o < 16; o <<= 1) {
            #pragma unroll
            for (int i = 0; i < 4; ++i) sprow[i] += __shfl_xor(sprow[i], o);
        }
        if (ccol == 0) {
            #pragma unroll
            for (int i = 0; i < 4; ++i)
                atomicAdd(&scoreS[rt * 16 + lrow + i], sprow[i]);
        }
        __syncthreads();
        if (t < 32 && n0 + t < N)
            scoreP[(size_t)(dir * 3 + l) * N + n0 + t] = scoreS[t];
        // (scoreS reset next iter is by the same thread that read it: no race)
    }
}

// ---------------- JK finish: layer softmax + weighted sum ------------------
__global__ __launch_bounds__(256) void k_jkfin(
    const unsigned short* __restrict__ xsb, const float* __restrict__ scoreP,
    float* __restrict__ hJK, int N) {
    const int nl = threadIdx.x >> 7;           // 2 nodes per block
    const int ch = threadIdx.x & 127;
    const int n = blockIdx.x * 2 + nl;
    if (n >= N) return;
    float s0 = scoreP[n]                  + scoreP[(size_t)3 * N + n];
    float s1 = scoreP[(size_t)N + n]      + scoreP[(size_t)4 * N + n];
    float s2 = scoreP[(size_t)2 * N + n]  + scoreP[(size_t)5 * N + n];
    float m = fmaxf(s0, fmaxf(s1, s2));
    float e0 = __expf(s0 - m), e1 = __expf(s1 - m), e2 = __expf(s2 - m);
    float inv = 1.f / (e0 + e1 + e2);
    e0 *= inv; e1 *= inv; e2 *= inv;
    const size_t nb = (size_t)n * 128 + ch;
    const size_t L1o = (size_t)N * 128, L2o = 2 * (size_t)N * 128;
    hJK[nb] = e0 * bf2f(xsb[nb]) + e1 * bf2f(xsb[L1o + nb]) + e2 * bf2f(xsb[L2o + nb]);
}

// ---------------- node classifier: 2 nodes/wave ----------------------------
__global__ __launch_bounds__(256) void k_nodemlp(
    const float* __restrict__ hJK, const float* __restrict__ W1, const float* __restrict__ b1,
    const float* __restrict__ W2, const float* __restrict__ b2,
    float* __restrict__ out, int N) {
    __shared__ float xl[8][128];
    const int t = threadIdx.x;
    const int wid = t >> 6, lane = t & 63;
    const int nb = blockIdx.x * 8;
    for (int i = t; i < 1024; i += 256) {
        int r = i >> 7, k = i & 127;
        int n = nb + r;
        xl[r][k] = (n < N) ? hJK[(size_t)n * 128 + k] : 0.f;
    }
    __syncthreads();
    const int c0 = lane, c1 = lane + 64;
    const int ra = wid * 2, rb = wid * 2 + 1;
    float h0a = 0.f, h1a = 0.f, h0b = 0.f, h1b = 0.f;
    #pragma unroll 4
    for (int k = 0; k < 128; ++k) {
        float w0 = W1[k * 128 + c0], w1 = W1[k * 128 + c1];
        float xa = xl[ra][k], xb = xl[rb][k];
        h0a += xa * w0; h1a += xa * w1;
        h0b += xb * w0; h1b += xb * w1;
    }
    h0a = fmaxf(h0a + b1[c0], 0.f); h1a = fmaxf(h1a + b1[c1], 0.f);
    h0b = fmaxf(h0b + b1[c0], 0.f); h1b = fmaxf(h1b + b1[c1], 0.f);
    float p0a = h0a * W2[c0 * 2 + 0] + h1a * W2[c1 * 2 + 0];
    float p1a = h0a * W2[c0 * 2 + 1] + h1a * W2[c1 * 2 + 1];
    float p0b = h0b * W2[c0 * 2 + 0] + h1b * W2[c1 * 2 + 0];
    float p1b = h0b * W2[c0 * 2 + 1] + h1b * W2[c1 * 2 + 1];
    for (int o = 32; o; o >>= 1) {
        p0a += __shfl_down(p0a, o); p1a += __shfl_down(p1a, o);
        p0b += __shfl_down(p0b, o); p1b += __shfl_down(p1b, o);
    }
    if (lane == 0) {
        int na = nb + ra, nb2 = nb + rb;
        if (na < N) {
            float l0 = p0a + b2[0], l1 = p1a + b2[1];
            float mm = fmaxf(l0, l1);
            float e0 = __expf(l0 - mm), e1 = __expf(l1 - mm);
            float inv = 1.f / (e0 + e1);
            out[2 * (size_t)na]     = e0 * inv;
            out[2 * (size_t)na + 1] = e1 * inv;
        }
        if (nb2 < N) {
            float l0 = p0b + b2[0], l1 = p1b + b2[1];
            float mm = fmaxf(l0, l1);
            float e0 = __expf(l0 - mm), e1 = __expf(l1 - mm);
            float inv = 1.f / (e0 + e1);
            out[2 * (size_t)nb2]     = e0 * inv;
            out[2 * (size_t)nb2 + 1] = e1 * inv;
        }
    }
}

// ---------------- edge MLP: per-node P/Q precompute, 2 nodes/wave ----------
__global__ __launch_bounds__(256) void k_pqlin(
    const float* __restrict__ hJK, const float* __restrict__ W1,
    const float* __restrict__ b1,
    unsigned short* __restrict__ P, unsigned short* __restrict__ Q, int N) {
    __shared__ float xl[8][128];
    const int t = threadIdx.x;
    const int wid = t >> 6, lane = t & 63;
    const int nb = blockIdx.x * 8;
    for (int i = t; i < 1024; i += 256) {
        int r = i >> 7, k = i & 127;
        int n = nb + r;
        xl[r][k] = (n < N) ? hJK[(size_t)n * 128 + k] : 0.f;
    }
    __syncthreads();
    const int c0 = lane, c1 = lane + 64;
    const int ra = wid * 2, rb = wid * 2 + 1;
    float p0a = 0.f, p1a = 0.f, q0a = 0.f, q1a = 0.f;
    float p0b = 0.f, p1b = 0.f, q0b = 0.f, q1b = 0.f;
    #pragma unroll 2
    for (int k = 0; k < 128; ++k) {
        float wp0 = W1[k * 128 + c0], wp1 = W1[k * 128 + c1];
        float wq0 = W1[(128 + k) * 128 + c0], wq1 = W1[(128 + k) * 128 + c1];
        float xa = xl[ra][k], xb = xl[rb][k];
        p0a += xa * wp0; p1a += xa * wp1; q0a += xa * wq0; q1a += xa * wq1;
        p0b += xb * wp0; p1b += xb * wp1; q0b += xb * wq0; q1b += xb * wq1;
    }
    const int na = nb + ra, nb2 = nb + rb;
    if (na < N) {
        P[(size_t)na * 128 + c0] = f2bf(p0a + b1[c0]);
        P[(size_t)na * 128 + c1] = f2bf(p1a + b1[c1]);
        Q[(size_t)na * 128 + c0] = f2bf(q0a);
        Q[(size_t)na * 128 + c1] = f2bf(q1a);
    }
    if (nb2 < N) {
        P[(size_t)nb2 * 128 + c0] = f2bf(p0b + b1[c0]);
        P[(size_t)nb2 * 128 + c1] = f2bf(p1b + b1[c1]);
        Q[(size_t)nb2 * 128 + c0] = f2bf(q0b);
        Q[(size_t)nb2 * 128 + c1] = f2bf(q1b);
    }
}

// ---------------- edge MLP finish: gather-add-relu-dot (bf16 P/Q) ----------
__global__ __launch_bounds__(256) void k_edge2(
    const unsigned short* __restrict__ P, const unsigned short* __restrict__ Q,
    const int* __restrict__ row, const int* __restrict__ col,
    const float* __restrict__ W2, const float* __restrict__ b2,
    float* __restrict__ out, long long E, int N) {
    long long g = (((long long)blockIdx.x * blockDim.x) + threadIdx.x) >> 4;
    const int sl = threadIdx.x & 15;
    if (g >= E) return;
    int r = row[g], c = col[g];
    u16x8 pv = *(const u16x8*)(P + (size_t)r * 128 + sl * 8);
    u16x8 qv = *(const u16x8*)(Q + (size_t)c * 128 + sl * 8);
    const float4* w2 = (const float4*)W2 + sl * 4;
    float l0 = 0.f, l1 = 0.f;
    #pragma unroll
    for (int jj = 0; jj < 4; ++jj) {
        float h0 = fmaxf(bf2f(pv[2 * jj])     + bf2f(qv[2 * jj]), 0.f);
        float h1 = fmaxf(bf2f(pv[2 * jj + 1]) + bf2f(qv[2 * jj + 1]), 0.f);
        float4 wv = w2[jj];
        l0 += h0 * wv.x + h1 * wv.z;
        l1 += h0 * wv.y + h1 * wv.w;
    }
    #pragma unroll
    for (int o = 1; o < 16; o <<= 1) { l0 += __shfl_xor(l0, o); l1 += __shfl_xor(l1, o); }
    if (sl == 0) {
        l0 += b2[0]; l1 += b2[1];
        float mm = fmaxf(l0, l1);
        float e0 = __expf(l0 - mm), e1 = __expf(l1 - mm);
        float inv = 1.f / (e0 + e1);
        out[2 * (long long)N + 2 * g]     = e0 * inv;
        out[2 * (long long)N + 2 * g + 1] = e1 * inv;
    }
}

// ---------------------------------------------------------------------------
extern "C" void kernel_launch(void* const* d_in, const int* in_sizes, int n_in,
                              void* d_out, int out_size, void* d_ws, size_t ws_size,
                              hipStream_t stream) {
    if (n_in < NIN) return;
    const int N = in_sizes[0] / 3;
    const int E = in_sizes[1] / 2;

    char* ws = (char*)d_ws;
    size_t off = 0;
    auto alloc = [&](size_t bytes) -> char* {
        char* p = ws + off;
        off = (off + bytes + 255) & ~(size_t)255;
        return p;
    };
    int* flags = (int*)alloc(32 * sizeof(int));
    float* canon[NIN];
    for (int i = 0; i < NIN; ++i) canon[i] = nullptr;
    for (int i = 0; i < NIN; ++i) {
        if (i == 1 || (i >= 10 && i <= 17)) continue;   // LSTM weights read raw
        canon[i] = (float*)alloc((size_t)in_sizes[i] * 4);
    }
    int* row32  = (int*)alloc((size_t)E * 4);
    int* col32  = (int*)alloc((size_t)E * 4);
    int* indptr = (int*)alloc((size_t)(N + 1) * 4);
    int* cnt    = (int*)alloc((size_t)N * 4);
    int* colS   = (int*)alloc((size_t)E * 4);
    float* hs   = (float*)alloc((size_t)N * 4);
    float* hd   = (float*)alloc((size_t)N * 4);
    // hlin: bf16 during GAT phase; same buffer reused as f32 hJK after LSTM
    float* hJK  = (float*)alloc((size_t)N * 128 * 4);
    unsigned short* hlin = (unsigned short*)hJK;
    unsigned short* xsb = (unsigned short*)alloc((size_t)3 * N * 128 * 2);  // bf16 xs
    unsigned short* Bpack = (unsigned short*)alloc((size_t)2 * 10 * 48 * 512 * 2);
    float* bsum = (float*)alloc((size_t)2 * 768 * 4);
    float* scoreP;
    if ((size_t)E >= (size_t)6 * N) scoreP = (float*)colS;   // dead after last aggr
    else                            scoreP = (float*)alloc((size_t)6 * N * 4);
    if (off > ws_size) return;
    // P/Q (bf16, N*128 each) alias xsb (dead after k_jkfin)
    unsigned short* P = xsb;
    unsigned short* Q = xsb + (size_t)N * 128;

    InPtrs ip;
    for (int i = 0; i < NIN; ++i) { ip.p[i] = d_in[i]; ip.n[i] = in_sizes[i]; }

    k_sniff<<<NIN, 256, 0, stream>>>(ip, flags);
    for (int i = 0; i < NIN; ++i) {
        if (i == 1 || (i >= 10 && i <= 17)) continue;
        int n = in_sizes[i];
        k_convf<<<(n + 255) / 256, 256, 0, stream>>>(d_in[i], canon[i], n, flags, i);
    }
    k_conve<<<(E + 255) / 256, 256, 0, stream>>>(d_in[1], row32, col32, E, flags);
    k_wpack<<<(2 * 10 * 48 * 512 + 255) / 256, 256, 0, stream>>>(
        d_in[10], d_in[11], d_in[14], d_in[15],
        d_in[12], d_in[13], d_in[16], d_in[17], flags, Bpack, bsum);

    // CSR by row (shared across all 3 GAT layers)
    k_zeroi<<<(N + 255) / 256, 256, 0, stream>>>(cnt, N);
    k_hist<<<(E + 255) / 256, 256, 0, stream>>>(row32, cnt, E);
    k_scan<<<1, 1024, 0, stream>>>(cnt, indptr, N);
    k_zeroi<<<(N + 255) / 256, 256, 0, stream>>>(cnt, N);
    k_fill<<<(E + 255) / 256, 256, 0, stream>>>(row32, col32, indptr, cnt, colS, E);

    // GAT layer 0 (in=3)
    k_lin0<<<(N + 3) / 4, 256, 0, stream>>>(canon[0], canon[2], canon[4], canon[5],
                                            hlin, hs, hd, N);
    k_aggr<<<(N + 3) / 4, 256, 0, stream>>>(hlin, hs, hd, indptr, colS, canon[3], xsb, N);
    // GAT layers 1..2 (in=128, bf16 in/out)
    for (int l = 1; l < 3; ++l) {
        const float* W  = canon[6] + (size_t)(l - 1) * 128 * 128;
        const float* bb = canon[7] + (size_t)(l - 1) * 128;
        const float* as = canon[8] + (size_t)(l - 1) * 128;
        const float* ad = canon[9] + (size_t)(l - 1) * 128;
        k_lin<<<(N + 7) / 8, 256, 0, stream>>>(xsb + (size_t)(l - 1) * N * 128, W, as, ad,
                                               hlin, hs, hd, N);
        k_aggr<<<(N + 3) / 4, 256, 0, stream>>>(hlin, hs, hd, indptr, colS, bb,
                                                xsb + (size_t)l * N * 128, N);
    }

    // fused bidirectional LSTM (MFMA, 8-wave) + JK attention finish
    dim3 lgrid((N + 31) / 32, 2);
    k_lstm_mfma<<<lgrid, 512, 0, stream>>>(xsb, Bpack, bsum, canon[18], scoreP, N);
    k_jkfin<<<(N + 1) / 2, 256, 0, stream>>>(xsb, scoreP, hJK, N);

    float* out = (float*)d_out;
    k_nodemlp<<<(N + 7) / 8, 256, 0, stream>>>(hJK, canon[20], canon[21], canon[22],
                                               canon[23], out, N);
    // edge MLP: P/Q precompute (bf16, overwrites dead xsb), then gather-dot
    k_pqlin<<<(N + 7) / 8, 256, 0, stream>>>(hJK, canon[24], canon[25], P, Q, N);
    {
        long long tot = (long long)E * 16;
        int blocks = (int)((tot + 255) / 256);
        k_edge2<<<blocks, 256, 0, stream>>>(P, Q, row32, col32, canon[26], canon[27],
                                            out, (long long)E, N);
    }
}

// Round 10
// 847.555 us; speedup vs baseline: 40.9840x; 1.2674x over previous
//
#include <hip/hip_runtime.h>
#include <cstdint>
#include <cstddef>

// ---------------------------------------------------------------------------
// ParityGameGATNetwork: 3x GATConv -> JK bidirectional LSTM -> node/edge MLPs
// Round 10: (a) LSTM 64-row blocks, 12 waves, one base-frag per wave
// (4 B-loads feed 16 MFMAs -> 4x FLOP/byte, no B duplication, B ping-pong),
// (b) parallel 3-kernel scan (was 50us on one CU), (c) 19 convf launches
// batched into one kernel, (d) jkfin+nodemlp+pqlin fused into k_tail
// (hJK stays in LDS; P/Q live in the old hJK buffer, un-aliasing xsb).
// ---------------------------------------------------------------------------

#define NIN 28
#define MAXJOBS 20

struct InPtrs { const void* p[NIN]; int n[NIN]; };

struct ConvJobs {
    const void* src[MAXJOBS];
    float* dst[MAXJOBS];
    int n[MAXJOBS];
    int ai[MAXJOBS];
    int blk0[MAXJOBS + 1];
    int njobs;
};

typedef short s16x4 __attribute__((ext_vector_type(4)));
typedef short s16x8 __attribute__((ext_vector_type(8)));
typedef float f32x4 __attribute__((ext_vector_type(4)));
typedef unsigned short u16x8 __attribute__((ext_vector_type(8)));

__device__ __forceinline__ float bf2f(unsigned short v) {
    unsigned int u = ((unsigned int)v) << 16;
    return __uint_as_float(u);
}

__device__ __forceinline__ unsigned short f2bf(float x) {
    unsigned int u = __float_as_uint(x);
    unsigned int r = u + 0x7fffu + ((u >> 16) & 1u);
    return (unsigned short)(r >> 16);
}

__device__ __forceinline__ float rdx(const void* p, size_t i, int isf32) {
    return isf32 ? ((const float*)p)[i] : bf2f(((const unsigned short*)p)[i]);
}

__device__ __forceinline__ float fast_tanh(float x) {
    float e = __expf(2.f * x);
    return 1.f - 2.f / (e + 1.f);
}

// ---------------- dtype sniffing -------------------------------------------
__global__ void k_sniff(InPtrs in, int* flags) {
    int ai = blockIdx.x;
    if (ai >= NIN) return;
    __shared__ int cnt;
    if (threadIdx.x == 0) cnt = 0;
    __syncthreads();
    if (ai == 1) {
        const int* w = (const int*)in.p[1];
        int nw = in.n[1] < 512 ? in.n[1] : 512;
        int local = 0;
        for (int i = threadIdx.x; i < nw; i += blockDim.x)
            if ((i & 1) && w[i] != 0) local++;
        atomicAdd(&cnt, local);
        __syncthreads();
        if (threadIdx.x == 0) flags[1] = (cnt < 4) ? 1 : 0;
        return;
    }
    const unsigned short* u = (const unsigned short*)in.p[ai];
    int ns = in.n[ai] < 256 ? in.n[ai] : 256;
    int local = 0;
    for (int i = threadIdx.x; i < ns; i += blockDim.x) {
        if (i & 1) continue;
        unsigned short v = u[i];
        int e = (v >> 7) & 0xff;
        if ((v & 0x7fff) != 0 && (e < 100 || e > 154)) local++;
    }
    atomicAdd(&cnt, local);
    __syncthreads();
    if (threadIdx.x == 0) flags[ai] = (cnt * 4 >= ns) ? 1 : 0;
}

// ---------------- batched canonicalization (all f32/bf16 arrays) -----------
__global__ void k_convall(ConvJobs J, const int* __restrict__ flags) {
    int b = blockIdx.x;
    int j = 0;
    while (j + 1 < J.njobs && b >= J.blk0[j + 1]) ++j;
    int i = (b - J.blk0[j]) * 256 + threadIdx.x;
    if (i >= J.n[j]) return;
    J.dst[j][i] = rdx(J.src[j], i, flags[J.ai[j]]);
}

__global__ void k_conve(const void* src, int* row, int* col, int E, const int* flags) {
    int i = blockIdx.x * blockDim.x + threadIdx.x;
    if (i >= E) return;
    if (flags[1]) {
        const long long* s = (const long long*)src;
        row[i] = (int)s[i];
        col[i] = (int)s[(size_t)E + i];
    } else {
        const int* s = (const int*)src;
        row[i] = s[i];
        col[i] = s[(size_t)E + i];
    }
}

// ---------------- CSR build ------------------------------------------------
__global__ void k_zeroi(int* p, int n) {
    int i = blockIdx.x * blockDim.x + threadIdx.x;
    if (i < n) p[i] = 0;
}

__global__ void k_hist(const int* __restrict__ row, int* __restrict__ cnt, int E) {
    int i = blockIdx.x * blockDim.x + threadIdx.x;
    if (i < E) atomicAdd(&cnt[row[i]], 1);
}

// parallel scan: per-1024-block local exclusive scan + block sums
__global__ void k_scan1(const int* __restrict__ deg, int* __restrict__ indptr,
                        int* __restrict__ bsums, int N) {
    __shared__ int buf[1024];
    const int t = threadIdx.x;
    const int base = blockIdx.x * 1024;
    int v = (base + t < N) ? deg[base + t] : 0;
    buf[t] = v;
    __syncthreads();
    for (int ofs = 1; ofs < 1024; ofs <<= 1) {
        int add = (t >= ofs) ? buf[t - ofs] : 0;
        __syncthreads();
        buf[t] += add;
        __syncthreads();
    }
    if (base + t < N) indptr[base + t] = buf[t] - v;   // local exclusive
    if (t == 1023) bsums[blockIdx.x] = buf[1023];
}

__global__ void k_scan2(int* bsums, int nb) {
    if (threadIdx.x == 0 && blockIdx.x == 0) {
        int acc = 0;
        for (int j = 0; j < nb; ++j) { int v = bsums[j]; bsums[j] = acc; acc += v; }
        bsums[nb] = acc;
    }
}

__global__ void k_scan3(const int* __restrict__ bsums, int* __restrict__ indptr,
                        int N, int nb) {
    int i = blockIdx.x * blockDim.x + threadIdx.x;
    if (i < N) indptr[i] += bsums[i >> 10];
    if (i == 0) indptr[N] = bsums[nb];
}

__global__ void k_fill(const int* __restrict__ row, const int* __restrict__ col,
                       const int* __restrict__ indptr, int* __restrict__ cur,
                       int* __restrict__ colS, int E) {
    int i = blockIdx.x * blockDim.x + threadIdx.x;
    if (i >= E) return;
    int r = row[i];
    int p = indptr[r] + atomicAdd(&cur[r], 1);
    colS[p] = col[i];
}

// ---------------- GAT linear layer 0 (in=3), hlin out bf16 -----------------
__global__ __launch_bounds__(256) void k_lin0(
    const float* __restrict__ x, const float* __restrict__ W0,
    const float* __restrict__ asrc, const float* __restrict__ adst,
    unsigned short* __restrict__ hlin, float* __restrict__ hs, float* __restrict__ hd,
    int N) {
    const int wid = threadIdx.x >> 6, lane = threadIdx.x & 63;
    const int n = blockIdx.x * 4 + wid;
    if (n >= N) return;
    float x0 = x[(size_t)n * 3], x1 = x[(size_t)n * 3 + 1], x2 = x[(size_t)n * 3 + 2];
    const int c0 = lane, c1 = lane + 64;
    float h0 = x0 * W0[c0] + x1 * W0[128 + c0] + x2 * W0[256 + c0];
    float h1 = x0 * W0[c1] + x1 * W0[128 + c1] + x2 * W0[256 + c1];
    hlin[(size_t)n * 128 + c0] = f2bf(h0);
    hlin[(size_t)n * 128 + c1] = f2bf(h1);
    float sp = h0 * asrc[c0] + h1 * asrc[c1];
    float dp = h0 * adst[c0] + h1 * adst[c1];
    for (int o = 32; o; o >>= 1) { sp += __shfl_down(sp, o); dp += __shfl_down(dp, o); }
    if (lane == 0) { hs[n] = sp; hd[n] = dp; }
}

// ---------------- GAT linear (bf16 in, bf16 hlin out), 2 nodes/wave --------
__global__ __launch_bounds__(256) void k_lin(
    const unsigned short* __restrict__ xin, const float* __restrict__ W,
    const float* __restrict__ asrc, const float* __restrict__ adst,
    unsigned short* __restrict__ hlin, float* __restrict__ hs, float* __restrict__ hd,
    int N) {
    __shared__ float xl[8][128];
    const int t = threadIdx.x;
    const int wid = t >> 6, lane = t & 63;
    const int nb = blockIdx.x * 8;
    for (int i = t; i < 1024; i += 256) {
        int r = i >> 7, k = i & 127;
        int n = nb + r;
        xl[r][k] = (n < N) ? bf2f(xin[(size_t)n * 128 + k]) : 0.f;
    }
    __syncthreads();
    const int c0 = lane, c1 = lane + 64;
    const int ra = wid * 2, rb = wid * 2 + 1;
    float h0a = 0.f, h1a = 0.f, h0b = 0.f, h1b = 0.f;
    #pragma unroll 4
    for (int k = 0; k < 128; ++k) {
        float w0 = W[k * 128 + c0], w1 = W[k * 128 + c1];
        float xa = xl[ra][k], xb = xl[rb][k];
        h0a += xa * w0; h1a += xa * w1;
        h0b += xb * w0; h1b += xb * w1;
    }
    const int na = nb + ra, nb2 = nb + rb;
    float spa = h0a * asrc[c0] + h1a * asrc[c1];
    float dpa = h0a * adst[c0] + h1a * adst[c1];
    float spb = h0b * asrc[c0] + h1b * asrc[c1];
    float dpb = h0b * adst[c0] + h1b * adst[c1];
    for (int o = 32; o; o >>= 1) {
        spa += __shfl_down(spa, o); dpa += __shfl_down(dpa, o);
        spb += __shfl_down(spb, o); dpb += __shfl_down(dpb, o);
    }
    if (na < N) {
        hlin[(size_t)na * 128 + c0] = f2bf(h0a);
        hlin[(size_t)na * 128 + c1] = f2bf(h1a);
        if (lane == 0) { hs[na] = spa; hd[na] = dpa; }
    }
    if (nb2 < N) {
        hlin[(size_t)nb2 * 128 + c0] = f2bf(h0b);
        hlin[(size_t)nb2 * 128 + c1] = f2bf(h1b);
        if (lane == 0) { hs[nb2] = spb; hd[nb2] = dpb; }
    }
}

// ---------------- GAT aggregation: online segment softmax, bf16 hlin -------
__global__ __launch_bounds__(256) void k_aggr(
    const unsigned short* __restrict__ hlin, const float* __restrict__ hs,
    const float* __restrict__ hd,
    const int* __restrict__ indptr, const int* __restrict__ colS,
    const float* __restrict__ b, unsigned short* __restrict__ xout, int N) {
    const int wid = threadIdx.x >> 6, lane = threadIdx.x & 63;
    const int n = blockIdx.x * 4 + wid;
    if (n >= N) return;
    const int s = indptr[n], epos = indptr[n + 1];
    const float hdv = hd[n];
    const int c0 = lane, c1 = lane + 64;
    float m = -1e30f, d = 0.f, a0 = 0.f, a1 = 0.f;
    int idx = s;
    for (; idx + 4 <= epos; idx += 4) {
        int col0 = colS[idx], col1 = colS[idx + 1], col2 = colS[idx + 2], col3 = colS[idx + 3];
        float e0 = hs[col0] + hdv, e1 = hs[col1] + hdv;
        float e2 = hs[col2] + hdv, e3 = hs[col3] + hdv;
        e0 = (e0 > 0.f) ? e0 : 0.2f * e0;
        e1 = (e1 > 0.f) ? e1 : 0.2f * e1;
        e2 = (e2 > 0.f) ? e2 : 0.2f * e2;
        e3 = (e3 > 0.f) ? e3 : 0.2f * e3;
        const unsigned short* h0p = hlin + (size_t)col0 * 128;
        const unsigned short* h1p = hlin + (size_t)col1 * 128;
        const unsigned short* h2p = hlin + (size_t)col2 * 128;
        const unsigned short* h3p = hlin + (size_t)col3 * 128;
        float v00 = bf2f(h0p[c0]), v01 = bf2f(h0p[c1]);
        float v10 = bf2f(h1p[c0]), v11 = bf2f(h1p[c1]);
        float v20 = bf2f(h2p[c0]), v21 = bf2f(h2p[c1]);
        float v30 = bf2f(h3p[c0]), v31 = bf2f(h3p[c1]);
        float m4 = fmaxf(fmaxf(e0, e1), fmaxf(e2, e3));
        if (m4 > m) {
            float sc = __expf(m - m4);
            a0 *= sc; a1 *= sc; d *= sc; m = m4;
        }
        float w0 = __expf(e0 - m), w1 = __expf(e1 - m);
        float w2 = __expf(e2 - m), w3 = __expf(e3 - m);
        a0 += w0 * v00 + w1 * v10 + w2 * v20 + w3 * v30;
        a1 += w0 * v01 + w1 * v11 + w2 * v21 + w3 * v31;
        d  += w0 + w1 + w2 + w3;
    }
    for (; idx < epos; ++idx) {
        int col = colS[idx];
        float e = hs[col] + hdv;
        e = (e > 0.f) ? e : 0.2f * e;
        const unsigned short* hr = hlin + (size_t)col * 128;
        float v0 = bf2f(hr[c0]), v1 = bf2f(hr[c1]);
        if (e > m) {
            float sc = __expf(m - e);
            a0 = a0 * sc + v0;
            a1 = a1 * sc + v1;
            d  = d * sc + 1.f;
            m  = e;
        } else {
            float w = __expf(e - m);
            a0 += w * v0;
            a1 += w * v1;
            d  += w;
        }
    }
    float inv = 1.f / (d + 1e-16f);
    float r0 = a0 * inv + b[c0];
    float r1 = a1 * inv + b[c1];
    xout[(size_t)n * 128 + c0] = f2bf(fmaxf(r0, 0.f));
    xout[(size_t)n * 128 + c1] = f2bf(fmaxf(r1, 0.f));
}

// ---------------- LSTM weight pack into MFMA fragment order ----------------
__global__ void k_wpack(const void* Wihf, const void* Whhf,
                        const void* Wihb, const void* Whhb,
                        const void* bihf, const void* bhhf,
                        const void* bihb, const void* bhhb,
                        const int* __restrict__ flags,
                        unsigned short* __restrict__ Bpack, float* __restrict__ bsum) {
    int idx = blockIdx.x * blockDim.x + threadIdx.x;
    const int TOT = 2 * 10 * 48 * 512;
    if (idx < TOT) {
        int dir = idx / (10 * 48 * 512);
        int r   = idx % (10 * 48 * 512);
        int kb  = r / (48 * 512);
        int r2  = r % (48 * 512);
        int f   = r2 / 512;
        int q   = r2 % 512;
        int lane = q >> 3, j = q & 7;
        int k   = kb * 32 + ((j >> 2) * 16) + ((lane >> 4) * 4) + (j & 3);
        int col = f * 16 + (lane & 15);
        float v;
        if (k < 128)
            v = dir ? rdx(Wihb, (size_t)col * 128 + k, flags[14])
                    : rdx(Wihf, (size_t)col * 128 + k, flags[10]);
        else
            v = dir ? rdx(Whhb, (size_t)col * 192 + (k - 128), flags[15])
                    : rdx(Whhf, (size_t)col * 192 + (k - 128), flags[11]);
        Bpack[idx] = f2bf(v);
    }
    if (idx < 2 * 768) {
        int d = idx / 768, j = idx % 768;
        bsum[idx] = d ? rdx(bihb, j, flags[16]) + rdx(bhhb, j, flags[17])
                      : rdx(bihf, j, flags[12]) + rdx(bhhf, j, flags[13]);
    }
}

// ---------------- fused bidirectional LSTM: 64 rows, 12 waves --------------
// Grid (ceil(N/64), 2); 768 threads = 12 waves. Wave w = base-frag bf in
// [0,12): owns gate-frags {bf, bf+12, bf+24, bf+36} (all 4 gates of units
// m = bf*16 + ccol) across 4 row-frags. Per kb: 4 B loads feed 16 MFMAs
// (64 FLOP/B; no within-block B duplication). B ping-pong prefetch.
__global__ __launch_bounds__(768, 3) void k_lstm_mfma(
    const unsigned short* __restrict__ xsb,  // [3][N][128] bf16
    const unsigned short* __restrict__ Bpack,// [2][10][48][512] bf16
    const float* __restrict__ bsum,          // [2][768]
    const float* __restrict__ attW,          // [384]
    float* __restrict__ scoreP,              // [2][3][N]
    int N) {
    __shared__ unsigned short AS[64][332];   // x:[0,128)  h:[128,320)
    __shared__ float scoreS[64];
    const int t = threadIdx.x;
    const int bf = t >> 6, lane = t & 63;
    const int dir = blockIdx.y;
    const int n0 = blockIdx.x * 64;
    const int ccol = lane & 15;
    const int klane = lane >> 4;
    const int lrow = klane * 4;
    const int akl = klane * 4;
    const int m = bf * 16 + ccol;            // this thread's hidden unit

    const float bI = bsum[dir * 768 + m];
    const float bF = bsum[dir * 768 + 192 + m];
    const float bG = bsum[dir * 768 + 384 + m];
    const float bO = bsum[dir * 768 + 576 + m];
    const float awt = attW[dir * 192 + m];
    float cst[16];
    #pragma unroll
    for (int i = 0; i < 16; ++i) cst[i] = 0.f;

    const unsigned short* Bd = Bpack + (size_t)dir * 10 * 48 * 512;

    for (int s = 0; s < 3; ++s) {
        const int l = dir ? (2 - s) : s;
        // ---- stage x tile: 64x128 bf16 ----
        {
            const unsigned short* xsrc = xsb + ((size_t)l * N + n0) * 128;
            for (int i = t; i < 1024; i += 768) {
                int r = i >> 4, kq = (i & 15) * 8;
                u16x8 v = (u16x8)(0);
                if (n0 + r < N) v = *(const u16x8*)(xsrc + (size_t)r * 128 + kq);
                *(u16x8*)&AS[r][kq] = v;
            }
        }
        if (t < 64) scoreS[t] = 0.f;
        __syncthreads();

        // ---- MFMA GEMM over K, B ping-pong prefetch ----
        const int KB = s ? 10 : 4;               // both even
        f32x4 acc[4][4];
        #pragma unroll
        for (int rf = 0; rf < 4; ++rf)
            #pragma unroll
            for (int g = 0; g < 4; ++g) acc[rf][g] = (f32x4)(0.f);
        s16x8 bA[4], bB[4];
        {
            const unsigned short* bb = Bd + (size_t)bf * 512 + lane * 8;   // kb=0
            #pragma unroll
            for (int g = 0; g < 4; ++g) bA[g] = *(const s16x8*)(bb + (size_t)g * 6144);
        }
        for (int kb = 0; kb < KB; kb += 2) {
            {   // prefetch kb+1
                const unsigned short* bb = Bd + ((size_t)(kb + 1) * 48 + bf) * 512 + lane * 8;
                #pragma unroll
                for (int g = 0; g < 4; ++g) bB[g] = *(const s16x8*)(bb + (size_t)g * 6144);
            }
            {   // compute kb on bA
                const int k0 = kb * 32 + akl;
                s16x8 av[4];
                #pragma unroll
                for (int rf = 0; rf < 4; ++rf) {
                    s16x4 alo = *(const s16x4*)&AS[rf * 16 + ccol][k0];
                    s16x4 ahi = *(const s16x4*)&AS[rf * 16 + ccol][k0 + 16];
                    av[rf] = __builtin_shufflevector(alo, ahi, 0, 1, 2, 3, 4, 5, 6, 7);
                }
                #pragma unroll
                for (int rf = 0; rf < 4; ++rf)
                    #pragma unroll
                    for (int g = 0; g < 4; ++g)
                        acc[rf][g] = __builtin_amdgcn_mfma_f32_16x16x32_bf16(
                            av[rf], bA[g], acc[rf][g], 0, 0, 0);
            }
            if (kb + 2 < KB) {   // prefetch kb+2
                const unsigned short* bb = Bd + ((size_t)(kb + 2) * 48 + bf) * 512 + lane * 8;
                #pragma unroll
                for (int g = 0; g < 4; ++g) bA[g] = *(const s16x8*)(bb + (size_t)g * 6144);
            }
            {   // compute kb+1 on bB
                const int k0 = (kb + 1) * 32 + akl;
                s16x8 av[4];
                #pragma unroll
                for (int rf = 0; rf < 4; ++rf) {
                    s16x4 alo = *(const s16x4*)&AS[rf * 16 + ccol][k0];
                    s16x4 ahi = *(const s16x4*)&AS[rf * 16 + ccol][k0 + 16];
                    av[rf] = __builtin_shufflevector(alo, ahi, 0, 1, 2, 3, 4, 5, 6, 7);
                }
                #pragma unroll
                for (int rf = 0; rf < 4; ++rf)
                    #pragma unroll
                    for (int g = 0; g < 4; ++g)
                        acc[rf][g] = __builtin_amdgcn_mfma_f32_16x16x32_bf16(
                            av[rf], bB[g], acc[rf][g], 0, 0, 0);
            }
        }
        __syncthreads();   // all A reads done before h overwrite

        // ---- cell epilogue: one unit per thread, 16 rows ----
        float sp[16];
        #pragma unroll
        for (int rf = 0; rf < 4; ++rf) {
            #pragma unroll
            for (int reg = 0; reg < 4; ++reg) {
                float gI = acc[rf][0][reg] + bI;
                float gF = acc[rf][1][reg] + bF;
                float gG = acc[rf][2][reg] + bG;
                float gO = acc[rf][3][reg] + bO;
                float ig = 1.f / (1.f + __expf(-gI));
                float fg = 1.f / (1.f + __expf(-gF));
                float gt = fast_tanh(gG);
                float og = 1.f / (1.f + __expf(-gO));
                int ci = rf * 4 + reg;
                float cn = fg * cst[ci] + ig * gt;
                cst[ci] = cn;
                float hh = og * fast_tanh(cn);
                AS[rf * 16 + lrow + reg][128 + m] = f2bf(hh);
                sp[ci] = hh * awt;
            }
        }
        #pragma unroll
        for (int o = 1; o < 16; o <<= 1) {
            #pragma unroll
            for (int i = 0; i < 16; ++i) sp[i] += __shfl_xor(sp[i], o);
        }
        if (ccol == 0) {
            #pragma unroll
            for (int i = 0; i < 16; ++i)
                atomicAdd(&scoreS[(i >> 2) * 16 + lrow + (i & 3)], sp[i]);
        }
        __syncthreads();
        if (t < 64 && n0 + t < N)
            scoreP[(size_t)(dir * 3 + l) * N + n0 + t] = scoreS[t];
    }
}

// ---------------- fused tail: JK softmax-sum + node MLP + P/Q --------------
// 8 nodes per 256-thread block; hJK built in LDS (never hits global).
__global__ __launch_bounds__(256) void k_tail(
    const unsigned short* __restrict__ xsb, const float* __restrict__ scoreP,
    const float* __restrict__ nW1, const float* __restrict__ nb1,
    const float* __restrict__ nW2, const float* __restrict__ nb2,
    const float* __restrict__ eW1, const float* __restrict__ eb1,
    unsigned short* __restrict__ P, unsigned short* __restrict__ Q,
    float* __restrict__ out, int N) {
    __shared__ float xl[8][128];
    __shared__ float al[8][4];
    const int t = threadIdx.x;
    const int wid = t >> 6, lane = t & 63;
    const int nb = blockIdx.x * 8;
    if (t < 8) {
        int n = nb + t;
        float e0 = 0.f, e1 = 0.f, e2 = 0.f;
        if (n < N) {
            float s0 = scoreP[n]                 + scoreP[(size_t)3 * N + n];
            float s1 = scoreP[(size_t)N + n]     + scoreP[(size_t)4 * N + n];
            float s2 = scoreP[(size_t)2 * N + n] + scoreP[(size_t)5 * N + n];
            float mm = fmaxf(s0, fmaxf(s1, s2));
            e0 = __expf(s0 - mm); e1 = __expf(s1 - mm); e2 = __expf(s2 - mm);
            float inv = 1.f / (e0 + e1 + e2);
            e0 *= inv; e1 *= inv; e2 *= inv;
        }
        al[t][0] = e0; al[t][1] = e1; al[t][2] = e2;
    }
    __syncthreads();
    const size_t L1o = (size_t)N * 128, L2o = 2 * L1o;
    for (int i = t; i < 1024; i += 256) {
        int r = i >> 7, k = i & 127;
        int n = nb + r;
        float v = 0.f;
        if (n < N) {
            size_t p = (size_t)n * 128 + k;
            v = al[r][0] * bf2f(xsb[p]) + al[r][1] * bf2f(xsb[L1o + p])
              + al[r][2] * bf2f(xsb[L2o + p]);
        }
        xl[r][k] = v;
    }
    __syncthreads();
    const int c0 = lane, c1 = lane + 64;
    const int ra = wid * 2, rb = wid * 2 + 1;
    // ---- node MLP ----
    {
        float h0a = 0.f, h1a = 0.f, h0b = 0.f, h1b = 0.f;
        #pragma unroll 4
        for (int k = 0; k < 128; ++k) {
            float w0 = nW1[k * 128 + c0], w1 = nW1[k * 128 + c1];
            float xa = xl[ra][k], xb = xl[rb][k];
            h0a += xa * w0; h1a += xa * w1;
            h0b += xb * w0; h1b += xb * w1;
        }
        h0a = fmaxf(h0a + nb1[c0], 0.f); h1a = fmaxf(h1a + nb1[c1], 0.f);
        h0b = fmaxf(h0b + nb1[c0], 0.f); h1b = fmaxf(h1b + nb1[c1], 0.f);
        float p0a = h0a * nW2[c0 * 2 + 0] + h1a * nW2[c1 * 2 + 0];
        float p1a = h0a * nW2[c0 * 2 + 1] + h1a * nW2[c1 * 2 + 1];
        float p0b = h0b * nW2[c0 * 2 + 0] + h1b * nW2[c1 * 2 + 0];
        float p1b = h0b * nW2[c0 * 2 + 1] + h1b * nW2[c1 * 2 + 1];
        for (int o = 32; o; o >>= 1) {
            p0a += __shfl_down(p0a, o); p1a += __shfl_down(p1a, o);
            p0b += __shfl_down(p0b, o); p1b += __shfl_down(p1b, o);
        }
        if (lane == 0) {
            int na = nb + ra, n2 = nb + rb;
            if (na < N) {
                float l0 = p0a + nb2[0], l1 = p1a + nb2[1];
                float mm = fmaxf(l0, l1);
                float e0 = __expf(l0 - mm), e1 = __expf(l1 - mm);
                float inv = 1.f / (e0 + e1);
                out[2 * (size_t)na]     = e0 * inv;
                out[2 * (size_t)na + 1] = e1 * inv;
            }
            if (n2 < N) {
                float l0 = p0b + nb2[0], l1 = p1b + nb2[1];
                float mm = fmaxf(l0, l1);
                float e0 = __expf(l0 - mm), e1 = __expf(l1 - mm);
                float inv = 1.f / (e0 + e1);
                out[2 * (size_t)n2]     = e0 * inv;
                out[2 * (size_t)n2 + 1] = e1 * inv;
            }
        }
    }
    // ---- P/Q precompute (bf16 out) ----
    {
        float p0a = 0.f, p1a = 0.f, q0a = 0.f, q1a = 0.f;
        float p0b = 0.f, p1b = 0.f, q0b = 0.f, q1b = 0.f;
        #pragma unroll 2
        for (int k = 0; k < 128; ++k) {
            float wp0 = eW1[k * 128 + c0], wp1 = eW1[k * 128 + c1];
            float wq0 = eW1[(128 + k) * 128 + c0], wq1 = eW1[(128 + k) * 128 + c1];
            float xa = xl[ra][k], xb = xl[rb][k];
            p0a += xa * wp0; p1a += xa * wp1; q0a += xa * wq0; q1a += xa * wq1;
            p0b += xb * wp0; p1b += xb * wp1; q0b += xb * wq0; q1b += xb * wq1;
        }
        const int na = nb + ra, n2 = nb + rb;
        if (na < N) {
            P[(size_t)na * 128 + c0] = f2bf(p0a + eb1[c0]);
            P[(size_t)na * 128 + c1] = f2bf(p1a + eb1[c1]);
            Q[(size_t)na * 128 + c0] = f2bf(q0a);
            Q[(size_t)na * 128 + c1] = f2bf(q1a);
        }
        if (n2 < N) {
            P[(size_t)n2 * 128 + c0] = f2bf(p0b + eb1[c0]);
            P[(size_t)n2 * 128 + c1] = f2bf(p1b + eb1[c1]);
            Q[(size_t)n2 * 128 + c0] = f2bf(q0b);
            Q[(size_t)n2 * 128 + c1] = f2bf(q1b);
        }
    }
}

// ---------------- edge MLP finish: gather-add-relu-dot (bf16 P/Q) ----------
__global__ __launch_bounds__(256) void k_edge2(
    const unsigned short* __restrict__ P, const unsigned short* __restrict__ Q,
    const int* __restrict__ row, const int* __restrict__ col,
    const float* __restrict__ W2, const float* __restrict__ b2,
    float* __restrict__ out, long long E, int N) {
    long long g = (((long long)blockIdx.x * blockDim.x) + threadIdx.x) >> 4;
    const int sl = threadIdx.x & 15;
    if (g >= E) return;
    int r = row[g], c = col[g];
    u16x8 pv = *(const u16x8*)(P + (size_t)r * 128 + sl * 8);
    u16x8 qv = *(const u16x8*)(Q + (size_t)c * 128 + sl * 8);
    const float4* w2 = (const float4*)W2 + sl * 4;
    float l0 = 0.f, l1 = 0.f;
    #pragma unroll
    for (int jj = 0; jj < 4; ++jj) {
        float h0 = fmaxf(bf2f(pv[2 * jj])     + bf2f(qv[2 * jj]), 0.f);
        float h1 = fmaxf(bf2f(pv[2 * jj + 1]) + bf2f(qv[2 * jj + 1]), 0.f);
        float4 wv = w2[jj];
        l0 += h0 * wv.x + h1 * wv.z;
        l1 += h0 * wv.y + h1 * wv.w;
    }
    #pragma unroll
    for (int o = 1; o < 16; o <<= 1) { l0 += __shfl_xor(l0, o); l1 += __shfl_xor(l1, o); }
    if (sl == 0) {
        l0 += b2[0]; l1 += b2[1];
        float mm = fmaxf(l0, l1);
        float e0 = __expf(l0 - mm), e1 = __expf(l1 - mm);
        float inv = 1.f / (e0 + e1);
        out[2 * (long long)N + 2 * g]     = e0 * inv;
        out[2 * (long long)N + 2 * g + 1] = e1 * inv;
    }
}

// ---------------------------------------------------------------------------
extern "C" void kernel_launch(void* const* d_in, const int* in_sizes, int n_in,
                              void* d_out, int out_size, void* d_ws, size_t ws_size,
                              hipStream_t stream) {
    if (n_in < NIN) return;
    const int N = in_sizes[0] / 3;
    const int E = in_sizes[1] / 2;

    char* ws = (char*)d_ws;
    size_t off = 0;
    auto alloc = [&](size_t bytes) -> char* {
        char* p = ws + off;
        off = (off + bytes + 255) & ~(size_t)255;
        return p;
    };
    int* flags = (int*)alloc(32 * sizeof(int));
    int* bsums = (int*)alloc(128 * sizeof(int));
    float* canon[NIN];
    for (int i = 0; i < NIN; ++i) canon[i] = nullptr;
    for (int i = 0; i < NIN; ++i) {
        if (i == 1 || (i >= 10 && i <= 17)) continue;   // LSTM weights read raw
        canon[i] = (float*)alloc((size_t)in_sizes[i] * 4);
    }
    int* row32  = (int*)alloc((size_t)E * 4);
    int* col32  = (int*)alloc((size_t)E * 4);
    int* indptr = (int*)alloc((size_t)(N + 1) * 4);
    int* cnt    = (int*)alloc((size_t)N * 4);
    int* colS   = (int*)alloc((size_t)E * 4);
    float* hs   = (float*)alloc((size_t)N * 4);
    float* hd   = (float*)alloc((size_t)N * 4);
    // hJK buffer: bf16 hlin during GAT phase; bf16 P/Q after the LSTM
    float* hJK  = (float*)alloc((size_t)N * 128 * 4);
    unsigned short* hlin = (unsigned short*)hJK;
    unsigned short* xsb = (unsigned short*)alloc((size_t)3 * N * 128 * 2);  // bf16 xs
    unsigned short* Bpack = (unsigned short*)alloc((size_t)2 * 10 * 48 * 512 * 2);
    float* bsum = (float*)alloc((size_t)2 * 768 * 4);
    float* scoreP;
    if ((size_t)E >= (size_t)6 * N) scoreP = (float*)colS;   // dead after last aggr
    else                            scoreP = (float*)alloc((size_t)6 * N * 4);
    if (off > ws_size) return;
    unsigned short* P = (unsigned short*)hJK;           // bf16, N*128
    unsigned short* Q = (unsigned short*)hJK + (size_t)N * 128;

    InPtrs ip;
    for (int i = 0; i < NIN; ++i) { ip.p[i] = d_in[i]; ip.n[i] = in_sizes[i]; }

    k_sniff<<<NIN, 256, 0, stream>>>(ip, flags);

    // batched canonicalization of all f32/bf16 inputs
    {
        ConvJobs J;
        int nj = 0, blk = 0;
        for (int i = 0; i < NIN; ++i) {
            if (i == 1 || (i >= 10 && i <= 17)) continue;
            J.src[nj] = d_in[i];
            J.dst[nj] = canon[i];
            J.n[nj] = in_sizes[i];
            J.ai[nj] = i;
            J.blk0[nj] = blk;
            blk += (in_sizes[i] + 255) / 256;
            ++nj;
        }
        J.blk0[nj] = blk;
        J.njobs = nj;
        k_convall<<<blk, 256, 0, stream>>>(J, flags);
    }
    k_conve<<<(E + 255) / 256, 256, 0, stream>>>(d_in[1], row32, col32, E, flags);
    k_wpack<<<(2 * 10 * 48 * 512 + 255) / 256, 256, 0, stream>>>(
        d_in[10], d_in[11], d_in[14], d_in[15],
        d_in[12], d_in[13], d_in[16], d_in[17], flags, Bpack, bsum);

    // CSR by row (shared across all 3 GAT layers); parallel scan
    const int nb1k = (N + 1023) / 1024;
    k_zeroi<<<(N + 255) / 256, 256, 0, stream>>>(cnt, N);
    k_hist<<<(E + 255) / 256, 256, 0, stream>>>(row32, cnt, E);
    k_scan1<<<nb1k, 1024, 0, stream>>>(cnt, indptr, bsums, N);
    k_scan2<<<1, 64, 0, stream>>>(bsums, nb1k);
    k_scan3<<<(N + 255) / 256, 256, 0, stream>>>(bsums, indptr, N, nb1k);
    k_zeroi<<<(N + 255) / 256, 256, 0, stream>>>(cnt, N);
    k_fill<<<(E + 255) / 256, 256, 0, stream>>>(row32, col32, indptr, cnt, colS, E);

    // GAT layer 0 (in=3)
    k_lin0<<<(N + 3) / 4, 256, 0, stream>>>(canon[0], canon[2], canon[4], canon[5],
                                            hlin, hs, hd, N);
    k_aggr<<<(N + 3) / 4, 256, 0, stream>>>(hlin, hs, hd, indptr, colS, canon[3], xsb, N);
    // GAT layers 1..2 (in=128, bf16 in/out)
    for (int l = 1; l < 3; ++l) {
        const float* W  = canon[6] + (size_t)(l - 1) * 128 * 128;
        const float* bb = canon[7] + (size_t)(l - 1) * 128;
        const float* as = canon[8] + (size_t)(l - 1) * 128;
        const float* ad = canon[9] + (size_t)(l - 1) * 128;
        k_lin<<<(N + 7) / 8, 256, 0, stream>>>(xsb + (size_t)(l - 1) * N * 128, W, as, ad,
                                               hlin, hs, hd, N);
        k_aggr<<<(N + 3) / 4, 256, 0, stream>>>(hlin, hs, hd, indptr, colS, bb,
                                                xsb + (size_t)l * N * 128, N);
    }

    // fused bidirectional LSTM (MFMA, 64-row 12-wave) -> scores
    dim3 lgrid((N + 63) / 64, 2);
    k_lstm_mfma<<<lgrid, 768, 0, stream>>>(xsb, Bpack, bsum, canon[18], scoreP, N);

    float* out = (float*)d_out;
    // fused tail: JK finish + node MLP + P/Q (P/Q overwrite dead hlin buffer)
    k_tail<<<(N + 7) / 8, 256, 0, stream>>>(xsb, scoreP,
                                            canon[20], canon[21], canon[22], canon[23],
                                            canon[24], canon[25], P, Q, out, N);
    {
        long long tot = (long long)E * 16;
        int blocks = (int)((tot + 255) / 256);
        k_edge2<<<blocks, 256, 0, stream>>>(P, Q, row32, col32, canon[26], canon[27],
                                            out, (long long)E, N);
    }
}

// Round 11
// 836.493 us; speedup vs baseline: 41.5260x; 1.0132x over previous
//
#include <hip/hip_runtime.h>
#include <cstdint>
#include <cstddef>

// ---------------------------------------------------------------------------
// ParityGameGATNetwork: 3x GATConv -> JK bidirectional LSTM -> node/edge MLPs
// Round 11: (a) LSTM row-tile 64->32 (rf=2): acc 64->32 regs, total ~90/wave
// -> crosses the residency quantum (round-10 was 1 block/CU at ~148 regs incl
// accs); (b) k_aggr unroll 8 (gather latency); (c) k_lin/k_tail 4 nodes/wave
// (halves weight re-read traffic).
// ---------------------------------------------------------------------------

#define NIN 28
#define MAXJOBS 20

struct InPtrs { const void* p[NIN]; int n[NIN]; };

struct ConvJobs {
    const void* src[MAXJOBS];
    float* dst[MAXJOBS];
    int n[MAXJOBS];
    int ai[MAXJOBS];
    int blk0[MAXJOBS + 1];
    int njobs;
};

typedef short s16x4 __attribute__((ext_vector_type(4)));
typedef short s16x8 __attribute__((ext_vector_type(8)));
typedef float f32x4 __attribute__((ext_vector_type(4)));
typedef unsigned short u16x8 __attribute__((ext_vector_type(8)));

__device__ __forceinline__ float bf2f(unsigned short v) {
    unsigned int u = ((unsigned int)v) << 16;
    return __uint_as_float(u);
}

__device__ __forceinline__ unsigned short f2bf(float x) {
    unsigned int u = __float_as_uint(x);
    unsigned int r = u + 0x7fffu + ((u >> 16) & 1u);
    return (unsigned short)(r >> 16);
}

__device__ __forceinline__ float rdx(const void* p, size_t i, int isf32) {
    return isf32 ? ((const float*)p)[i] : bf2f(((const unsigned short*)p)[i]);
}

__device__ __forceinline__ float fast_tanh(float x) {
    float e = __expf(2.f * x);
    return 1.f - 2.f / (e + 1.f);
}

// ---------------- dtype sniffing -------------------------------------------
__global__ void k_sniff(InPtrs in, int* flags) {
    int ai = blockIdx.x;
    if (ai >= NIN) return;
    __shared__ int cnt;
    if (threadIdx.x == 0) cnt = 0;
    __syncthreads();
    if (ai == 1) {
        const int* w = (const int*)in.p[1];
        int nw = in.n[1] < 512 ? in.n[1] : 512;
        int local = 0;
        for (int i = threadIdx.x; i < nw; i += blockDim.x)
            if ((i & 1) && w[i] != 0) local++;
        atomicAdd(&cnt, local);
        __syncthreads();
        if (threadIdx.x == 0) flags[1] = (cnt < 4) ? 1 : 0;
        return;
    }
    const unsigned short* u = (const unsigned short*)in.p[ai];
    int ns = in.n[ai] < 256 ? in.n[ai] : 256;
    int local = 0;
    for (int i = threadIdx.x; i < ns; i += blockDim.x) {
        if (i & 1) continue;
        unsigned short v = u[i];
        int e = (v >> 7) & 0xff;
        if ((v & 0x7fff) != 0 && (e < 100 || e > 154)) local++;
    }
    atomicAdd(&cnt, local);
    __syncthreads();
    if (threadIdx.x == 0) flags[ai] = (cnt * 4 >= ns) ? 1 : 0;
}

// ---------------- batched canonicalization ---------------------------------
__global__ void k_convall(ConvJobs J, const int* __restrict__ flags) {
    int b = blockIdx.x;
    int j = 0;
    while (j + 1 < J.njobs && b >= J.blk0[j + 1]) ++j;
    int i = (b - J.blk0[j]) * 256 + threadIdx.x;
    if (i >= J.n[j]) return;
    J.dst[j][i] = rdx(J.src[j], i, flags[J.ai[j]]);
}

__global__ void k_conve(const void* src, int* row, int* col, int E, const int* flags) {
    int i = blockIdx.x * blockDim.x + threadIdx.x;
    if (i >= E) return;
    if (flags[1]) {
        const long long* s = (const long long*)src;
        row[i] = (int)s[i];
        col[i] = (int)s[(size_t)E + i];
    } else {
        const int* s = (const int*)src;
        row[i] = s[i];
        col[i] = s[(size_t)E + i];
    }
}

// ---------------- CSR build ------------------------------------------------
__global__ void k_zeroi(int* p, int n) {
    int i = blockIdx.x * blockDim.x + threadIdx.x;
    if (i < n) p[i] = 0;
}

__global__ void k_hist(const int* __restrict__ row, int* __restrict__ cnt, int E) {
    int i = blockIdx.x * blockDim.x + threadIdx.x;
    if (i < E) atomicAdd(&cnt[row[i]], 1);
}

__global__ void k_scan1(const int* __restrict__ deg, int* __restrict__ indptr,
                        int* __restrict__ bsums, int N) {
    __shared__ int buf[1024];
    const int t = threadIdx.x;
    const int base = blockIdx.x * 1024;
    int v = (base + t < N) ? deg[base + t] : 0;
    buf[t] = v;
    __syncthreads();
    for (int ofs = 1; ofs < 1024; ofs <<= 1) {
        int add = (t >= ofs) ? buf[t - ofs] : 0;
        __syncthreads();
        buf[t] += add;
        __syncthreads();
    }
    if (base + t < N) indptr[base + t] = buf[t] - v;
    if (t == 1023) bsums[blockIdx.x] = buf[1023];
}

__global__ void k_scan2(int* bsums, int nb) {
    if (threadIdx.x == 0 && blockIdx.x == 0) {
        int acc = 0;
        for (int j = 0; j < nb; ++j) { int v = bsums[j]; bsums[j] = acc; acc += v; }
        bsums[nb] = acc;
    }
}

__global__ void k_scan3(const int* __restrict__ bsums, int* __restrict__ indptr,
                        int N, int nb) {
    int i = blockIdx.x * blockDim.x + threadIdx.x;
    if (i < N) indptr[i] += bsums[i >> 10];
    if (i == 0) indptr[N] = bsums[nb];
}

__global__ void k_fill(const int* __restrict__ row, const int* __restrict__ col,
                       const int* __restrict__ indptr, int* __restrict__ cur,
                       int* __restrict__ colS, int E) {
    int i = blockIdx.x * blockDim.x + threadIdx.x;
    if (i >= E) return;
    int r = row[i];
    int p = indptr[r] + atomicAdd(&cur[r], 1);
    colS[p] = col[i];
}

// ---------------- GAT linear layer 0 (in=3), hlin out bf16 -----------------
__global__ __launch_bounds__(256) void k_lin0(
    const float* __restrict__ x, const float* __restrict__ W0,
    const float* __restrict__ asrc, const float* __restrict__ adst,
    unsigned short* __restrict__ hlin, float* __restrict__ hs, float* __restrict__ hd,
    int N) {
    const int wid = threadIdx.x >> 6, lane = threadIdx.x & 63;
    const int n = blockIdx.x * 4 + wid;
    if (n >= N) return;
    float x0 = x[(size_t)n * 3], x1 = x[(size_t)n * 3 + 1], x2 = x[(size_t)n * 3 + 2];
    const int c0 = lane, c1 = lane + 64;
    float h0 = x0 * W0[c0] + x1 * W0[128 + c0] + x2 * W0[256 + c0];
    float h1 = x0 * W0[c1] + x1 * W0[128 + c1] + x2 * W0[256 + c1];
    hlin[(size_t)n * 128 + c0] = f2bf(h0);
    hlin[(size_t)n * 128 + c1] = f2bf(h1);
    float sp = h0 * asrc[c0] + h1 * asrc[c1];
    float dp = h0 * adst[c0] + h1 * adst[c1];
    for (int o = 32; o; o >>= 1) { sp += __shfl_down(sp, o); dp += __shfl_down(dp, o); }
    if (lane == 0) { hs[n] = sp; hd[n] = dp; }
}

// ---------------- GAT linear (bf16 in/out), 4 nodes/wave -------------------
__global__ __launch_bounds__(256) void k_lin(
    const unsigned short* __restrict__ xin, const float* __restrict__ W,
    const float* __restrict__ asrc, const float* __restrict__ adst,
    unsigned short* __restrict__ hlin, float* __restrict__ hs, float* __restrict__ hd,
    int N) {
    __shared__ float xl[16][128];
    const int t = threadIdx.x;
    const int wid = t >> 6, lane = t & 63;
    const int nb = blockIdx.x * 16;
    for (int i = t; i < 2048; i += 256) {
        int r = i >> 7, k = i & 127;
        int n = nb + r;
        xl[r][k] = (n < N) ? bf2f(xin[(size_t)n * 128 + k]) : 0.f;
    }
    __syncthreads();
    const int c0 = lane, c1 = lane + 64;
    const int r0 = wid * 4;
    float h0[4], h1[4];
    #pragma unroll
    for (int j = 0; j < 4; ++j) { h0[j] = 0.f; h1[j] = 0.f; }
    #pragma unroll 2
    for (int k = 0; k < 128; ++k) {
        float w0 = W[k * 128 + c0], w1 = W[k * 128 + c1];
        #pragma unroll
        for (int j = 0; j < 4; ++j) {
            float xv = xl[r0 + j][k];
            h0[j] += xv * w0;
            h1[j] += xv * w1;
        }
    }
    float sp[4], dp[4];
    #pragma unroll
    for (int j = 0; j < 4; ++j) {
        sp[j] = h0[j] * asrc[c0] + h1[j] * asrc[c1];
        dp[j] = h0[j] * adst[c0] + h1[j] * adst[c1];
    }
    #pragma unroll
    for (int o = 32; o; o >>= 1) {
        #pragma unroll
        for (int j = 0; j < 4; ++j) {
            sp[j] += __shfl_down(sp[j], o);
            dp[j] += __shfl_down(dp[j], o);
        }
    }
    #pragma unroll
    for (int j = 0; j < 4; ++j) {
        int n = nb + r0 + j;
        if (n < N) {
            hlin[(size_t)n * 128 + c0] = f2bf(h0[j]);
            hlin[(size_t)n * 128 + c1] = f2bf(h1[j]);
            if (lane == 0) { hs[n] = sp[j]; hd[n] = dp[j]; }
        }
    }
}

// ---------------- GAT aggregation: online segment softmax, 8-way unrolled --
__global__ __launch_bounds__(256) void k_aggr(
    const unsigned short* __restrict__ hlin, const float* __restrict__ hs,
    const float* __restrict__ hd,
    const int* __restrict__ indptr, const int* __restrict__ colS,
    const float* __restrict__ b, unsigned short* __restrict__ xout, int N) {
    const int wid = threadIdx.x >> 6, lane = threadIdx.x & 63;
    const int n = blockIdx.x * 4 + wid;
    if (n >= N) return;
    const int s = indptr[n], epos = indptr[n + 1];
    const float hdv = hd[n];
    const int c0 = lane, c1 = lane + 64;
    float m = -1e30f, d = 0.f, a0 = 0.f, a1 = 0.f;
    int idx = s;
    for (; idx + 8 <= epos; idx += 8) {
        int cl[8];
        #pragma unroll
        for (int j = 0; j < 8; ++j) cl[j] = colS[idx + j];
        float e[8];
        #pragma unroll
        for (int j = 0; j < 8; ++j) {
            float ev = hs[cl[j]] + hdv;
            e[j] = (ev > 0.f) ? ev : 0.2f * ev;
        }
        float v0[8], v1[8];
        #pragma unroll
        for (int j = 0; j < 8; ++j) {
            const unsigned short* hp = hlin + (size_t)cl[j] * 128;
            v0[j] = bf2f(hp[c0]);
            v1[j] = bf2f(hp[c1]);
        }
        float m8 = e[0];
        #pragma unroll
        for (int j = 1; j < 8; ++j) m8 = fmaxf(m8, e[j]);
        if (m8 > m) {
            float sc = __expf(m - m8);
            a0 *= sc; a1 *= sc; d *= sc; m = m8;
        }
        #pragma unroll
        for (int j = 0; j < 8; ++j) {
            float w = __expf(e[j] - m);
            a0 += w * v0[j];
            a1 += w * v1[j];
            d  += w;
        }
    }
    for (; idx < epos; ++idx) {
        int col = colS[idx];
        float e = hs[col] + hdv;
        e = (e > 0.f) ? e : 0.2f * e;
        const unsigned short* hr = hlin + (size_t)col * 128;
        float v0 = bf2f(hr[c0]), v1 = bf2f(hr[c1]);
        if (e > m) {
            float sc = __expf(m - e);
            a0 = a0 * sc + v0;
            a1 = a1 * sc + v1;
            d  = d * sc + 1.f;
            m  = e;
        } else {
            float w = __expf(e - m);
            a0 += w * v0;
            a1 += w * v1;
            d  += w;
        }
    }
    float inv = 1.f / (d + 1e-16f);
    float r0 = a0 * inv + b[c0];
    float r1 = a1 * inv + b[c1];
    xout[(size_t)n * 128 + c0] = f2bf(fmaxf(r0, 0.f));
    xout[(size_t)n * 128 + c1] = f2bf(fmaxf(r1, 0.f));
}

// ---------------- LSTM weight pack into MFMA fragment order ----------------
__global__ void k_wpack(const void* Wihf, const void* Whhf,
                        const void* Wihb, const void* Whhb,
                        const void* bihf, const void* bhhf,
                        const void* bihb, const void* bhhb,
                        const int* __restrict__ flags,
                        unsigned short* __restrict__ Bpack, float* __restrict__ bsum) {
    int idx = blockIdx.x * blockDim.x + threadIdx.x;
    const int TOT = 2 * 10 * 48 * 512;
    if (idx < TOT) {
        int dir = idx / (10 * 48 * 512);
        int r   = idx % (10 * 48 * 512);
        int kb  = r / (48 * 512);
        int r2  = r % (48 * 512);
        int f   = r2 / 512;
        int q   = r2 % 512;
        int lane = q >> 3, j = q & 7;
        int k   = kb * 32 + ((j >> 2) * 16) + ((lane >> 4) * 4) + (j & 3);
        int col = f * 16 + (lane & 15);
        float v;
        if (k < 128)
            v = dir ? rdx(Wihb, (size_t)col * 128 + k, flags[14])
                    : rdx(Wihf, (size_t)col * 128 + k, flags[10]);
        else
            v = dir ? rdx(Whhb, (size_t)col * 192 + (k - 128), flags[15])
                    : rdx(Whhf, (size_t)col * 192 + (k - 128), flags[11]);
        Bpack[idx] = f2bf(v);
    }
    if (idx < 2 * 768) {
        int d = idx / 768, j = idx % 768;
        bsum[idx] = d ? rdx(bihb, j, flags[16]) + rdx(bhhb, j, flags[17])
                      : rdx(bihf, j, flags[12]) + rdx(bhhf, j, flags[13]);
    }
}

// ---------------- fused bidirectional LSTM: 32 rows, 12 waves --------------
// Grid (ceil(N/32), 2); 768 threads = 12 waves. Wave bf owns gate-frags
// {bf, bf+12, bf+24, bf+36} (all 4 gates of units m = bf*16 + ccol) across
// 2 row-frags. acc = 8 f32x4 -> ~90 total regs incl acc (residency quantum).
__global__ __launch_bounds__(768) void k_lstm_mfma(
    const unsigned short* __restrict__ xsb,  // [3][N][128] bf16
    const unsigned short* __restrict__ Bpack,// [2][10][48][512] bf16
    const float* __restrict__ bsum,          // [2][768]
    const float* __restrict__ attW,          // [384]
    float* __restrict__ scoreP,              // [2][3][N]
    int N) {
    __shared__ unsigned short AS[32][332];   // x:[0,128)  h:[128,320)
    __shared__ float scoreS[32];
    const int t = threadIdx.x;
    const int bf = t >> 6, lane = t & 63;
    const int dir = blockIdx.y;
    const int n0 = blockIdx.x * 32;
    const int ccol = lane & 15;
    const int klane = lane >> 4;
    const int lrow = klane * 4;
    const int akl = klane * 4;
    const int m = bf * 16 + ccol;            // this thread's hidden unit

    const float bI = bsum[dir * 768 + m];
    const float bF = bsum[dir * 768 + 192 + m];
    const float bG = bsum[dir * 768 + 384 + m];
    const float bO = bsum[dir * 768 + 576 + m];
    const float awt = attW[dir * 192 + m];
    float cst[8];
    #pragma unroll
    for (int i = 0; i < 8; ++i) cst[i] = 0.f;

    const unsigned short* Bd = Bpack + (size_t)dir * 10 * 48 * 512;

    for (int s = 0; s < 3; ++s) {
        const int l = dir ? (2 - s) : s;
        // ---- stage x tile: 32x128 bf16 (512 items; threads t<512) ----
        if (t < 512) {
            const unsigned short* xsrc = xsb + ((size_t)l * N + n0) * 128;
            int r = t >> 4, kq = (t & 15) * 8;
            u16x8 v = (u16x8)(0);
            if (n0 + r < N) v = *(const u16x8*)(xsrc + (size_t)r * 128 + kq);
            *(u16x8*)&AS[r][kq] = v;
        }
        if (t < 32) scoreS[t] = 0.f;
        __syncthreads();

        // ---- MFMA GEMM over K ----
        const int KB = s ? 10 : 4;
        f32x4 acc[2][4];
        #pragma unroll
        for (int rf = 0; rf < 2; ++rf)
            #pragma unroll
            for (int g = 0; g < 4; ++g) acc[rf][g] = (f32x4)(0.f);
        for (int kb = 0; kb < KB; ++kb) {
            const unsigned short* bb = Bd + ((size_t)kb * 48 + bf) * 512 + lane * 8;
            s16x8 bfr[4];
            #pragma unroll
            for (int g = 0; g < 4; ++g) bfr[g] = *(const s16x8*)(bb + (size_t)g * 6144);
            const int k0 = kb * 32 + akl;
            s16x8 av[2];
            #pragma unroll
            for (int rf = 0; rf < 2; ++rf) {
                s16x4 alo = *(const s16x4*)&AS[rf * 16 + ccol][k0];
                s16x4 ahi = *(const s16x4*)&AS[rf * 16 + ccol][k0 + 16];
                av[rf] = __builtin_shufflevector(alo, ahi, 0, 1, 2, 3, 4, 5, 6, 7);
            }
            #pragma unroll
            for (int rf = 0; rf < 2; ++rf)
                #pragma unroll
                for (int g = 0; g < 4; ++g)
                    acc[rf][g] = __builtin_amdgcn_mfma_f32_16x16x32_bf16(
                        av[rf], bfr[g], acc[rf][g], 0, 0, 0);
        }
        __syncthreads();   // all A reads done before h overwrite

        // ---- cell epilogue: one unit per thread, 8 rows ----
        float sp[8];
        #pragma unroll
        for (int rf = 0; rf < 2; ++rf) {
            #pragma unroll
            for (int reg = 0; reg < 4; ++reg) {
                float gI = acc[rf][0][reg] + bI;
                float gF = acc[rf][1][reg] + bF;
                float gG = acc[rf][2][reg] + bG;
                float gO = acc[rf][3][reg] + bO;
                float ig = 1.f / (1.f + __expf(-gI));
                float fg = 1.f / (1.f + __expf(-gF));
                float gt = fast_tanh(gG);
                float og = 1.f / (1.f + __expf(-gO));
                int ci = rf * 4 + reg;
                float cn = fg * cst[ci] + ig * gt;
                cst[ci] = cn;
                float hh = og * fast_tanh(cn);
                AS[rf * 16 + lrow + reg][128 + m] = f2bf(hh);
                sp[ci] = hh * awt;
            }
        }
        #pragma unroll
        for (int o = 1; o < 16; o <<= 1) {
            #pragma unroll
            for (int i = 0; i < 8; ++i) sp[i] += __shfl_xor(sp[i], o);
        }
        if (ccol == 0) {
            #pragma unroll
            for (int i = 0; i < 8; ++i)
                atomicAdd(&scoreS[(i >> 2) * 16 + lrow + (i & 3)], sp[i]);
        }
        __syncthreads();
        if (t < 32 && n0 + t < N)
            scoreP[(size_t)(dir * 3 + l) * N + n0 + t] = scoreS[t];
    }
}

// ---------------- fused tail: JK softmax-sum + node MLP + P/Q, 16 nodes ----
__global__ __launch_bounds__(256) void k_tail(
    const unsigned short* __restrict__ xsb, const float* __restrict__ scoreP,
    const float* __restrict__ nW1, const float* __restrict__ nb1,
    const float* __restrict__ nW2, const float* __restrict__ nb2,
    const float* __restrict__ eW1, const float* __restrict__ eb1,
    unsigned short* __restrict__ P, unsigned short* __restrict__ Q,
    float* __restrict__ out, int N) {
    __shared__ float xl[16][128];
    __shared__ float al[16][4];
    const int t = threadIdx.x;
    const int wid = t >> 6, lane = t & 63;
    const int nb = blockIdx.x * 16;
    if (t < 16) {
        int n = nb + t;
        float e0 = 0.f, e1 = 0.f, e2 = 0.f;
        if (n < N) {
            float s0 = scoreP[n]                 + scoreP[(size_t)3 * N + n];
            float s1 = scoreP[(size_t)N + n]     + scoreP[(size_t)4 * N + n];
            float s2 = scoreP[(size_t)2 * N + n] + scoreP[(size_t)5 * N + n];
            float mm = fmaxf(s0, fmaxf(s1, s2));
            e0 = __expf(s0 - mm); e1 = __expf(s1 - mm); e2 = __expf(s2 - mm);
            float inv = 1.f / (e0 + e1 + e2);
            e0 *= inv; e1 *= inv; e2 *= inv;
        }
        al[t][0] = e0; al[t][1] = e1; al[t][2] = e2;
    }
    __syncthreads();
    const size_t L1o = (size_t)N * 128, L2o = 2 * L1o;
    for (int i = t; i < 2048; i += 256) {
        int r = i >> 7, k = i & 127;
        int n = nb + r;
        float v = 0.f;
        if (n < N) {
            size_t p = (size_t)n * 128 + k;
            v = al[r][0] * bf2f(xsb[p]) + al[r][1] * bf2f(xsb[L1o + p])
              + al[r][2] * bf2f(xsb[L2o + p]);
        }
        xl[r][k] = v;
    }
    __syncthreads();
    const int c0 = lane, c1 = lane + 64;
    const int r0 = wid * 4;
    // ---- node MLP (4 nodes/wave) ----
    {
        float h0[4], h1[4];
        #pragma unroll
        for (int j = 0; j < 4; ++j) { h0[j] = 0.f; h1[j] = 0.f; }
        #pragma unroll 2
        for (int k = 0; k < 128; ++k) {
            float w0 = nW1[k * 128 + c0], w1 = nW1[k * 128 + c1];
            #pragma unroll
            for (int j = 0; j < 4; ++j) {
                float xv = xl[r0 + j][k];
                h0[j] += xv * w0;
                h1[j] += xv * w1;
            }
        }
        float p0[4], p1[4];
        #pragma unroll
        for (int j = 0; j < 4; ++j) {
            float a = fmaxf(h0[j] + nb1[c0], 0.f);
            float bq = fmaxf(h1[j] + nb1[c1], 0.f);
            p0[j] = a * nW2[c0 * 2 + 0] + bq * nW2[c1 * 2 + 0];
            p1[j] = a * nW2[c0 * 2 + 1] + bq * nW2[c1 * 2 + 1];
        }
        #pragma unroll
        for (int o = 32; o; o >>= 1) {
            #pragma unroll
            for (int j = 0; j < 4; ++j) {
                p0[j] += __shfl_down(p0[j], o);
                p1[j] += __shfl_down(p1[j], o);
            }
        }
        if (lane == 0) {
            #pragma unroll
            for (int j = 0; j < 4; ++j) {
                int n = nb + r0 + j;
                if (n < N) {
                    float l0 = p0[j] + nb2[0], l1 = p1[j] + nb2[1];
                    float mm = fmaxf(l0, l1);
                    float e0 = __expf(l0 - mm), e1 = __expf(l1 - mm);
                    float inv = 1.f / (e0 + e1);
                    out[2 * (size_t)n]     = e0 * inv;
                    out[2 * (size_t)n + 1] = e1 * inv;
                }
            }
        }
    }
    // ---- P/Q precompute (bf16 out, 4 nodes/wave) ----
    {
        float pp0[4], pp1[4], qq0[4], qq1[4];
        #pragma unroll
        for (int j = 0; j < 4; ++j) { pp0[j] = 0.f; pp1[j] = 0.f; qq0[j] = 0.f; qq1[j] = 0.f; }
        for (int k = 0; k < 128; ++k) {
            float wp0 = eW1[k * 128 + c0], wp1 = eW1[k * 128 + c1];
            float wq0 = eW1[(128 + k) * 128 + c0], wq1 = eW1[(128 + k) * 128 + c1];
            #pragma unroll
            for (int j = 0; j < 4; ++j) {
                float xv = xl[r0 + j][k];
                pp0[j] += xv * wp0; pp1[j] += xv * wp1;
                qq0[j] += xv * wq0; qq1[j] += xv * wq1;
            }
        }
        #pragma unroll
        for (int j = 0; j < 4; ++j) {
            int n = nb + r0 + j;
            if (n < N) {
                P[(size_t)n * 128 + c0] = f2bf(pp0[j] + eb1[c0]);
                P[(size_t)n * 128 + c1] = f2bf(pp1[j] + eb1[c1]);
                Q[(size_t)n * 128 + c0] = f2bf(qq0[j]);
                Q[(size_t)n * 128 + c1] = f2bf(qq1[j]);
            }
        }
    }
}

// ---------------- edge MLP finish: gather-add-relu-dot (bf16 P/Q) ----------
__global__ __launch_bounds__(256) void k_edge2(
    const unsigned short* __restrict__ P, const unsigned short* __restrict__ Q,
    const int* __restrict__ row, const int* __restrict__ col,
    const float* __restrict__ W2, const float* __restrict__ b2,
    float* __restrict__ out, long long E, int N) {
    long long g = (((long long)blockIdx.x * blockDim.x) + threadIdx.x) >> 4;
    const int sl = threadIdx.x & 15;
    if (g >= E) return;
    int r = row[g], c = col[g];
    u16x8 pv = *(const u16x8*)(P + (size_t)r * 128 + sl * 8);
    u16x8 qv = *(const u16x8*)(Q + (size_t)c * 128 + sl * 8);
    const float4* w2 = (const float4*)W2 + sl * 4;
    float l0 = 0.f, l1 = 0.f;
    #pragma unroll
    for (int jj = 0; jj < 4; ++jj) {
        float h0 = fmaxf(bf2f(pv[2 * jj])     + bf2f(qv[2 * jj]), 0.f);
        float h1 = fmaxf(bf2f(pv[2 * jj + 1]) + bf2f(qv[2 * jj + 1]), 0.f);
        float4 wv = w2[jj];
        l0 += h0 * wv.x + h1 * wv.z;
        l1 += h0 * wv.y + h1 * wv.w;
    }
    #pragma unroll
    for (int o = 1; o < 16; o <<= 1) { l0 += __shfl_xor(l0, o); l1 += __shfl_xor(l1, o); }
    if (sl == 0) {
        l0 += b2[0]; l1 += b2[1];
        float mm = fmaxf(l0, l1);
        float e0 = __expf(l0 - mm), e1 = __expf(l1 - mm);
        float inv = 1.f / (e0 + e1);
        out[2 * (long long)N + 2 * g]     = e0 * inv;
        out[2 * (long long)N + 2 * g + 1] = e1 * inv;
    }
}

// ---------------------------------------------------------------------------
extern "C" void kernel_launch(void* const* d_in, const int* in_sizes, int n_in,
                              void* d_out, int out_size, void* d_ws, size_t ws_size,
                              hipStream_t stream) {
    if (n_in < NIN) return;
    const int N = in_sizes[0] / 3;
    const int E = in_sizes[1] / 2;

    char* ws = (char*)d_ws;
    size_t off = 0;
    auto alloc = [&](size_t bytes) -> char* {
        char* p = ws + off;
        off = (off + bytes + 255) & ~(size_t)255;
        return p;
    };
    int* flags = (int*)alloc(32 * sizeof(int));
    int* bsums = (int*)alloc(128 * sizeof(int));
    float* canon[NIN];
    for (int i = 0; i < NIN; ++i) canon[i] = nullptr;
    for (int i = 0; i < NIN; ++i) {
        if (i == 1 || (i >= 10 && i <= 17)) continue;   // LSTM weights read raw
        canon[i] = (float*)alloc((size_t)in_sizes[i] * 4);
    }
    int* row32  = (int*)alloc((size_t)E * 4);
    int* col32  = (int*)alloc((size_t)E * 4);
    int* indptr = (int*)alloc((size_t)(N + 1) * 4);
    int* cnt    = (int*)alloc((size_t)N * 4);
    int* colS   = (int*)alloc((size_t)E * 4);
    float* hs   = (float*)alloc((size_t)N * 4);
    float* hd   = (float*)alloc((size_t)N * 4);
    // hJK buffer: bf16 hlin during GAT phase; bf16 P/Q after the LSTM
    float* hJK  = (float*)alloc((size_t)N * 128 * 4);
    unsigned short* hlin = (unsigned short*)hJK;
    unsigned short* xsb = (unsigned short*)alloc((size_t)3 * N * 128 * 2);  // bf16 xs
    unsigned short* Bpack = (unsigned short*)alloc((size_t)2 * 10 * 48 * 512 * 2);
    float* bsum = (float*)alloc((size_t)2 * 768 * 4);
    float* scoreP;
    if ((size_t)E >= (size_t)6 * N) scoreP = (float*)colS;   // dead after last aggr
    else                            scoreP = (float*)alloc((size_t)6 * N * 4);
    if (off > ws_size) return;
    unsigned short* P = (unsigned short*)hJK;           // bf16, N*128
    unsigned short* Q = (unsigned short*)hJK + (size_t)N * 128;

    InPtrs ip;
    for (int i = 0; i < NIN; ++i) { ip.p[i] = d_in[i]; ip.n[i] = in_sizes[i]; }

    k_sniff<<<NIN, 256, 0, stream>>>(ip, flags);

    // batched canonicalization of all f32/bf16 inputs
    {
        ConvJobs J;
        int nj = 0, blk = 0;
        for (int i = 0; i < NIN; ++i) {
            if (i == 1 || (i >= 10 && i <= 17)) continue;
            J.src[nj] = d_in[i];
            J.dst[nj] = canon[i];
            J.n[nj] = in_sizes[i];
            J.ai[nj] = i;
            J.blk0[nj] = blk;
            blk += (in_sizes[i] + 255) / 256;
            ++nj;
        }
        J.blk0[nj] = blk;
        J.njobs = nj;
        k_convall<<<blk, 256, 0, stream>>>(J, flags);
    }
    k_conve<<<(E + 255) / 256, 256, 0, stream>>>(d_in[1], row32, col32, E, flags);
    k_wpack<<<(2 * 10 * 48 * 512 + 255) / 256, 256, 0, stream>>>(
        d_in[10], d_in[11], d_in[14], d_in[15],
        d_in[12], d_in[13], d_in[16], d_in[17], flags, Bpack, bsum);

    // CSR by row (shared across all 3 GAT layers); parallel scan
    const int nb1k = (N + 1023) / 1024;
    k_zeroi<<<(N + 255) / 256, 256, 0, stream>>>(cnt, N);
    k_hist<<<(E + 255) / 256, 256, 0, stream>>>(row32, cnt, E);
    k_scan1<<<nb1k, 1024, 0, stream>>>(cnt, indptr, bsums, N);
    k_scan2<<<1, 64, 0, stream>>>(bsums, nb1k);
    k_scan3<<<(N + 255) / 256, 256, 0, stream>>>(bsums, indptr, N, nb1k);
    k_zeroi<<<(N + 255) / 256, 256, 0, stream>>>(cnt, N);
    k_fill<<<(E + 255) / 256, 256, 0, stream>>>(row32, col32, indptr, cnt, colS, E);

    // GAT layer 0 (in=3)
    k_lin0<<<(N + 3) / 4, 256, 0, stream>>>(canon[0], canon[2], canon[4], canon[5],
                                            hlin, hs, hd, N);
    k_aggr<<<(N + 3) / 4, 256, 0, stream>>>(hlin, hs, hd, indptr, colS, canon[3], xsb, N);
    // GAT layers 1..2 (in=128, bf16 in/out)
    for (int l = 1; l < 3; ++l) {
        const float* W  = canon[6] + (size_t)(l - 1) * 128 * 128;
        const float* bb = canon[7] + (size_t)(l - 1) * 128;
        const float* as = canon[8] + (size_t)(l - 1) * 128;
        const float* ad = canon[9] + (size_t)(l - 1) * 128;
        k_lin<<<(N + 15) / 16, 256, 0, stream>>>(xsb + (size_t)(l - 1) * N * 128, W, as, ad,
                                                 hlin, hs, hd, N);
        k_aggr<<<(N + 3) / 4, 256, 0, stream>>>(hlin, hs, hd, indptr, colS, bb,
                                                xsb + (size_t)l * N * 128, N);
    }

    // fused bidirectional LSTM (MFMA, 32-row 12-wave) -> scores
    dim3 lgrid((N + 31) / 32, 2);
    k_lstm_mfma<<<lgrid, 768, 0, stream>>>(xsb, Bpack, bsum, canon[18], scoreP, N);

    float* out = (float*)d_out;
    // fused tail: JK finish + node MLP + P/Q (P/Q overwrite dead hlin buffer)
    k_tail<<<(N + 15) / 16, 256, 0, stream>>>(xsb, scoreP,
                                              canon[20], canon[21], canon[22], canon[23],
                                              canon[24], canon[25], P, Q, out, N);
    {
        long long tot = (long long)E * 16;
        int blocks = (int)((tot + 255) / 256);
        k_edge2<<<blocks, 256, 0, stream>>>(P, Q, row32, col32, canon[26], canon[27],
                                            out, (long long)E, N);
    }
}

// Round 12
// 778.458 us; speedup vs baseline: 44.6218x; 1.0746x over previous
//
#include <hip/hip_runtime.h>
#include <cstdint>
#include <cstddef>

// ---------------------------------------------------------------------------
// ParityGameGATNetwork: 3x GATConv -> JK bidirectional LSTM -> node/edge MLPs
// Round 12: revert LSTM to the round-10 configuration (64 rows x 12 waves,
// rf=4, B ping-pong; measured 310us vs round-11's 365us regression -- the
// 32-row variant doubled Bpack traffic without gaining residency). Keep all
// round-11 non-LSTM wins (aggr unroll-8, 4-node/wave lin/tail).
// ---------------------------------------------------------------------------

#define NIN 28
#define MAXJOBS 20

struct InPtrs { const void* p[NIN]; int n[NIN]; };

struct ConvJobs {
    const void* src[MAXJOBS];
    float* dst[MAXJOBS];
    int n[MAXJOBS];
    int ai[MAXJOBS];
    int blk0[MAXJOBS + 1];
    int njobs;
};

typedef short s16x4 __attribute__((ext_vector_type(4)));
typedef short s16x8 __attribute__((ext_vector_type(8)));
typedef float f32x4 __attribute__((ext_vector_type(4)));
typedef unsigned short u16x8 __attribute__((ext_vector_type(8)));

__device__ __forceinline__ float bf2f(unsigned short v) {
    unsigned int u = ((unsigned int)v) << 16;
    return __uint_as_float(u);
}

__device__ __forceinline__ unsigned short f2bf(float x) {
    unsigned int u = __float_as_uint(x);
    unsigned int r = u + 0x7fffu + ((u >> 16) & 1u);
    return (unsigned short)(r >> 16);
}

__device__ __forceinline__ float rdx(const void* p, size_t i, int isf32) {
    return isf32 ? ((const float*)p)[i] : bf2f(((const unsigned short*)p)[i]);
}

__device__ __forceinline__ float fast_tanh(float x) {
    float e = __expf(2.f * x);
    return 1.f - 2.f / (e + 1.f);
}

// ---------------- dtype sniffing -------------------------------------------
__global__ void k_sniff(InPtrs in, int* flags) {
    int ai = blockIdx.x;
    if (ai >= NIN) return;
    __shared__ int cnt;
    if (threadIdx.x == 0) cnt = 0;
    __syncthreads();
    if (ai == 1) {
        const int* w = (const int*)in.p[1];
        int nw = in.n[1] < 512 ? in.n[1] : 512;
        int local = 0;
        for (int i = threadIdx.x; i < nw; i += blockDim.x)
            if ((i & 1) && w[i] != 0) local++;
        atomicAdd(&cnt, local);
        __syncthreads();
        if (threadIdx.x == 0) flags[1] = (cnt < 4) ? 1 : 0;
        return;
    }
    const unsigned short* u = (const unsigned short*)in.p[ai];
    int ns = in.n[ai] < 256 ? in.n[ai] : 256;
    int local = 0;
    for (int i = threadIdx.x; i < ns; i += blockDim.x) {
        if (i & 1) continue;
        unsigned short v = u[i];
        int e = (v >> 7) & 0xff;
        if ((v & 0x7fff) != 0 && (e < 100 || e > 154)) local++;
    }
    atomicAdd(&cnt, local);
    __syncthreads();
    if (threadIdx.x == 0) flags[ai] = (cnt * 4 >= ns) ? 1 : 0;
}

// ---------------- batched canonicalization ---------------------------------
__global__ void k_convall(ConvJobs J, const int* __restrict__ flags) {
    int b = blockIdx.x;
    int j = 0;
    while (j + 1 < J.njobs && b >= J.blk0[j + 1]) ++j;
    int i = (b - J.blk0[j]) * 256 + threadIdx.x;
    if (i >= J.n[j]) return;
    J.dst[j][i] = rdx(J.src[j], i, flags[J.ai[j]]);
}

__global__ void k_conve(const void* src, int* row, int* col, int E, const int* flags) {
    int i = blockIdx.x * blockDim.x + threadIdx.x;
    if (i >= E) return;
    if (flags[1]) {
        const long long* s = (const long long*)src;
        row[i] = (int)s[i];
        col[i] = (int)s[(size_t)E + i];
    } else {
        const int* s = (const int*)src;
        row[i] = s[i];
        col[i] = s[(size_t)E + i];
    }
}

// ---------------- CSR build ------------------------------------------------
__global__ void k_zeroi(int* p, int n) {
    int i = blockIdx.x * blockDim.x + threadIdx.x;
    if (i < n) p[i] = 0;
}

__global__ void k_hist(const int* __restrict__ row, int* __restrict__ cnt, int E) {
    int i = blockIdx.x * blockDim.x + threadIdx.x;
    if (i < E) atomicAdd(&cnt[row[i]], 1);
}

__global__ void k_scan1(const int* __restrict__ deg, int* __restrict__ indptr,
                        int* __restrict__ bsums, int N) {
    __shared__ int buf[1024];
    const int t = threadIdx.x;
    const int base = blockIdx.x * 1024;
    int v = (base + t < N) ? deg[base + t] : 0;
    buf[t] = v;
    __syncthreads();
    for (int ofs = 1; ofs < 1024; ofs <<= 1) {
        int add = (t >= ofs) ? buf[t - ofs] : 0;
        __syncthreads();
        buf[t] += add;
        __syncthreads();
    }
    if (base + t < N) indptr[base + t] = buf[t] - v;
    if (t == 1023) bsums[blockIdx.x] = buf[1023];
}

__global__ void k_scan2(int* bsums, int nb) {
    if (threadIdx.x == 0 && blockIdx.x == 0) {
        int acc = 0;
        for (int j = 0; j < nb; ++j) { int v = bsums[j]; bsums[j] = acc; acc += v; }
        bsums[nb] = acc;
    }
}

__global__ void k_scan3(const int* __restrict__ bsums, int* __restrict__ indptr,
                        int N, int nb) {
    int i = blockIdx.x * blockDim.x + threadIdx.x;
    if (i < N) indptr[i] += bsums[i >> 10];
    if (i == 0) indptr[N] = bsums[nb];
}

__global__ void k_fill(const int* __restrict__ row, const int* __restrict__ col,
                       const int* __restrict__ indptr, int* __restrict__ cur,
                       int* __restrict__ colS, int E) {
    int i = blockIdx.x * blockDim.x + threadIdx.x;
    if (i >= E) return;
    int r = row[i];
    int p = indptr[r] + atomicAdd(&cur[r], 1);
    colS[p] = col[i];
}

// ---------------- GAT linear layer 0 (in=3), hlin out bf16 -----------------
__global__ __launch_bounds__(256) void k_lin0(
    const float* __restrict__ x, const float* __restrict__ W0,
    const float* __restrict__ asrc, const float* __restrict__ adst,
    unsigned short* __restrict__ hlin, float* __restrict__ hs, float* __restrict__ hd,
    int N) {
    const int wid = threadIdx.x >> 6, lane = threadIdx.x & 63;
    const int n = blockIdx.x * 4 + wid;
    if (n >= N) return;
    float x0 = x[(size_t)n * 3], x1 = x[(size_t)n * 3 + 1], x2 = x[(size_t)n * 3 + 2];
    const int c0 = lane, c1 = lane + 64;
    float h0 = x0 * W0[c0] + x1 * W0[128 + c0] + x2 * W0[256 + c0];
    float h1 = x0 * W0[c1] + x1 * W0[128 + c1] + x2 * W0[256 + c1];
    hlin[(size_t)n * 128 + c0] = f2bf(h0);
    hlin[(size_t)n * 128 + c1] = f2bf(h1);
    float sp = h0 * asrc[c0] + h1 * asrc[c1];
    float dp = h0 * adst[c0] + h1 * adst[c1];
    for (int o = 32; o; o >>= 1) { sp += __shfl_down(sp, o); dp += __shfl_down(dp, o); }
    if (lane == 0) { hs[n] = sp; hd[n] = dp; }
}

// ---------------- GAT linear (bf16 in/out), 4 nodes/wave -------------------
__global__ __launch_bounds__(256) void k_lin(
    const unsigned short* __restrict__ xin, const float* __restrict__ W,
    const float* __restrict__ asrc, const float* __restrict__ adst,
    unsigned short* __restrict__ hlin, float* __restrict__ hs, float* __restrict__ hd,
    int N) {
    __shared__ float xl[16][128];
    const int t = threadIdx.x;
    const int wid = t >> 6, lane = t & 63;
    const int nb = blockIdx.x * 16;
    for (int i = t; i < 2048; i += 256) {
        int r = i >> 7, k = i & 127;
        int n = nb + r;
        xl[r][k] = (n < N) ? bf2f(xin[(size_t)n * 128 + k]) : 0.f;
    }
    __syncthreads();
    const int c0 = lane, c1 = lane + 64;
    const int r0 = wid * 4;
    float h0[4], h1[4];
    #pragma unroll
    for (int j = 0; j < 4; ++j) { h0[j] = 0.f; h1[j] = 0.f; }
    #pragma unroll 2
    for (int k = 0; k < 128; ++k) {
        float w0 = W[k * 128 + c0], w1 = W[k * 128 + c1];
        #pragma unroll
        for (int j = 0; j < 4; ++j) {
            float xv = xl[r0 + j][k];
            h0[j] += xv * w0;
            h1[j] += xv * w1;
        }
    }
    float sp[4], dp[4];
    #pragma unroll
    for (int j = 0; j < 4; ++j) {
        sp[j] = h0[j] * asrc[c0] + h1[j] * asrc[c1];
        dp[j] = h0[j] * adst[c0] + h1[j] * adst[c1];
    }
    #pragma unroll
    for (int o = 32; o; o >>= 1) {
        #pragma unroll
        for (int j = 0; j < 4; ++j) {
            sp[j] += __shfl_down(sp[j], o);
            dp[j] += __shfl_down(dp[j], o);
        }
    }
    #pragma unroll
    for (int j = 0; j < 4; ++j) {
        int n = nb + r0 + j;
        if (n < N) {
            hlin[(size_t)n * 128 + c0] = f2bf(h0[j]);
            hlin[(size_t)n * 128 + c1] = f2bf(h1[j]);
            if (lane == 0) { hs[n] = sp[j]; hd[n] = dp[j]; }
        }
    }
}

// ---------------- GAT aggregation: online segment softmax, 8-way unrolled --
__global__ __launch_bounds__(256) void k_aggr(
    const unsigned short* __restrict__ hlin, const float* __restrict__ hs,
    const float* __restrict__ hd,
    const int* __restrict__ indptr, const int* __restrict__ colS,
    const float* __restrict__ b, unsigned short* __restrict__ xout, int N) {
    const int wid = threadIdx.x >> 6, lane = threadIdx.x & 63;
    const int n = blockIdx.x * 4 + wid;
    if (n >= N) return;
    const int s = indptr[n], epos = indptr[n + 1];
    const float hdv = hd[n];
    const int c0 = lane, c1 = lane + 64;
    float m = -1e30f, d = 0.f, a0 = 0.f, a1 = 0.f;
    int idx = s;
    for (; idx + 8 <= epos; idx += 8) {
        int cl[8];
        #pragma unroll
        for (int j = 0; j < 8; ++j) cl[j] = colS[idx + j];
        float e[8];
        #pragma unroll
        for (int j = 0; j < 8; ++j) {
            float ev = hs[cl[j]] + hdv;
            e[j] = (ev > 0.f) ? ev : 0.2f * ev;
        }
        float v0[8], v1[8];
        #pragma unroll
        for (int j = 0; j < 8; ++j) {
            const unsigned short* hp = hlin + (size_t)cl[j] * 128;
            v0[j] = bf2f(hp[c0]);
            v1[j] = bf2f(hp[c1]);
        }
        float m8 = e[0];
        #pragma unroll
        for (int j = 1; j < 8; ++j) m8 = fmaxf(m8, e[j]);
        if (m8 > m) {
            float sc = __expf(m - m8);
            a0 *= sc; a1 *= sc; d *= sc; m = m8;
        }
        #pragma unroll
        for (int j = 0; j < 8; ++j) {
            float w = __expf(e[j] - m);
            a0 += w * v0[j];
            a1 += w * v1[j];
            d  += w;
        }
    }
    for (; idx < epos; ++idx) {
        int col = colS[idx];
        float e = hs[col] + hdv;
        e = (e > 0.f) ? e : 0.2f * e;
        const unsigned short* hr = hlin + (size_t)col * 128;
        float v0 = bf2f(hr[c0]), v1 = bf2f(hr[c1]);
        if (e > m) {
            float sc = __expf(m - e);
            a0 = a0 * sc + v0;
            a1 = a1 * sc + v1;
            d  = d * sc + 1.f;
            m  = e;
        } else {
            float w = __expf(e - m);
            a0 += w * v0;
            a1 += w * v1;
            d  += w;
        }
    }
    float inv = 1.f / (d + 1e-16f);
    float r0 = a0 * inv + b[c0];
    float r1 = a1 * inv + b[c1];
    xout[(size_t)n * 128 + c0] = f2bf(fmaxf(r0, 0.f));
    xout[(size_t)n * 128 + c1] = f2bf(fmaxf(r1, 0.f));
}

// ---------------- LSTM weight pack into MFMA fragment order ----------------
__global__ void k_wpack(const void* Wihf, const void* Whhf,
                        const void* Wihb, const void* Whhb,
                        const void* bihf, const void* bhhf,
                        const void* bihb, const void* bhhb,
                        const int* __restrict__ flags,
                        unsigned short* __restrict__ Bpack, float* __restrict__ bsum) {
    int idx = blockIdx.x * blockDim.x + threadIdx.x;
    const int TOT = 2 * 10 * 48 * 512;
    if (idx < TOT) {
        int dir = idx / (10 * 48 * 512);
        int r   = idx % (10 * 48 * 512);
        int kb  = r / (48 * 512);
        int r2  = r % (48 * 512);
        int f   = r2 / 512;
        int q   = r2 % 512;
        int lane = q >> 3, j = q & 7;
        int k   = kb * 32 + ((j >> 2) * 16) + ((lane >> 4) * 4) + (j & 3);
        int col = f * 16 + (lane & 15);
        float v;
        if (k < 128)
            v = dir ? rdx(Wihb, (size_t)col * 128 + k, flags[14])
                    : rdx(Wihf, (size_t)col * 128 + k, flags[10]);
        else
            v = dir ? rdx(Whhb, (size_t)col * 192 + (k - 128), flags[15])
                    : rdx(Whhf, (size_t)col * 192 + (k - 128), flags[11]);
        Bpack[idx] = f2bf(v);
    }
    if (idx < 2 * 768) {
        int d = idx / 768, j = idx % 768;
        bsum[idx] = d ? rdx(bihb, j, flags[16]) + rdx(bhhb, j, flags[17])
                      : rdx(bihf, j, flags[12]) + rdx(bhhf, j, flags[13]);
    }
}

// ---------------- fused bidirectional LSTM: 64 rows, 12 waves (round-10) ---
// Grid (ceil(N/64), 2); 768 threads = 12 waves. Wave w = base-frag bf in
// [0,12): owns gate-frags {bf, bf+12, bf+24, bf+36} (all 4 gates of units
// m = bf*16 + ccol) across 4 row-frags. Per kb: 4 B loads feed 16 MFMAs
// (64 FLOP/B; no within-block B duplication). B ping-pong prefetch.
__global__ __launch_bounds__(768, 3) void k_lstm_mfma(
    const unsigned short* __restrict__ xsb,  // [3][N][128] bf16
    const unsigned short* __restrict__ Bpack,// [2][10][48][512] bf16
    const float* __restrict__ bsum,          // [2][768]
    const float* __restrict__ attW,          // [384]
    float* __restrict__ scoreP,              // [2][3][N]
    int N) {
    __shared__ unsigned short AS[64][332];   // x:[0,128)  h:[128,320)
    __shared__ float scoreS[64];
    const int t = threadIdx.x;
    const int bf = t >> 6, lane = t & 63;
    const int dir = blockIdx.y;
    const int n0 = blockIdx.x * 64;
    const int ccol = lane & 15;
    const int klane = lane >> 4;
    const int lrow = klane * 4;
    const int akl = klane * 4;
    const int m = bf * 16 + ccol;            // this thread's hidden unit

    const float bI = bsum[dir * 768 + m];
    const float bF = bsum[dir * 768 + 192 + m];
    const float bG = bsum[dir * 768 + 384 + m];
    const float bO = bsum[dir * 768 + 576 + m];
    const float awt = attW[dir * 192 + m];
    float cst[16];
    #pragma unroll
    for (int i = 0; i < 16; ++i) cst[i] = 0.f;

    const unsigned short* Bd = Bpack + (size_t)dir * 10 * 48 * 512;

    for (int s = 0; s < 3; ++s) {
        const int l = dir ? (2 - s) : s;
        // ---- stage x tile: 64x128 bf16 ----
        {
            const unsigned short* xsrc = xsb + ((size_t)l * N + n0) * 128;
            for (int i = t; i < 1024; i += 768) {
                int r = i >> 4, kq = (i & 15) * 8;
                u16x8 v = (u16x8)(0);
                if (n0 + r < N) v = *(const u16x8*)(xsrc + (size_t)r * 128 + kq);
                *(u16x8*)&AS[r][kq] = v;
            }
        }
        if (t < 64) scoreS[t] = 0.f;
        __syncthreads();

        // ---- MFMA GEMM over K, B ping-pong prefetch ----
        const int KB = s ? 10 : 4;               // both even
        f32x4 acc[4][4];
        #pragma unroll
        for (int rf = 0; rf < 4; ++rf)
            #pragma unroll
            for (int g = 0; g < 4; ++g) acc[rf][g] = (f32x4)(0.f);
        s16x8 bA[4], bB[4];
        {
            const unsigned short* bb = Bd + (size_t)bf * 512 + lane * 8;   // kb=0
            #pragma unroll
            for (int g = 0; g < 4; ++g) bA[g] = *(const s16x8*)(bb + (size_t)g * 6144);
        }
        for (int kb = 0; kb < KB; kb += 2) {
            {   // prefetch kb+1
                const unsigned short* bb = Bd + ((size_t)(kb + 1) * 48 + bf) * 512 + lane * 8;
                #pragma unroll
                for (int g = 0; g < 4; ++g) bB[g] = *(const s16x8*)(bb + (size_t)g * 6144);
            }
            {   // compute kb on bA
                const int k0 = kb * 32 + akl;
                s16x8 av[4];
                #pragma unroll
                for (int rf = 0; rf < 4; ++rf) {
                    s16x4 alo = *(const s16x4*)&AS[rf * 16 + ccol][k0];
                    s16x4 ahi = *(const s16x4*)&AS[rf * 16 + ccol][k0 + 16];
                    av[rf] = __builtin_shufflevector(alo, ahi, 0, 1, 2, 3, 4, 5, 6, 7);
                }
                #pragma unroll
                for (int rf = 0; rf < 4; ++rf)
                    #pragma unroll
                    for (int g = 0; g < 4; ++g)
                        acc[rf][g] = __builtin_amdgcn_mfma_f32_16x16x32_bf16(
                            av[rf], bA[g], acc[rf][g], 0, 0, 0);
            }
            if (kb + 2 < KB) {   // prefetch kb+2
                const unsigned short* bb = Bd + ((size_t)(kb + 2) * 48 + bf) * 512 + lane * 8;
                #pragma unroll
                for (int g = 0; g < 4; ++g) bA[g] = *(const s16x8*)(bb + (size_t)g * 6144);
            }
            {   // compute kb+1 on bB
                const int k0 = (kb + 1) * 32 + akl;
                s16x8 av[4];
                #pragma unroll
                for (int rf = 0; rf < 4; ++rf) {
                    s16x4 alo = *(const s16x4*)&AS[rf * 16 + ccol][k0];
                    s16x4 ahi = *(const s16x4*)&AS[rf * 16 + ccol][k0 + 16];
                    av[rf] = __builtin_shufflevector(alo, ahi, 0, 1, 2, 3, 4, 5, 6, 7);
                }
                #pragma unroll
                for (int rf = 0; rf < 4; ++rf)
                    #pragma unroll
                    for (int g = 0; g < 4; ++g)
                        acc[rf][g] = __builtin_amdgcn_mfma_f32_16x16x32_bf16(
                            av[rf], bB[g], acc[rf][g], 0, 0, 0);
            }
        }
        __syncthreads();   // all A reads done before h overwrite

        // ---- cell epilogue: one unit per thread, 16 rows ----
        float sp[16];
        #pragma unroll
        for (int rf = 0; rf < 4; ++rf) {
            #pragma unroll
            for (int reg = 0; reg < 4; ++reg) {
                float gI = acc[rf][0][reg] + bI;
                float gF = acc[rf][1][reg] + bF;
                float gG = acc[rf][2][reg] + bG;
                float gO = acc[rf][3][reg] + bO;
                float ig = 1.f / (1.f + __expf(-gI));
                float fg = 1.f / (1.f + __expf(-gF));
                float gt = fast_tanh(gG);
                float og = 1.f / (1.f + __expf(-gO));
                int ci = rf * 4 + reg;
                float cn = fg * cst[ci] + ig * gt;
                cst[ci] = cn;
                float hh = og * fast_tanh(cn);
                AS[rf * 16 + lrow + reg][128 + m] = f2bf(hh);
                sp[ci] = hh * awt;
            }
        }
        #pragma unroll
        for (int o = 1; o < 16; o <<= 1) {
            #pragma unroll
            for (int i = 0; i < 16; ++i) sp[i] += __shfl_xor(sp[i], o);
        }
        if (ccol == 0) {
            #pragma unroll
            for (int i = 0; i < 16; ++i)
                atomicAdd(&scoreS[(i >> 2) * 16 + lrow + (i & 3)], sp[i]);
        }
        __syncthreads();
        if (t < 64 && n0 + t < N)
            scoreP[(size_t)(dir * 3 + l) * N + n0 + t] = scoreS[t];
    }
}

// ---------------- fused tail: JK softmax-sum + node MLP + P/Q, 16 nodes ----
__global__ __launch_bounds__(256) void k_tail(
    const unsigned short* __restrict__ xsb, const float* __restrict__ scoreP,
    const float* __restrict__ nW1, const float* __restrict__ nb1,
    const float* __restrict__ nW2, const float* __restrict__ nb2,
    const float* __restrict__ eW1, const float* __restrict__ eb1,
    unsigned short* __restrict__ P, unsigned short* __restrict__ Q,
    float* __restrict__ out, int N) {
    __shared__ float xl[16][128];
    __shared__ float al[16][4];
    const int t = threadIdx.x;
    const int wid = t >> 6, lane = t & 63;
    const int nb = blockIdx.x * 16;
    if (t < 16) {
        int n = nb + t;
        float e0 = 0.f, e1 = 0.f, e2 = 0.f;
        if (n < N) {
            float s0 = scoreP[n]                 + scoreP[(size_t)3 * N + n];
            float s1 = scoreP[(size_t)N + n]     + scoreP[(size_t)4 * N + n];
            float s2 = scoreP[(size_t)2 * N + n] + scoreP[(size_t)5 * N + n];
            float mm = fmaxf(s0, fmaxf(s1, s2));
            e0 = __expf(s0 - mm); e1 = __expf(s1 - mm); e2 = __expf(s2 - mm);
            float inv = 1.f / (e0 + e1 + e2);
            e0 *= inv; e1 *= inv; e2 *= inv;
        }
        al[t][0] = e0; al[t][1] = e1; al[t][2] = e2;
    }
    __syncthreads();
    const size_t L1o = (size_t)N * 128, L2o = 2 * L1o;
    for (int i = t; i < 2048; i += 256) {
        int r = i >> 7, k = i & 127;
        int n = nb + r;
        float v = 0.f;
        if (n < N) {
            size_t p = (size_t)n * 128 + k;
            v = al[r][0] * bf2f(xsb[p]) + al[r][1] * bf2f(xsb[L1o + p])
              + al[r][2] * bf2f(xsb[L2o + p]);
        }
        xl[r][k] = v;
    }
    __syncthreads();
    const int c0 = lane, c1 = lane + 64;
    const int r0 = wid * 4;
    // ---- node MLP (4 nodes/wave) ----
    {
        float h0[4], h1[4];
        #pragma unroll
        for (int j = 0; j < 4; ++j) { h0[j] = 0.f; h1[j] = 0.f; }
        #pragma unroll 2
        for (int k = 0; k < 128; ++k) {
            float w0 = nW1[k * 128 + c0], w1 = nW1[k * 128 + c1];
            #pragma unroll
            for (int j = 0; j < 4; ++j) {
                float xv = xl[r0 + j][k];
                h0[j] += xv * w0;
                h1[j] += xv * w1;
            }
        }
        float p0[4], p1[4];
        #pragma unroll
        for (int j = 0; j < 4; ++j) {
            float a = fmaxf(h0[j] + nb1[c0], 0.f);
            float bq = fmaxf(h1[j] + nb1[c1], 0.f);
            p0[j] = a * nW2[c0 * 2 + 0] + bq * nW2[c1 * 2 + 0];
            p1[j] = a * nW2[c0 * 2 + 1] + bq * nW2[c1 * 2 + 1];
        }
        #pragma unroll
        for (int o = 32; o; o >>= 1) {
            #pragma unroll
            for (int j = 0; j < 4; ++j) {
                p0[j] += __shfl_down(p0[j], o);
                p1[j] += __shfl_down(p1[j], o);
            }
        }
        if (lane == 0) {
            #pragma unroll
            for (int j = 0; j < 4; ++j) {
                int n = nb + r0 + j;
                if (n < N) {
                    float l0 = p0[j] + nb2[0], l1 = p1[j] + nb2[1];
                    float mm = fmaxf(l0, l1);
                    float e0 = __expf(l0 - mm), e1 = __expf(l1 - mm);
                    float inv = 1.f / (e0 + e1);
                    out[2 * (size_t)n]     = e0 * inv;
                    out[2 * (size_t)n + 1] = e1 * inv;
                }
            }
        }
    }
    // ---- P/Q precompute (bf16 out, 4 nodes/wave) ----
    {
        float pp0[4], pp1[4], qq0[4], qq1[4];
        #pragma unroll
        for (int j = 0; j < 4; ++j) { pp0[j] = 0.f; pp1[j] = 0.f; qq0[j] = 0.f; qq1[j] = 0.f; }
        for (int k = 0; k < 128; ++k) {
            float wp0 = eW1[k * 128 + c0], wp1 = eW1[k * 128 + c1];
            float wq0 = eW1[(128 + k) * 128 + c0], wq1 = eW1[(128 + k) * 128 + c1];
            #pragma unroll
            for (int j = 0; j < 4; ++j) {
                float xv = xl[r0 + j][k];
                pp0[j] += xv * wp0; pp1[j] += xv * wp1;
                qq0[j] += xv * wq0; qq1[j] += xv * wq1;
            }
        }
        #pragma unroll
        for (int j = 0; j < 4; ++j) {
            int n = nb + r0 + j;
            if (n < N) {
                P[(size_t)n * 128 + c0] = f2bf(pp0[j] + eb1[c0]);
                P[(size_t)n * 128 + c1] = f2bf(pp1[j] + eb1[c1]);
                Q[(size_t)n * 128 + c0] = f2bf(qq0[j]);
                Q[(size_t)n * 128 + c1] = f2bf(qq1[j]);
            }
        }
    }
}

// ---------------- edge MLP finish: gather-add-relu-dot (bf16 P/Q) ----------
__global__ __launch_bounds__(256) void k_edge2(
    const unsigned short* __restrict__ P, const unsigned short* __restrict__ Q,
    const int* __restrict__ row, const int* __restrict__ col,
    const float* __restrict__ W2, const float* __restrict__ b2,
    float* __restrict__ out, long long E, int N) {
    long long g = (((long long)blockIdx.x * blockDim.x) + threadIdx.x) >> 4;
    const int sl = threadIdx.x & 15;
    if (g >= E) return;
    int r = row[g], c = col[g];
    u16x8 pv = *(const u16x8*)(P + (size_t)r * 128 + sl * 8);
    u16x8 qv = *(const u16x8*)(Q + (size_t)c * 128 + sl * 8);
    const float4* w2 = (const float4*)W2 + sl * 4;
    float l0 = 0.f, l1 = 0.f;
    #pragma unroll
    for (int jj = 0; jj < 4; ++jj) {
        float h0 = fmaxf(bf2f(pv[2 * jj])     + bf2f(qv[2 * jj]), 0.f);
        float h1 = fmaxf(bf2f(pv[2 * jj + 1]) + bf2f(qv[2 * jj + 1]), 0.f);
        float4 wv = w2[jj];
        l0 += h0 * wv.x + h1 * wv.z;
        l1 += h0 * wv.y + h1 * wv.w;
    }
    #pragma unroll
    for (int o = 1; o < 16; o <<= 1) { l0 += __shfl_xor(l0, o); l1 += __shfl_xor(l1, o); }
    if (sl == 0) {
        l0 += b2[0]; l1 += b2[1];
        float mm = fmaxf(l0, l1);
        float e0 = __expf(l0 - mm), e1 = __expf(l1 - mm);
        float inv = 1.f / (e0 + e1);
        out[2 * (long long)N + 2 * g]     = e0 * inv;
        out[2 * (long long)N + 2 * g + 1] = e1 * inv;
    }
}

// ---------------------------------------------------------------------------
extern "C" void kernel_launch(void* const* d_in, const int* in_sizes, int n_in,
                              void* d_out, int out_size, void* d_ws, size_t ws_size,
                              hipStream_t stream) {
    if (n_in < NIN) return;
    const int N = in_sizes[0] / 3;
    const int E = in_sizes[1] / 2;

    char* ws = (char*)d_ws;
    size_t off = 0;
    auto alloc = [&](size_t bytes) -> char* {
        char* p = ws + off;
        off = (off + bytes + 255) & ~(size_t)255;
        return p;
    };
    int* flags = (int*)alloc(32 * sizeof(int));
    int* bsums = (int*)alloc(128 * sizeof(int));
    float* canon[NIN];
    for (int i = 0; i < NIN; ++i) canon[i] = nullptr;
    for (int i = 0; i < NIN; ++i) {
        if (i == 1 || (i >= 10 && i <= 17)) continue;   // LSTM weights read raw
        canon[i] = (float*)alloc((size_t)in_sizes[i] * 4);
    }
    int* row32  = (int*)alloc((size_t)E * 4);
    int* col32  = (int*)alloc((size_t)E * 4);
    int* indptr = (int*)alloc((size_t)(N + 1) * 4);
    int* cnt    = (int*)alloc((size_t)N * 4);
    int* colS   = (int*)alloc((size_t)E * 4);
    float* hs   = (float*)alloc((size_t)N * 4);
    float* hd   = (float*)alloc((size_t)N * 4);
    // hJK buffer: bf16 hlin during GAT phase; bf16 P/Q after the LSTM
    float* hJK  = (float*)alloc((size_t)N * 128 * 4);
    unsigned short* hlin = (unsigned short*)hJK;
    unsigned short* xsb = (unsigned short*)alloc((size_t)3 * N * 128 * 2);  // bf16 xs
    unsigned short* Bpack = (unsigned short*)alloc((size_t)2 * 10 * 48 * 512 * 2);
    float* bsum = (float*)alloc((size_t)2 * 768 * 4);
    float* scoreP;
    if ((size_t)E >= (size_t)6 * N) scoreP = (float*)colS;   // dead after last aggr
    else                            scoreP = (float*)alloc((size_t)6 * N * 4);
    if (off > ws_size) return;
    unsigned short* P = (unsigned short*)hJK;           // bf16, N*128
    unsigned short* Q = (unsigned short*)hJK + (size_t)N * 128;

    InPtrs ip;
    for (int i = 0; i < NIN; ++i) { ip.p[i] = d_in[i]; ip.n[i] = in_sizes[i]; }

    k_sniff<<<NIN, 256, 0, stream>>>(ip, flags);

    // batched canonicalization of all f32/bf16 inputs
    {
        ConvJobs J;
        int nj = 0, blk = 0;
        for (int i = 0; i < NIN; ++i) {
            if (i == 1 || (i >= 10 && i <= 17)) continue;
            J.src[nj] = d_in[i];
            J.dst[nj] = canon[i];
            J.n[nj] = in_sizes[i];
            J.ai[nj] = i;
            J.blk0[nj] = blk;
            blk += (in_sizes[i] + 255) / 256;
            ++nj;
        }
        J.blk0[nj] = blk;
        J.njobs = nj;
        k_convall<<<blk, 256, 0, stream>>>(J, flags);
    }
    k_conve<<<(E + 255) / 256, 256, 0, stream>>>(d_in[1], row32, col32, E, flags);
    k_wpack<<<(2 * 10 * 48 * 512 + 255) / 256, 256, 0, stream>>>(
        d_in[10], d_in[11], d_in[14], d_in[15],
        d_in[12], d_in[13], d_in[16], d_in[17], flags, Bpack, bsum);

    // CSR by row (shared across all 3 GAT layers); parallel scan
    const int nb1k = (N + 1023) / 1024;
    k_zeroi<<<(N + 255) / 256, 256, 0, stream>>>(cnt, N);
    k_hist<<<(E + 255) / 256, 256, 0, stream>>>(row32, cnt, E);
    k_scan1<<<nb1k, 1024, 0, stream>>>(cnt, indptr, bsums, N);
    k_scan2<<<1, 64, 0, stream>>>(bsums, nb1k);
    k_scan3<<<(N + 255) / 256, 256, 0, stream>>>(bsums, indptr, N, nb1k);
    k_zeroi<<<(N + 255) / 256, 256, 0, stream>>>(cnt, N);
    k_fill<<<(E + 255) / 256, 256, 0, stream>>>(row32, col32, indptr, cnt, colS, E);

    // GAT layer 0 (in=3)
    k_lin0<<<(N + 3) / 4, 256, 0, stream>>>(canon[0], canon[2], canon[4], canon[5],
                                            hlin, hs, hd, N);
    k_aggr<<<(N + 3) / 4, 256, 0, stream>>>(hlin, hs, hd, indptr, colS, canon[3], xsb, N);
    // GAT layers 1..2 (in=128, bf16 in/out)
    for (int l = 1; l < 3; ++l) {
        const float* W  = canon[6] + (size_t)(l - 1) * 128 * 128;
        const float* bb = canon[7] + (size_t)(l - 1) * 128;
        const float* as = canon[8] + (size_t)(l - 1) * 128;
        const float* ad = canon[9] + (size_t)(l - 1) * 128;
        k_lin<<<(N + 15) / 16, 256, 0, stream>>>(xsb + (size_t)(l - 1) * N * 128, W, as, ad,
                                                 hlin, hs, hd, N);
        k_aggr<<<(N + 3) / 4, 256, 0, stream>>>(hlin, hs, hd, indptr, colS, bb,
                                                xsb + (size_t)l * N * 128, N);
    }

    // fused bidirectional LSTM (MFMA, 64-row 12-wave) -> scores
    dim3 lgrid((N + 63) / 64, 2);
    k_lstm_mfma<<<lgrid, 768, 0, stream>>>(xsb, Bpack, bsum, canon[18], scoreP, N);

    float* out = (float*)d_out;
    // fused tail: JK finish + node MLP + P/Q (P/Q overwrite dead hlin buffer)
    k_tail<<<(N + 15) / 16, 256, 0, stream>>>(xsb, scoreP,
                                              canon[20], canon[21], canon[22], canon[23],
                                              canon[24], canon[25], P, Q, out, N);
    {
        long long tot = (long long)E * 16;
        int blocks = (int)((tot + 255) / 256);
        k_edge2<<<blocks, 256, 0, stream>>>(P, Q, row32, col32, canon[26], canon[27],
                                            out, (long long)E, N);
    }
}

// Round 13
// 709.826 us; speedup vs baseline: 48.9362x; 1.0967x over previous
//
#include <hip/hip_runtime.h>
#include <cstdint>
#include <cstddef>

// ---------------------------------------------------------------------------
// ParityGameGATNetwork: 3x GATConv -> JK bidirectional LSTM -> node/edge MLPs
// Round 13: replace IEEE division sequences (v_div_scale/.../v_div_fixup,
// ~10 instrs each) with raw v_rcp_f32 via __builtin_amdgcn_rcpf in all hot
// paths: LSTM cell (5 divs/cell -> dominant VALU cost), aggr normalizer,
// tail/edge softmaxes. ~1ulp rcp is negligible vs 0.0105 threshold.
// Everything else identical to round 12.
// ---------------------------------------------------------------------------

#define NIN 28
#define MAXJOBS 20

struct InPtrs { const void* p[NIN]; int n[NIN]; };

struct ConvJobs {
    const void* src[MAXJOBS];
    float* dst[MAXJOBS];
    int n[MAXJOBS];
    int ai[MAXJOBS];
    int blk0[MAXJOBS + 1];
    int njobs;
};

typedef short s16x4 __attribute__((ext_vector_type(4)));
typedef short s16x8 __attribute__((ext_vector_type(8)));
typedef float f32x4 __attribute__((ext_vector_type(4)));
typedef unsigned short u16x8 __attribute__((ext_vector_type(8)));

__device__ __forceinline__ float bf2f(unsigned short v) {
    unsigned int u = ((unsigned int)v) << 16;
    return __uint_as_float(u);
}

__device__ __forceinline__ unsigned short f2bf(float x) {
    unsigned int u = __float_as_uint(x);
    unsigned int r = u + 0x7fffu + ((u >> 16) & 1u);
    return (unsigned short)(r >> 16);
}

__device__ __forceinline__ float rdx(const void* p, size_t i, int isf32) {
    return isf32 ? ((const float*)p)[i] : bf2f(((const unsigned short*)p)[i]);
}

__device__ __forceinline__ float frcp(float x) {        // raw v_rcp_f32 (~1ulp)
    return __builtin_amdgcn_rcpf(x);
}

__device__ __forceinline__ float sigm(float x) {
    return frcp(1.f + __expf(-x));
}

__device__ __forceinline__ float fast_tanh(float x) {
    return 1.f - 2.f * frcp(__expf(2.f * x) + 1.f);
}

// ---------------- dtype sniffing -------------------------------------------
__global__ void k_sniff(InPtrs in, int* flags) {
    int ai = blockIdx.x;
    if (ai >= NIN) return;
    __shared__ int cnt;
    if (threadIdx.x == 0) cnt = 0;
    __syncthreads();
    if (ai == 1) {
        const int* w = (const int*)in.p[1];
        int nw = in.n[1] < 512 ? in.n[1] : 512;
        int local = 0;
        for (int i = threadIdx.x; i < nw; i += blockDim.x)
            if ((i & 1) && w[i] != 0) local++;
        atomicAdd(&cnt, local);
        __syncthreads();
        if (threadIdx.x == 0) flags[1] = (cnt < 4) ? 1 : 0;
        return;
    }
    const unsigned short* u = (const unsigned short*)in.p[ai];
    int ns = in.n[ai] < 256 ? in.n[ai] : 256;
    int local = 0;
    for (int i = threadIdx.x; i < ns; i += blockDim.x) {
        if (i & 1) continue;
        unsigned short v = u[i];
        int e = (v >> 7) & 0xff;
        if ((v & 0x7fff) != 0 && (e < 100 || e > 154)) local++;
    }
    atomicAdd(&cnt, local);
    __syncthreads();
    if (threadIdx.x == 0) flags[ai] = (cnt * 4 >= ns) ? 1 : 0;
}

// ---------------- batched canonicalization ---------------------------------
__global__ void k_convall(ConvJobs J, const int* __restrict__ flags) {
    int b = blockIdx.x;
    int j = 0;
    while (j + 1 < J.njobs && b >= J.blk0[j + 1]) ++j;
    int i = (b - J.blk0[j]) * 256 + threadIdx.x;
    if (i >= J.n[j]) return;
    J.dst[j][i] = rdx(J.src[j], i, flags[J.ai[j]]);
}

__global__ void k_conve(const void* src, int* row, int* col, int E, const int* flags) {
    int i = blockIdx.x * blockDim.x + threadIdx.x;
    if (i >= E) return;
    if (flags[1]) {
        const long long* s = (const long long*)src;
        row[i] = (int)s[i];
        col[i] = (int)s[(size_t)E + i];
    } else {
        const int* s = (const int*)src;
        row[i] = s[i];
        col[i] = s[(size_t)E + i];
    }
}

// ---------------- CSR build ------------------------------------------------
__global__ void k_zeroi(int* p, int n) {
    int i = blockIdx.x * blockDim.x + threadIdx.x;
    if (i < n) p[i] = 0;
}

__global__ void k_hist(const int* __restrict__ row, int* __restrict__ cnt, int E) {
    int i = blockIdx.x * blockDim.x + threadIdx.x;
    if (i < E) atomicAdd(&cnt[row[i]], 1);
}

__global__ void k_scan1(const int* __restrict__ deg, int* __restrict__ indptr,
                        int* __restrict__ bsums, int N) {
    __shared__ int buf[1024];
    const int t = threadIdx.x;
    const int base = blockIdx.x * 1024;
    int v = (base + t < N) ? deg[base + t] : 0;
    buf[t] = v;
    __syncthreads();
    for (int ofs = 1; ofs < 1024; ofs <<= 1) {
        int add = (t >= ofs) ? buf[t - ofs] : 0;
        __syncthreads();
        buf[t] += add;
        __syncthreads();
    }
    if (base + t < N) indptr[base + t] = buf[t] - v;
    if (t == 1023) bsums[blockIdx.x] = buf[1023];
}

__global__ void k_scan2(int* bsums, int nb) {
    if (threadIdx.x == 0 && blockIdx.x == 0) {
        int acc = 0;
        for (int j = 0; j < nb; ++j) { int v = bsums[j]; bsums[j] = acc; acc += v; }
        bsums[nb] = acc;
    }
}

__global__ void k_scan3(const int* __restrict__ bsums, int* __restrict__ indptr,
                        int N, int nb) {
    int i = blockIdx.x * blockDim.x + threadIdx.x;
    if (i < N) indptr[i] += bsums[i >> 10];
    if (i == 0) indptr[N] = bsums[nb];
}

__global__ void k_fill(const int* __restrict__ row, const int* __restrict__ col,
                       const int* __restrict__ indptr, int* __restrict__ cur,
                       int* __restrict__ colS, int E) {
    int i = blockIdx.x * blockDim.x + threadIdx.x;
    if (i >= E) return;
    int r = row[i];
    int p = indptr[r] + atomicAdd(&cur[r], 1);
    colS[p] = col[i];
}

// ---------------- GAT linear layer 0 (in=3), hlin out bf16 -----------------
__global__ __launch_bounds__(256) void k_lin0(
    const float* __restrict__ x, const float* __restrict__ W0,
    const float* __restrict__ asrc, const float* __restrict__ adst,
    unsigned short* __restrict__ hlin, float* __restrict__ hs, float* __restrict__ hd,
    int N) {
    const int wid = threadIdx.x >> 6, lane = threadIdx.x & 63;
    const int n = blockIdx.x * 4 + wid;
    if (n >= N) return;
    float x0 = x[(size_t)n * 3], x1 = x[(size_t)n * 3 + 1], x2 = x[(size_t)n * 3 + 2];
    const int c0 = lane, c1 = lane + 64;
    float h0 = x0 * W0[c0] + x1 * W0[128 + c0] + x2 * W0[256 + c0];
    float h1 = x0 * W0[c1] + x1 * W0[128 + c1] + x2 * W0[256 + c1];
    hlin[(size_t)n * 128 + c0] = f2bf(h0);
    hlin[(size_t)n * 128 + c1] = f2bf(h1);
    float sp = h0 * asrc[c0] + h1 * asrc[c1];
    float dp = h0 * adst[c0] + h1 * adst[c1];
    for (int o = 32; o; o >>= 1) { sp += __shfl_down(sp, o); dp += __shfl_down(dp, o); }
    if (lane == 0) { hs[n] = sp; hd[n] = dp; }
}

// ---------------- GAT linear (bf16 in/out), 4 nodes/wave -------------------
__global__ __launch_bounds__(256) void k_lin(
    const unsigned short* __restrict__ xin, const float* __restrict__ W,
    const float* __restrict__ asrc, const float* __restrict__ adst,
    unsigned short* __restrict__ hlin, float* __restrict__ hs, float* __restrict__ hd,
    int N) {
    __shared__ float xl[16][128];
    const int t = threadIdx.x;
    const int wid = t >> 6, lane = t & 63;
    const int nb = blockIdx.x * 16;
    for (int i = t; i < 2048; i += 256) {
        int r = i >> 7, k = i & 127;
        int n = nb + r;
        xl[r][k] = (n < N) ? bf2f(xin[(size_t)n * 128 + k]) : 0.f;
    }
    __syncthreads();
    const int c0 = lane, c1 = lane + 64;
    const int r0 = wid * 4;
    float h0[4], h1[4];
    #pragma unroll
    for (int j = 0; j < 4; ++j) { h0[j] = 0.f; h1[j] = 0.f; }
    #pragma unroll 2
    for (int k = 0; k < 128; ++k) {
        float w0 = W[k * 128 + c0], w1 = W[k * 128 + c1];
        #pragma unroll
        for (int j = 0; j < 4; ++j) {
            float xv = xl[r0 + j][k];
            h0[j] += xv * w0;
            h1[j] += xv * w1;
        }
    }
    float sp[4], dp[4];
    #pragma unroll
    for (int j = 0; j < 4; ++j) {
        sp[j] = h0[j] * asrc[c0] + h1[j] * asrc[c1];
        dp[j] = h0[j] * adst[c0] + h1[j] * adst[c1];
    }
    #pragma unroll
    for (int o = 32; o; o >>= 1) {
        #pragma unroll
        for (int j = 0; j < 4; ++j) {
            sp[j] += __shfl_down(sp[j], o);
            dp[j] += __shfl_down(dp[j], o);
        }
    }
    #pragma unroll
    for (int j = 0; j < 4; ++j) {
        int n = nb + r0 + j;
        if (n < N) {
            hlin[(size_t)n * 128 + c0] = f2bf(h0[j]);
            hlin[(size_t)n * 128 + c1] = f2bf(h1[j]);
            if (lane == 0) { hs[n] = sp[j]; hd[n] = dp[j]; }
        }
    }
}

// ---------------- GAT aggregation: online segment softmax, 8-way unrolled --
__global__ __launch_bounds__(256) void k_aggr(
    const unsigned short* __restrict__ hlin, const float* __restrict__ hs,
    const float* __restrict__ hd,
    const int* __restrict__ indptr, const int* __restrict__ colS,
    const float* __restrict__ b, unsigned short* __restrict__ xout, int N) {
    const int wid = threadIdx.x >> 6, lane = threadIdx.x & 63;
    const int n = blockIdx.x * 4 + wid;
    if (n >= N) return;
    const int s = indptr[n], epos = indptr[n + 1];
    const float hdv = hd[n];
    const int c0 = lane, c1 = lane + 64;
    float m = -1e30f, d = 0.f, a0 = 0.f, a1 = 0.f;
    int idx = s;
    for (; idx + 8 <= epos; idx += 8) {
        int cl[8];
        #pragma unroll
        for (int j = 0; j < 8; ++j) cl[j] = colS[idx + j];
        float e[8];
        #pragma unroll
        for (int j = 0; j < 8; ++j) {
            float ev = hs[cl[j]] + hdv;
            e[j] = (ev > 0.f) ? ev : 0.2f * ev;
        }
        float v0[8], v1[8];
        #pragma unroll
        for (int j = 0; j < 8; ++j) {
            const unsigned short* hp = hlin + (size_t)cl[j] * 128;
            v0[j] = bf2f(hp[c0]);
            v1[j] = bf2f(hp[c1]);
        }
        float m8 = e[0];
        #pragma unroll
        for (int j = 1; j < 8; ++j) m8 = fmaxf(m8, e[j]);
        if (m8 > m) {
            float sc = __expf(m - m8);
            a0 *= sc; a1 *= sc; d *= sc; m = m8;
        }
        #pragma unroll
        for (int j = 0; j < 8; ++j) {
            float w = __expf(e[j] - m);
            a0 += w * v0[j];
            a1 += w * v1[j];
            d  += w;
        }
    }
    for (; idx < epos; ++idx) {
        int col = colS[idx];
        float e = hs[col] + hdv;
        e = (e > 0.f) ? e : 0.2f * e;
        const unsigned short* hr = hlin + (size_t)col * 128;
        float v0 = bf2f(hr[c0]), v1 = bf2f(hr[c1]);
        if (e > m) {
            float sc = __expf(m - e);
            a0 = a0 * sc + v0;
            a1 = a1 * sc + v1;
            d  = d * sc + 1.f;
            m  = e;
        } else {
            float w = __expf(e - m);
            a0 += w * v0;
            a1 += w * v1;
            d  += w;
        }
    }
    float inv = frcp(d + 1e-16f);
    float r0 = a0 * inv + b[c0];
    float r1 = a1 * inv + b[c1];
    xout[(size_t)n * 128 + c0] = f2bf(fmaxf(r0, 0.f));
    xout[(size_t)n * 128 + c1] = f2bf(fmaxf(r1, 0.f));
}

// ---------------- LSTM weight pack into MFMA fragment order ----------------
__global__ void k_wpack(const void* Wihf, const void* Whhf,
                        const void* Wihb, const void* Whhb,
                        const void* bihf, const void* bhhf,
                        const void* bihb, const void* bhhb,
                        const int* __restrict__ flags,
                        unsigned short* __restrict__ Bpack, float* __restrict__ bsum) {
    int idx = blockIdx.x * blockDim.x + threadIdx.x;
    const int TOT = 2 * 10 * 48 * 512;
    if (idx < TOT) {
        int dir = idx / (10 * 48 * 512);
        int r   = idx % (10 * 48 * 512);
        int kb  = r / (48 * 512);
        int r2  = r % (48 * 512);
        int f   = r2 / 512;
        int q   = r2 % 512;
        int lane = q >> 3, j = q & 7;
        int k   = kb * 32 + ((j >> 2) * 16) + ((lane >> 4) * 4) + (j & 3);
        int col = f * 16 + (lane & 15);
        float v;
        if (k < 128)
            v = dir ? rdx(Wihb, (size_t)col * 128 + k, flags[14])
                    : rdx(Wihf, (size_t)col * 128 + k, flags[10]);
        else
            v = dir ? rdx(Whhb, (size_t)col * 192 + (k - 128), flags[15])
                    : rdx(Whhf, (size_t)col * 192 + (k - 128), flags[11]);
        Bpack[idx] = f2bf(v);
    }
    if (idx < 2 * 768) {
        int d = idx / 768, j = idx % 768;
        bsum[idx] = d ? rdx(bihb, j, flags[16]) + rdx(bhhb, j, flags[17])
                      : rdx(bihf, j, flags[12]) + rdx(bhhf, j, flags[13]);
    }
}

// ---------------- fused bidirectional LSTM: 64 rows, 12 waves --------------
// Grid (ceil(N/64), 2); 768 threads = 12 waves. Wave w = base-frag bf in
// [0,12): owns gate-frags {bf, bf+12, bf+24, bf+36} (all 4 gates of units
// m = bf*16 + ccol) across 4 row-frags. Per kb: 4 B loads feed 16 MFMAs
// (64 FLOP/B; no within-block B duplication). B ping-pong prefetch.
__global__ __launch_bounds__(768, 3) void k_lstm_mfma(
    const unsigned short* __restrict__ xsb,  // [3][N][128] bf16
    const unsigned short* __restrict__ Bpack,// [2][10][48][512] bf16
    const float* __restrict__ bsum,          // [2][768]
    const float* __restrict__ attW,          // [384]
    float* __restrict__ scoreP,              // [2][3][N]
    int N) {
    __shared__ unsigned short AS[64][332];   // x:[0,128)  h:[128,320)
    __shared__ float scoreS[64];
    const int t = threadIdx.x;
    const int bf = t >> 6, lane = t & 63;
    const int dir = blockIdx.y;
    const int n0 = blockIdx.x * 64;
    const int ccol = lane & 15;
    const int klane = lane >> 4;
    const int lrow = klane * 4;
    const int akl = klane * 4;
    const int m = bf * 16 + ccol;            // this thread's hidden unit

    const float bI = bsum[dir * 768 + m];
    const float bF = bsum[dir * 768 + 192 + m];
    const float bG = bsum[dir * 768 + 384 + m];
    const float bO = bsum[dir * 768 + 576 + m];
    const float awt = attW[dir * 192 + m];
    float cst[16];
    #pragma unroll
    for (int i = 0; i < 16; ++i) cst[i] = 0.f;

    const unsigned short* Bd = Bpack + (size_t)dir * 10 * 48 * 512;

    for (int s = 0; s < 3; ++s) {
        const int l = dir ? (2 - s) : s;
        // ---- stage x tile: 64x128 bf16 ----
        {
            const unsigned short* xsrc = xsb + ((size_t)l * N + n0) * 128;
            for (int i = t; i < 1024; i += 768) {
                int r = i >> 4, kq = (i & 15) * 8;
                u16x8 v = (u16x8)(0);
                if (n0 + r < N) v = *(const u16x8*)(xsrc + (size_t)r * 128 + kq);
                *(u16x8*)&AS[r][kq] = v;
            }
        }
        if (t < 64) scoreS[t] = 0.f;
        __syncthreads();

        // ---- MFMA GEMM over K, B ping-pong prefetch ----
        const int KB = s ? 10 : 4;               // both even
        f32x4 acc[4][4];
        #pragma unroll
        for (int rf = 0; rf < 4; ++rf)
            #pragma unroll
            for (int g = 0; g < 4; ++g) acc[rf][g] = (f32x4)(0.f);
        s16x8 bA[4], bB[4];
        {
            const unsigned short* bb = Bd + (size_t)bf * 512 + lane * 8;   // kb=0
            #pragma unroll
            for (int g = 0; g < 4; ++g) bA[g] = *(const s16x8*)(bb + (size_t)g * 6144);
        }
        for (int kb = 0; kb < KB; kb += 2) {
            {   // prefetch kb+1
                const unsigned short* bb = Bd + ((size_t)(kb + 1) * 48 + bf) * 512 + lane * 8;
                #pragma unroll
                for (int g = 0; g < 4; ++g) bB[g] = *(const s16x8*)(bb + (size_t)g * 6144);
            }
            {   // compute kb on bA
                const int k0 = kb * 32 + akl;
                s16x8 av[4];
                #pragma unroll
                for (int rf = 0; rf < 4; ++rf) {
                    s16x4 alo = *(const s16x4*)&AS[rf * 16 + ccol][k0];
                    s16x4 ahi = *(const s16x4*)&AS[rf * 16 + ccol][k0 + 16];
                    av[rf] = __builtin_shufflevector(alo, ahi, 0, 1, 2, 3, 4, 5, 6, 7);
                }
                #pragma unroll
                for (int rf = 0; rf < 4; ++rf)
                    #pragma unroll
                    for (int g = 0; g < 4; ++g)
                        acc[rf][g] = __builtin_amdgcn_mfma_f32_16x16x32_bf16(
                            av[rf], bA[g], acc[rf][g], 0, 0, 0);
            }
            if (kb + 2 < KB) {   // prefetch kb+2
                const unsigned short* bb = Bd + ((size_t)(kb + 2) * 48 + bf) * 512 + lane * 8;
                #pragma unroll
                for (int g = 0; g < 4; ++g) bA[g] = *(const s16x8*)(bb + (size_t)g * 6144);
            }
            {   // compute kb+1 on bB
                const int k0 = (kb + 1) * 32 + akl;
                s16x8 av[4];
                #pragma unroll
                for (int rf = 0; rf < 4; ++rf) {
                    s16x4 alo = *(const s16x4*)&AS[rf * 16 + ccol][k0];
                    s16x4 ahi = *(const s16x4*)&AS[rf * 16 + ccol][k0 + 16];
                    av[rf] = __builtin_shufflevector(alo, ahi, 0, 1, 2, 3, 4, 5, 6, 7);
                }
                #pragma unroll
                for (int rf = 0; rf < 4; ++rf)
                    #pragma unroll
                    for (int g = 0; g < 4; ++g)
                        acc[rf][g] = __builtin_amdgcn_mfma_f32_16x16x32_bf16(
                            av[rf], bB[g], acc[rf][g], 0, 0, 0);
            }
        }
        __syncthreads();   // all A reads done before h overwrite

        // ---- cell epilogue: one unit per thread, 16 rows (rcp-based) ----
        float sp[16];
        #pragma unroll
        for (int rf = 0; rf < 4; ++rf) {
            #pragma unroll
            for (int reg = 0; reg < 4; ++reg) {
                float gI = acc[rf][0][reg] + bI;
                float gF = acc[rf][1][reg] + bF;
                float gG = acc[rf][2][reg] + bG;
                float gO = acc[rf][3][reg] + bO;
                float ig = sigm(gI);
                float fg = sigm(gF);
                float gt = fast_tanh(gG);
                float og = sigm(gO);
                int ci = rf * 4 + reg;
                float cn = fg * cst[ci] + ig * gt;
                cst[ci] = cn;
                float hh = og * fast_tanh(cn);
                AS[rf * 16 + lrow + reg][128 + m] = f2bf(hh);
                sp[ci] = hh * awt;
            }
        }
        #pragma unroll
        for (int o = 1; o < 16; o <<= 1) {
            #pragma unroll
            for (int i = 0; i < 16; ++i) sp[i] += __shfl_xor(sp[i], o);
        }
        if (ccol == 0) {
            #pragma unroll
            for (int i = 0; i < 16; ++i)
                atomicAdd(&scoreS[(i >> 2) * 16 + lrow + (i & 3)], sp[i]);
        }
        __syncthreads();
        if (t < 64 && n0 + t < N)
            scoreP[(size_t)(dir * 3 + l) * N + n0 + t] = scoreS[t];
    }
}

// ---------------- fused tail: JK softmax-sum + node MLP + P/Q, 16 nodes ----
__global__ __launch_bounds__(256) void k_tail(
    const unsigned short* __restrict__ xsb, const float* __restrict__ scoreP,
    const float* __restrict__ nW1, const float* __restrict__ nb1,
    const float* __restrict__ nW2, const float* __restrict__ nb2,
    const float* __restrict__ eW1, const float* __restrict__ eb1,
    unsigned short* __restrict__ P, unsigned short* __restrict__ Q,
    float* __restrict__ out, int N) {
    __shared__ float xl[16][128];
    __shared__ float al[16][4];
    const int t = threadIdx.x;
    const int wid = t >> 6, lane = t & 63;
    const int nb = blockIdx.x * 16;
    if (t < 16) {
        int n = nb + t;
        float e0 = 0.f, e1 = 0.f, e2 = 0.f;
        if (n < N) {
            float s0 = scoreP[n]                 + scoreP[(size_t)3 * N + n];
            float s1 = scoreP[(size_t)N + n]     + scoreP[(size_t)4 * N + n];
            float s2 = scoreP[(size_t)2 * N + n] + scoreP[(size_t)5 * N + n];
            float mm = fmaxf(s0, fmaxf(s1, s2));
            e0 = __expf(s0 - mm); e1 = __expf(s1 - mm); e2 = __expf(s2 - mm);
            float inv = frcp(e0 + e1 + e2);
            e0 *= inv; e1 *= inv; e2 *= inv;
        }
        al[t][0] = e0; al[t][1] = e1; al[t][2] = e2;
    }
    __syncthreads();
    const size_t L1o = (size_t)N * 128, L2o = 2 * L1o;
    for (int i = t; i < 2048; i += 256) {
        int r = i >> 7, k = i & 127;
        int n = nb + r;
        float v = 0.f;
        if (n < N) {
            size_t p = (size_t)n * 128 + k;
            v = al[r][0] * bf2f(xsb[p]) + al[r][1] * bf2f(xsb[L1o + p])
              + al[r][2] * bf2f(xsb[L2o + p]);
        }
        xl[r][k] = v;
    }
    __syncthreads();
    const int c0 = lane, c1 = lane + 64;
    const int r0 = wid * 4;
    // ---- node MLP (4 nodes/wave) ----
    {
        float h0[4], h1[4];
        #pragma unroll
        for (int j = 0; j < 4; ++j) { h0[j] = 0.f; h1[j] = 0.f; }
        #pragma unroll 2
        for (int k = 0; k < 128; ++k) {
            float w0 = nW1[k * 128 + c0], w1 = nW1[k * 128 + c1];
            #pragma unroll
            for (int j = 0; j < 4; ++j) {
                float xv = xl[r0 + j][k];
                h0[j] += xv * w0;
                h1[j] += xv * w1;
            }
        }
        float p0[4], p1[4];
        #pragma unroll
        for (int j = 0; j < 4; ++j) {
            float a = fmaxf(h0[j] + nb1[c0], 0.f);
            float bq = fmaxf(h1[j] + nb1[c1], 0.f);
            p0[j] = a * nW2[c0 * 2 + 0] + bq * nW2[c1 * 2 + 0];
            p1[j] = a * nW2[c0 * 2 + 1] + bq * nW2[c1 * 2 + 1];
        }
        #pragma unroll
        for (int o = 32; o; o >>= 1) {
            #pragma unroll
            for (int j = 0; j < 4; ++j) {
                p0[j] += __shfl_down(p0[j], o);
                p1[j] += __shfl_down(p1[j], o);
            }
        }
        if (lane == 0) {
            #pragma unroll
            for (int j = 0; j < 4; ++j) {
                int n = nb + r0 + j;
                if (n < N) {
                    float l0 = p0[j] + nb2[0], l1 = p1[j] + nb2[1];
                    float mm = fmaxf(l0, l1);
                    float e0 = __expf(l0 - mm), e1 = __expf(l1 - mm);
                    float inv = frcp(e0 + e1);
                    out[2 * (size_t)n]     = e0 * inv;
                    out[2 * (size_t)n + 1] = e1 * inv;
                }
            }
        }
    }
    // ---- P/Q precompute (bf16 out, 4 nodes/wave) ----
    {
        float pp0[4], pp1[4], qq0[4], qq1[4];
        #pragma unroll
        for (int j = 0; j < 4; ++j) { pp0[j] = 0.f; pp1[j] = 0.f; qq0[j] = 0.f; qq1[j] = 0.f; }
        for (int k = 0; k < 128; ++k) {
            float wp0 = eW1[k * 128 + c0], wp1 = eW1[k * 128 + c1];
            float wq0 = eW1[(128 + k) * 128 + c0], wq1 = eW1[(128 + k) * 128 + c1];
            #pragma unroll
            for (int j = 0; j < 4; ++j) {
                float xv = xl[r0 + j][k];
                pp0[j] += xv * wp0; pp1[j] += xv * wp1;
                qq0[j] += xv * wq0; qq1[j] += xv * wq1;
            }
        }
        #pragma unroll
        for (int j = 0; j < 4; ++j) {
            int n = nb + r0 + j;
            if (n < N) {
                P[(size_t)n * 128 + c0] = f2bf(pp0[j] + eb1[c0]);
                P[(size_t)n * 128 + c1] = f2bf(pp1[j] + eb1[c1]);
                Q[(size_t)n * 128 + c0] = f2bf(qq0[j]);
                Q[(size_t)n * 128 + c1] = f2bf(qq1[j]);
            }
        }
    }
}

// ---------------- edge MLP finish: gather-add-relu-dot (bf16 P/Q) ----------
__global__ __launch_bounds__(256) void k_edge2(
    const unsigned short* __restrict__ P, const unsigned short* __restrict__ Q,
    const int* __restrict__ row, const int* __restrict__ col,
    const float* __restrict__ W2, const float* __restrict__ b2,
    float* __restrict__ out, long long E, int N) {
    long long g = (((long long)blockIdx.x * blockDim.x) + threadIdx.x) >> 4;
    const int sl = threadIdx.x & 15;
    if (g >= E) return;
    int r = row[g], c = col[g];
    u16x8 pv = *(const u16x8*)(P + (size_t)r * 128 + sl * 8);
    u16x8 qv = *(const u16x8*)(Q + (size_t)c * 128 + sl * 8);
    const float4* w2 = (const float4*)W2 + sl * 4;
    float l0 = 0.f, l1 = 0.f;
    #pragma unroll
    for (int jj = 0; jj < 4; ++jj) {
        float h0 = fmaxf(bf2f(pv[2 * jj])     + bf2f(qv[2 * jj]), 0.f);
        float h1 = fmaxf(bf2f(pv[2 * jj + 1]) + bf2f(qv[2 * jj + 1]), 0.f);
        float4 wv = w2[jj];
        l0 += h0 * wv.x + h1 * wv.z;
        l1 += h0 * wv.y + h1 * wv.w;
    }
    #pragma unroll
    for (int o = 1; o < 16; o <<= 1) { l0 += __shfl_xor(l0, o); l1 += __shfl_xor(l1, o); }
    if (sl == 0) {
        l0 += b2[0]; l1 += b2[1];
        float mm = fmaxf(l0, l1);
        float e0 = __expf(l0 - mm), e1 = __expf(l1 - mm);
        float inv = frcp(e0 + e1);
        out[2 * (long long)N + 2 * g]     = e0 * inv;
        out[2 * (long long)N + 2 * g + 1] = e1 * inv;
    }
}

// ---------------------------------------------------------------------------
extern "C" void kernel_launch(void* const* d_in, const int* in_sizes, int n_in,
                              void* d_out, int out_size, void* d_ws, size_t ws_size,
                              hipStream_t stream) {
    if (n_in < NIN) return;
    const int N = in_sizes[0] / 3;
    const int E = in_sizes[1] / 2;

    char* ws = (char*)d_ws;
    size_t off = 0;
    auto alloc = [&](size_t bytes) -> char* {
        char* p = ws + off;
        off = (off + bytes + 255) & ~(size_t)255;
        return p;
    };
    int* flags = (int*)alloc(32 * sizeof(int));
    int* bsums = (int*)alloc(128 * sizeof(int));
    float* canon[NIN];
    for (int i = 0; i < NIN; ++i) canon[i] = nullptr;
    for (int i = 0; i < NIN; ++i) {
        if (i == 1 || (i >= 10 && i <= 17)) continue;   // LSTM weights read raw
        canon[i] = (float*)alloc((size_t)in_sizes[i] * 4);
    }
    int* row32  = (int*)alloc((size_t)E * 4);
    int* col32  = (int*)alloc((size_t)E * 4);
    int* indptr = (int*)alloc((size_t)(N + 1) * 4);
    int* cnt    = (int*)alloc((size_t)N * 4);
    int* colS   = (int*)alloc((size_t)E * 4);
    float* hs   = (float*)alloc((size_t)N * 4);
    float* hd   = (float*)alloc((size_t)N * 4);
    // hJK buffer: bf16 hlin during GAT phase; bf16 P/Q after the LSTM
    float* hJK  = (float*)alloc((size_t)N * 128 * 4);
    unsigned short* hlin = (unsigned short*)hJK;
    unsigned short* xsb = (unsigned short*)alloc((size_t)3 * N * 128 * 2);  // bf16 xs
    unsigned short* Bpack = (unsigned short*)alloc((size_t)2 * 10 * 48 * 512 * 2);
    float* bsum = (float*)alloc((size_t)2 * 768 * 4);
    float* scoreP;
    if ((size_t)E >= (size_t)6 * N) scoreP = (float*)colS;   // dead after last aggr
    else                            scoreP = (float*)alloc((size_t)6 * N * 4);
    if (off > ws_size) return;
    unsigned short* P = (unsigned short*)hJK;           // bf16, N*128
    unsigned short* Q = (unsigned short*)hJK + (size_t)N * 128;

    InPtrs ip;
    for (int i = 0; i < NIN; ++i) { ip.p[i] = d_in[i]; ip.n[i] = in_sizes[i]; }

    k_sniff<<<NIN, 256, 0, stream>>>(ip, flags);

    // batched canonicalization of all f32/bf16 inputs
    {
        ConvJobs J;
        int nj = 0, blk = 0;
        for (int i = 0; i < NIN; ++i) {
            if (i == 1 || (i >= 10 && i <= 17)) continue;
            J.src[nj] = d_in[i];
            J.dst[nj] = canon[i];
            J.n[nj] = in_sizes[i];
            J.ai[nj] = i;
            J.blk0[nj] = blk;
            blk += (in_sizes[i] + 255) / 256;
            ++nj;
        }
        J.blk0[nj] = blk;
        J.njobs = nj;
        k_convall<<<blk, 256, 0, stream>>>(J, flags);
    }
    k_conve<<<(E + 255) / 256, 256, 0, stream>>>(d_in[1], row32, col32, E, flags);
    k_wpack<<<(2 * 10 * 48 * 512 + 255) / 256, 256, 0, stream>>>(
        d_in[10], d_in[11], d_in[14], d_in[15],
        d_in[12], d_in[13], d_in[16], d_in[17], flags, Bpack, bsum);

    // CSR by row (shared across all 3 GAT layers); parallel scan
    const int nb1k = (N + 1023) / 1024;
    k_zeroi<<<(N + 255) / 256, 256, 0, stream>>>(cnt, N);
    k_hist<<<(E + 255) / 256, 256, 0, stream>>>(row32, cnt, E);
    k_scan1<<<nb1k, 1024, 0, stream>>>(cnt, indptr, bsums, N);
    k_scan2<<<1, 64, 0, stream>>>(bsums, nb1k);
    k_scan3<<<(N + 255) / 256, 256, 0, stream>>>(bsums, indptr, N, nb1k);
    k_zeroi<<<(N + 255) / 256, 256, 0, stream>>>(cnt, N);
    k_fill<<<(E + 255) / 256, 256, 0, stream>>>(row32, col32, indptr, cnt, colS, E);

    // GAT layer 0 (in=3)
    k_lin0<<<(N + 3) / 4, 256, 0, stream>>>(canon[0], canon[2], canon[4], canon[5],
                                            hlin, hs, hd, N);
    k_aggr<<<(N + 3) / 4, 256, 0, stream>>>(hlin, hs, hd, indptr, colS, canon[3], xsb, N);
    // GAT layers 1..2 (in=128, bf16 in/out)
    for (int l = 1; l < 3; ++l) {
        const float* W  = canon[6] + (size_t)(l - 1) * 128 * 128;
        const float* bb = canon[7] + (size_t)(l - 1) * 128;
        const float* as = canon[8] + (size_t)(l - 1) * 128;
        const float* ad = canon[9] + (size_t)(l - 1) * 128;
        k_lin<<<(N + 15) / 16, 256, 0, stream>>>(xsb + (size_t)(l - 1) * N * 128, W, as, ad,
                                                 hlin, hs, hd, N);
        k_aggr<<<(N + 3) / 4, 256, 0, stream>>>(hlin, hs, hd, indptr, colS, bb,
                                                xsb + (size_t)l * N * 128, N);
    }

    // fused bidirectional LSTM (MFMA, 64-row 12-wave) -> scores
    dim3 lgrid((N + 63) / 64, 2);
    k_lstm_mfma<<<lgrid, 768, 0, stream>>>(xsb, Bpack, bsum, canon[18], scoreP, N);

    float* out = (float*)d_out;
    // fused tail: JK finish + node MLP + P/Q (P/Q overwrite dead hlin buffer)
    k_tail<<<(N + 15) / 16, 256, 0, stream>>>(xsb, scoreP,
                                              canon[20], canon[21], canon[22], canon[23],
                                              canon[24], canon[25], P, Q, out, N);
    {
        long long tot = (long long)E * 16;
        int blocks = (int)((tot + 255) / 256);
        k_edge2<<<blocks, 256, 0, stream>>>(P, Q, row32, col32, canon[26], canon[27],
                                            out, (long long)E, N);
    }
}